// Round 6
// baseline (268.252 us; speedup 1.0000x reference)
//
#include <hip/hip_runtime.h>

#define NB 2
#define T_SEQ 2048
#define D_MODEL 1024
#define NH 16
#define HD 64
#define U_SEL 38
#define CAND_CAP 96
#define CGROUP 24

typedef __attribute__((ext_vector_type(8))) short s16x8;
typedef __attribute__((ext_vector_type(4))) short s16x4;
typedef __attribute__((ext_vector_type(4))) float f32x4;
typedef unsigned short ushort_t;

__device__ __forceinline__ unsigned short f2bf(float f) {
    unsigned u = __float_as_uint(f);
    u += 0x7FFFu + ((u >> 16) & 1u);          // RNE
    return (unsigned short)(u >> 16);
}
__device__ __forceinline__ float bf2f(unsigned short h) {
    return __uint_as_float(((unsigned)h) << 16);
}

__device__ __forceinline__ void async_copy16(const void* g, void* l) {
    __builtin_amdgcn_global_load_lds(
        (const __attribute__((address_space(1))) void*)g,
        (__attribute__((address_space(3))) void*)l, 16, 0, 0);
}

// ---------------------------------------------------------------------------
// prep: blocks [0,2048): x -> xh (bf16). blocks [2048,2816): W -> W^T bf16.
// ---------------------------------------------------------------------------
__global__ __launch_bounds__(256) void prep(
    const float* __restrict__ x,
    const float* __restrict__ Wq, const float* __restrict__ Wk, const float* __restrict__ Wv,
    ushort_t* __restrict__ xh,
    ushort_t* __restrict__ wqhT, ushort_t* __restrict__ wkhT, ushort_t* __restrict__ wvhT)
{
    __shared__ float T[64][68];
    const int tid = threadIdx.x;
    if (blockIdx.x < 2048) {
        const size_t i0 = ((size_t)blockIdx.x * 256 + tid) * 8;
        const f32x4 a = *(const f32x4*)(x + i0);
        const f32x4 b = *(const f32x4*)(x + i0 + 4);
        const float f[8] = {a.x, a.y, a.z, a.w, b.x, b.y, b.z, b.w};
        s16x8 hi;
        #pragma unroll
        for (int e = 0; e < 8; ++e) hi[e] = (short)f2bf(f[e]);
        *(s16x8*)(xh + i0) = hi;
        return;
    }
    const int id2 = blockIdx.x - 2048;
    const int z = id2 >> 8;
    const int rem = id2 & 255;
    const int k0 = (rem & 15) * 64, n0 = (rem >> 4) * 64;
    const float* W = (z == 0) ? Wq : (z == 1) ? Wk : Wv;

    #pragma unroll
    for (int i = 0; i < 4; ++i) {
        const int r = (tid >> 4) + i * 16, c = (tid & 15) * 4;
        *(f32x4*)&T[r][c] = *(const f32x4*)&W[(size_t)(k0 + r) * D_MODEL + n0 + c];
    }
    __syncthreads();

    const int n = tid >> 2, kq = (tid & 3) * 16;
    s16x8 hi0, hi1;
    #pragma unroll
    for (int j = 0; j < 16; ++j) {
        const float f = T[kq + j][n];
        if (j < 8) hi0[j] = (short)f2bf(f);
        else       hi1[j - 8] = (short)f2bf(f);
    }
    ushort_t* oh = (z == 0) ? wqhT : (z == 1) ? wkhT : wvhT;
    const size_t ob = (size_t)(n0 + n) * D_MODEL + k0 + kq;
    *(s16x8*)(oh + ob) = hi0;
    *(s16x8*)(oh + ob + 8) = hi1;
}

// ---------------------------------------------------------------------------
// qkv_mfma: 128x128 tile, BK=32, 4 waves, global_load_lds width 16.
// Three uniform 32-step jobs: z0 Q=xh@WqhT -> f32 (+bq);  z1 K bf16 (+bk);
// z2 V -> vT bf16 transposed [bh*64+d][t] (+bv).
// ---------------------------------------------------------------------------
#define GBM 128
#define GBN 128
#define GBK 32

__global__ __launch_bounds__(256) void qkv_mfma(
    const ushort_t* __restrict__ xh,
    const ushort_t* __restrict__ wqhT, const ushort_t* __restrict__ wkhT,
    const ushort_t* __restrict__ wvhT,
    const float* __restrict__ bq, const float* __restrict__ bk, const float* __restrict__ bv,
    float* __restrict__ qo, ushort_t* __restrict__ ko, ushort_t* __restrict__ vT)
{
    const int z = blockIdx.z;
    __shared__ ushort_t Ah[GBM * GBK];
    __shared__ ushort_t Bh[GBN * GBK];

    const int tid = threadIdx.x;
    const int lane = tid & 63;
    const int wid = tid >> 6;
    const int wr = wid >> 1, wc = wid & 1;
    const size_t rowBase = (size_t)blockIdx.x * GBM;
    const size_t colBase = (size_t)blockIdx.y * GBN;

    const ushort_t* B0 = (z == 0) ? wqhT : (z == 1) ? wkhT : wvhT;
    const int srow = tid >> 2;
    const int skq  = (tid & 3) * 8;

    f32x4 acc[4][4] = {};

    for (int kk = 0; kk < 32; ++kk) {
        const int k0 = kk * GBK;
        async_copy16(xh + (rowBase + srow) * D_MODEL + k0 + skq,      &Ah[tid * 8]);
        async_copy16(xh + (rowBase + 64 + srow) * D_MODEL + k0 + skq, &Ah[2048 + tid * 8]);
        async_copy16(B0 + (colBase + srow) * D_MODEL + k0 + skq,      &Bh[tid * 8]);
        async_copy16(B0 + (colBase + 64 + srow) * D_MODEL + k0 + skq, &Bh[2048 + tid * 8]);
        __syncthreads();

        s16x8 af[4], bf[4];
        #pragma unroll
        for (int i = 0; i < 4; ++i)
            af[i] = *(const s16x8*)&Ah[(wr * 64 + i * 16 + (lane & 15)) * GBK + (lane >> 4) * 8];
        #pragma unroll
        for (int j = 0; j < 4; ++j)
            bf[j] = *(const s16x8*)&Bh[(wc * 64 + j * 16 + (lane & 15)) * GBK + (lane >> 4) * 8];
        #pragma unroll
        for (int i = 0; i < 4; ++i)
            #pragma unroll
            for (int j = 0; j < 4; ++j)
                acc[i][j] = __builtin_amdgcn_mfma_f32_16x16x32_bf16(af[i], bf[j], acc[i][j], 0, 0, 0);
        __syncthreads();
    }

    // epilogue: C/D layout col=lane&15, row=(lane>>4)*4+r
    const int cB = (int)colBase + wc * 64 + (lane & 15);
    const int rL = wr * 64 + ((lane >> 4) << 2);
    const int rB = (int)rowBase + rL;
    if (z == 0) {
        #pragma unroll
        for (int j = 0; j < 4; ++j) {
            const float bj = bq[cB + j * 16];
            #pragma unroll
            for (int i = 0; i < 4; ++i)
                #pragma unroll
                for (int r = 0; r < 4; ++r)
                    qo[(size_t)(rB + i * 16 + r) * D_MODEL + cB + j * 16] = acc[i][j][r] + bj;
        }
    } else if (z == 1) {
        #pragma unroll
        for (int j = 0; j < 4; ++j) {
            const float bj = bk[cB + j * 16];
            #pragma unroll
            for (int i = 0; i < 4; ++i)
                #pragma unroll
                for (int r = 0; r < 4; ++r)
                    ko[(size_t)(rB + i * 16 + r) * D_MODEL + cB + j * 16] = f2bf(acc[i][j][r] + bj);
        }
    } else {
        const int bb = (int)(rowBase >> 11);
        const int tBase = (int)(rowBase & (T_SEQ - 1)) + rL;
        #pragma unroll
        for (int j = 0; j < 4; ++j) {
            const int dg = cB + j * 16;
            const float bj = bv[dg];
            ushort_t* vrow = vT + ((size_t)(bb * NH) * HD + dg) * T_SEQ;
            #pragma unroll
            for (int i = 0; i < 4; ++i) {
                s16x4 pk;
                #pragma unroll
                for (int r = 0; r < 4; ++r)
                    pk[r] = (short)f2bf(acc[i][j][r] + bj);
                *(s16x4*)&vrow[tBase + i * 16] = pk;
            }
        }
    }
}

// ---------------------------------------------------------------------------
// q_norms: approximate L1 norms from the f32 Q_hh buffer.
// ---------------------------------------------------------------------------
__global__ __launch_bounds__(256) void q_norms(
    const float* __restrict__ qo, float* __restrict__ norms)
{
    const int gid = blockIdx.x * 256 + threadIdx.x;     // 0..65535
    const int h = gid & 15;
    const int t = (gid >> 4) & (T_SEQ - 1);
    const int b = gid >> 15;
    const float* qr = qo + ((size_t)(b * T_SEQ + t)) * D_MODEL + h * HD;
    float s = 0.f;
    #pragma unroll
    for (int d0 = 0; d0 < HD; d0 += 4) {
        const f32x4 a = *(const f32x4*)(qr + d0);
        s += fabsf(a.x) + fabsf(a.y) + fabsf(a.z) + fabsf(a.w);
    }
    norms[(size_t)(b * NH + h) * T_SEQ + t] = s;
}

// ---------------------------------------------------------------------------
// topk_select: 3-pass radix gives v38 (38th largest approx norm); then emit
// candidate band {t : norm >= v38 - 0.3} (conservative >> 11 sigma bound on
// the bf16-GEMM norm error).
// ---------------------------------------------------------------------------
__global__ __launch_bounds__(256) void topk_select(
    const float* __restrict__ norms, int* __restrict__ cand_t, int* __restrict__ cand_cnt)
{
    const int bh = blockIdx.x;
    const int tid = threadIdx.x;
    const int lane = tid & 63;
    const int w = tid >> 6;

    __shared__ unsigned keys[T_SEQ];
    __shared__ unsigned hist[2048];
    __shared__ unsigned wsum[4];
    __shared__ unsigned bc_bin, bc_above;
    __shared__ int cnt;

    const float* nr = norms + (size_t)bh * T_SEQ;
    #pragma unroll
    for (int j = 0; j < 8; ++j)
        keys[tid + j * 256] = __float_as_uint(nr[tid + j * 256]);

    const int  shifts[3] = {21, 10, 0};
    const unsigned binm[3]  = {0x7FFu, 0x7FFu, 0x3FFu};
    const unsigned prefm[3] = {0x00000000u, 0xFFE00000u, 0xFFFFFC00u};

    unsigned prefix = 0;
    unsigned K_rem = U_SEL;

    for (int p = 0; p < 3; ++p) {
        #pragma unroll
        for (int j = 0; j < 8; ++j) hist[tid + j * 256] = 0;
        __syncthreads();
        #pragma unroll
        for (int j = 0; j < 8; ++j) {
            const unsigned k = keys[tid + j * 256];
            if ((k & prefm[p]) == prefix)
                atomicAdd(&hist[(k >> shifts[p]) & binm[p]], 1u);
        }
        __syncthreads();

        unsigned s = 0;
        #pragma unroll
        for (int e = 0; e < 8; ++e) s += hist[tid * 8 + e];
        unsigned v = s;
        #pragma unroll
        for (int off = 1; off < 64; off <<= 1) {
            const unsigned o = __shfl_down((int)v, off);
            if (lane + off < 64) v += o;
        }
        if (lane == 0) wsum[w] = v;
        __syncthreads();
        unsigned suf = v;
        for (int ww = w + 1; ww < 4; ++ww) suf += wsum[ww];
        const unsigned suf_next = suf - s;

        if (suf >= K_rem && suf_next < K_rem) {
            unsigned acc = suf_next;
            #pragma unroll
            for (int e = 7; e >= 0; --e) {
                const unsigned nb = hist[tid * 8 + e];
                if (acc + nb >= K_rem) { bc_bin = tid * 8 + e; bc_above = acc; break; }
                acc += nb;
            }
        }
        __syncthreads();
        prefix |= bc_bin << shifts[p];
        K_rem -= bc_above;
        __syncthreads();
    }

    const float thr = __uint_as_float(prefix) - 0.3f;
    if (tid == 0) cnt = 0;
    __syncthreads();
    #pragma unroll
    for (int j = 0; j < 8; ++j) {
        const int i = tid + j * 256;
        if (__uint_as_float(keys[i]) >= thr) {
            const int s = atomicAdd(&cnt, 1);
            if (s < CAND_CAP) cand_t[bh * CAND_CAP + s] = i;
        }
    }
    __syncthreads();
    if (tid == 0) cand_cnt[bh] = cnt < CAND_CAP ? cnt : CAND_CAP;
}

// ---------------------------------------------------------------------------
// fixup_norms: exact f32 norms for candidates, directly from x and Wq.
// Grid (32 bh, 4 cgroups of 24). Thread (cq=tid>>6, d=lane): 6 candidates,
// serial-k accumulation (deterministic), LDS-staged 64-k chunks.
// ---------------------------------------------------------------------------
__global__ __launch_bounds__(256) void fixup_norms(
    const float* __restrict__ x, const float* __restrict__ Wq,
    const float* __restrict__ bq, const int* __restrict__ cand_t,
    const int* __restrict__ cand_cnt, float* __restrict__ n_exact)
{
    const int bh = blockIdx.x, cg = blockIdx.y;
    const int b = bh >> 4, h = bh & 15;
    const int nc = cand_cnt[bh];
    const int base = cg * CGROUP;
    if (base >= nc) return;

    __shared__ float Ws[64][64];
    __shared__ float xs[CGROUP][64];
    __shared__ int tc[CGROUP];

    const int tid = threadIdx.x, lane = tid & 63, cq = tid >> 6;
    if (tid < CGROUP) {
        const int gi = base + tid;
        tc[tid] = cand_t[bh * CAND_CAP + (gi < nc ? gi : base)];
    }
    __syncthreads();

    float acc[6] = {};
    for (int k0 = 0; k0 < D_MODEL; k0 += 64) {
        #pragma unroll
        for (int p = 0; p < 4; ++p) {
            const int r = p * 16 + (tid >> 4), col = (tid & 15) * 4;
            *(f32x4*)&Ws[r][col] = *(const f32x4*)&Wq[(size_t)(k0 + r) * D_MODEL + h * HD + col];
        }
        for (int s = tid; s < CGROUP * 16; s += 256) {
            const int r = s >> 4, col = (s & 15) * 4;
            *(f32x4*)&xs[r][col] = *(const f32x4*)&x[((size_t)(b * T_SEQ + tc[r])) * D_MODEL + k0 + col];
        }
        __syncthreads();
        for (int ke = 0; ke < 64; ++ke) {
            const float wv = Ws[ke][lane];
            #pragma unroll
            for (int j = 0; j < 6; ++j)
                acc[j] += xs[cq + j * 4][ke] * wv;
        }
        __syncthreads();
    }

    const float bqv = bq[h * HD + lane];
    #pragma unroll
    for (int j = 0; j < 6; ++j) {
        float v = fabsf(acc[j] + bqv);
        #pragma unroll
        for (int off = 1; off < 64; off <<= 1) v += __shfl_xor(v, off);
        const int c = cq + j * 4;
        if (lane == 0 && base + c < nc)
            n_exact[bh * CAND_CAP + base + c] = v;
    }
}

// ---------------------------------------------------------------------------
// fixup_select: top-38 among candidates by (exact norm, -t). Deterministic.
// ---------------------------------------------------------------------------
__global__ __launch_bounds__(256) void fixup_select(
    const float* __restrict__ n_exact, const int* __restrict__ cand_t,
    const int* __restrict__ cand_cnt, int* __restrict__ idx_out)
{
    const int bh = blockIdx.x;
    const int tid = threadIdx.x, lane = tid & 63, w = tid >> 6;
    const int nc = cand_cnt[bh];

    __shared__ float nv[CAND_CAP];
    __shared__ int   tv[CAND_CAP];
    __shared__ float wv[4]; __shared__ int wt[4]; __shared__ int wsl[4];

    if (tid < CAND_CAP) {
        nv[tid] = (tid < nc) ? n_exact[bh * CAND_CAP + tid] : -1e30f;
        tv[tid] = (tid < nc) ? cand_t[bh * CAND_CAP + tid] : 0x7FFFFFFF;
    }
    __syncthreads();

    for (int r = 0; r < U_SEL; ++r) {
        float v; int t, sl;
        if (tid < CAND_CAP) { v = nv[tid]; t = tv[tid]; sl = tid; }
        else { v = -1e30f; t = 0x7FFFFFFF; sl = 0; }
        #pragma unroll
        for (int off = 1; off < 64; off <<= 1) {
            const float ov = __shfl_xor(v, off);
            const int   ot = __shfl_xor(t, off);
            const int   osl = __shfl_xor(sl, off);
            if (ov > v || (ov == v && ot < t)) { v = ov; t = ot; sl = osl; }
        }
        if (lane == 0) { wv[w] = v; wt[w] = t; wsl[w] = sl; }
        __syncthreads();
        if (tid == 0) {
            float bvv = wv[0]; int btt = wt[0]; int bsl = wsl[0];
            #pragma unroll
            for (int ww = 1; ww < 4; ++ww)
                if (wv[ww] > bvv || (wv[ww] == bvv && wt[ww] < btt)) {
                    bvv = wv[ww]; btt = wt[ww]; bsl = wsl[ww];
                }
            idx_out[bh * U_SEL + r] = btt;
            nv[bsl] = -1e30f;
        }
        __syncthreads();
    }
}

// ---------------------------------------------------------------------------
// attn_scores: S[bh][u][t] = (q_sel . k_t) * scale for t <= qi.
// ---------------------------------------------------------------------------
__global__ __launch_bounds__(256) void attn_scores(
    const float* __restrict__ q, const ushort_t* __restrict__ kk_,
    const int* __restrict__ idx, float* __restrict__ S)
{
    const int bh = blockIdx.x, ch = blockIdx.y;
    const int b = bh >> 4, h = bh & 15;
    const int tid = threadIdx.x;
    const int t = ch * 256 + tid;

    __shared__ float qs[U_SEL][HD];
    __shared__ int qis[U_SEL];

    if (tid < U_SEL) qis[tid] = idx[bh * U_SEL + tid];
    __syncthreads();
    for (int e = tid; e < U_SEL * HD; e += 256) {
        const int u = e >> 6, d = e & 63;
        qs[u][d] = q[((size_t)(b * T_SEQ + qis[u])) * D_MODEL + h * HD + d] * 0.125f;
    }

    float kr[64];
    {
        const ushort_t* kp = kk_ + ((size_t)(b * T_SEQ + t)) * D_MODEL + h * HD;
        #pragma unroll
        for (int d0 = 0; d0 < 64; d0 += 8) {
            const s16x8 r = *(const s16x8*)(kp + d0);
            #pragma unroll
            for (int e = 0; e < 8; ++e) kr[d0 + e] = bf2f((unsigned short)r[e]);
        }
    }
    __syncthreads();

    const int wbase = ch * 256 + (tid & ~63);
    for (int u = 0; u < U_SEL; ++u) {
        const int qi = qis[u];
        if (wbase > qi) continue;
        float sp0 = 0.f, sp1 = 0.f, sp2 = 0.f, sp3 = 0.f;
        #pragma unroll
        for (int d0 = 0; d0 < 64; d0 += 16) {
            const f32x4 q0 = *(const f32x4*)&qs[u][d0];
            const f32x4 q1 = *(const f32x4*)&qs[u][d0 + 4];
            const f32x4 q2 = *(const f32x4*)&qs[u][d0 + 8];
            const f32x4 q3 = *(const f32x4*)&qs[u][d0 + 12];
            sp0 += q0.x * kr[d0] + q0.y * kr[d0 + 1] + q0.z * kr[d0 + 2] + q0.w * kr[d0 + 3];
            sp1 += q1.x * kr[d0 + 4] + q1.y * kr[d0 + 5] + q1.z * kr[d0 + 6] + q1.w * kr[d0 + 7];
            sp2 += q2.x * kr[d0 + 8] + q2.y * kr[d0 + 9] + q2.z * kr[d0 + 10] + q2.w * kr[d0 + 11];
            sp3 += q3.x * kr[d0 + 12] + q3.y * kr[d0 + 13] + q3.z * kr[d0 + 14] + q3.w * kr[d0 + 15];
        }
        S[((size_t)(bh * U_SEL + u)) * T_SEQ + t] = sp0 + sp1 + sp2 + sp3;
    }
}

// ---------------------------------------------------------------------------
// attn_pv: one block per (bh,u). Softmax over S[0..qi] (LDS), PV along the
// contiguous t axis of transposed V.
// ---------------------------------------------------------------------------
__global__ __launch_bounds__(256) void attn_pv(
    const float* __restrict__ S, const ushort_t* __restrict__ vT,
    const int* __restrict__ idx, float* __restrict__ sel_out)
{
    const int bh = blockIdx.x, u = blockIdx.y;
    const int tid = threadIdx.x;
    const int d = tid & 63;
    const int qtr = tid >> 6;
    const int qi = idx[bh * U_SEL + u];
    const int nk = qi + 1;
    const int pad8 = (nk + 7) & ~7;
    const float* Srow = S + ((size_t)(bh * U_SEL + u)) * T_SEQ;

    __shared__ float sc[T_SEQ];
    __shared__ float red[256];
    __shared__ float part[4][HD];

    float lm = -1e30f;
    for (int t = tid; t < nk; t += 256) { const float s = Srow[t]; sc[t] = s; lm = fmaxf(lm, s); }
    red[tid] = lm;
    __syncthreads();
    for (int s = 128; s > 0; s >>= 1) {
        if (tid < s) red[tid] = fmaxf(red[tid], red[tid + s]);
        __syncthreads();
    }
    const float m = red[0];
    __syncthreads();

    float ls = 0.f;
    for (int t = tid; t < nk; t += 256) { const float p = __expf(sc[t] - m); sc[t] = p; ls += p; }
    if (tid < 7) { const int t = nk + tid; if (t < pad8) sc[t] = 0.f; }
    red[tid] = ls;
    __syncthreads();
    for (int s = 128; s > 0; s >>= 1) {
        if (tid < s) red[tid] += red[tid + s];
        __syncthreads();
    }
    const float l = red[0];

    const ushort_t* vrow = vT + ((size_t)(bh * HD + d)) * T_SEQ;
    float a0 = 0.f, a1 = 0.f;
    #pragma unroll
    for (int mm = 0; mm < 4; ++mm) {
        const int base = mm * 512 + qtr * 128;
        if (base >= nk) break;
        const int bend = base + 128 < pad8 ? base + 128 : pad8;
        for (int t = base; t < bend; t += 8) {
            const s16x8 v8 = *(const s16x8*)(vrow + t);
            const f32x4 p0 = *(const f32x4*)&sc[t];
            const f32x4 p1 = *(const f32x4*)&sc[t + 4];
            a0 += p0.x * bf2f((unsigned short)v8[0]) + p0.y * bf2f((unsigned short)v8[1])
                + p0.z * bf2f((unsigned short)v8[2]) + p0.w * bf2f((unsigned short)v8[3]);
            a1 += p1.x * bf2f((unsigned short)v8[4]) + p1.y * bf2f((unsigned short)v8[5])
                + p1.z * bf2f((unsigned short)v8[6]) + p1.w * bf2f((unsigned short)v8[7]);
        }
    }
    part[qtr][d] = a0 + a1;
    __syncthreads();
    if (tid < HD)
        sel_out[((size_t)(bh * U_SEL + u)) * HD + tid] =
            (part[0][tid] + part[1][tid] + part[2][tid] + part[3][tid]) / l;
}

// ---------------------------------------------------------------------------
__global__ __launch_bounds__(256) void init_out(
    float* __restrict__ out, const float* __restrict__ bo)
{
    const size_t i = (size_t)blockIdx.x * 256 + threadIdx.x;
    out[i] = bo[i & (D_MODEL - 1)];
}

__global__ __launch_bounds__(256) void scatter_proj(
    const float* __restrict__ sel_out, const int* __restrict__ idx,
    const float* __restrict__ Wo, float* __restrict__ out)
{
    const int bh = blockIdx.x;
    const int ui = blockIdx.y;
    const int b = bh >> 4, h = bh & 15;
    const int t = idx[bh * U_SEL + ui];
    const int tid = threadIdx.x;

    __shared__ float s[HD];
    if (tid < HD) s[tid] = sel_out[((size_t)(bh * U_SEL + ui)) * HD + tid];
    __syncthreads();

    const int c0 = tid * 4;
    float a0 = 0.f, a1 = 0.f, a2 = 0.f, a3 = 0.f;
    #pragma unroll 8
    for (int r = 0; r < HD; ++r) {
        const float sv = s[r];
        const f32x4 w4 = *(const f32x4*)&Wo[((size_t)(h * HD + r)) * D_MODEL + c0];
        a0 += sv * w4.x; a1 += sv * w4.y; a2 += sv * w4.z; a3 += sv * w4.w;
    }
    float* op = &out[((size_t)(b * T_SEQ + t)) * D_MODEL + c0];
    atomicAdd(&op[0], a0);
    atomicAdd(&op[1], a1);
    atomicAdd(&op[2], a2);
    atomicAdd(&op[3], a3);
}

// ---------------------------------------------------------------------------
extern "C" void kernel_launch(void* const* d_in, const int* in_sizes, int n_in,
                              void* d_out, int out_size, void* d_ws, size_t ws_size,
                              hipStream_t stream)
{
    const float* x  = (const float*)d_in[0];
    const float* Wq = (const float*)d_in[1];
    const float* bq = (const float*)d_in[2];
    const float* Wk = (const float*)d_in[3];
    const float* bk = (const float*)d_in[4];
    const float* Wv = (const float*)d_in[5];
    const float* bv = (const float*)d_in[6];
    const float* Wo = (const float*)d_in[7];
    const float* bo = (const float*)d_in[8];
    float* out = (float*)d_out;

    // workspace layout (~41 MB, no aliasing)
    char* ws = (char*)d_ws;
    ushort_t* xh      = (ushort_t*)(ws);                              //  8 MB
    ushort_t* wqhT    = (ushort_t*)(ws + (8u << 20));                 //  2 MB
    ushort_t* wkhT    = (ushort_t*)(ws + (10u << 20));                //  2 MB
    ushort_t* wvhT    = (ushort_t*)(ws + (12u << 20));                //  2 MB
    ushort_t* k       = (ushort_t*)(ws + (14u << 20));                //  8 MB
    ushort_t* vT      = (ushort_t*)(ws + (22u << 20));                //  8 MB
    float*    S       = (float*)(ws + (30u << 20));                   // 10 MB
    float*    norms   = (float*)(ws + (40u << 20));                   // 256 KB
    int*      cand_t  = (int*)(ws + (40u << 20) + (256u << 10));      // 12 KB
    int*      cand_cnt= (int*)(ws + (40u << 20) + (272u << 10));      // 128 B
    float*    n_exact = (float*)(ws + (40u << 20) + (276u << 10));    // 12 KB
    int*      idx     = (int*)(ws + (40u << 20) + (292u << 10));      // ~5 KB
    float*    sel_out = (float*)(ws + (40u << 20) + (300u << 10));    // 304 KB
    float*    q       = (float*)d_out;   // Q lives in d_out until init_out

    prep<<<2048 + 768, 256, 0, stream>>>(x, Wq, Wk, Wv, xh, wqhT, wkhT, wvhT);
    {
        dim3 g((NB * T_SEQ) / GBM, D_MODEL / GBN, 3);
        qkv_mfma<<<g, 256, 0, stream>>>(xh, wqhT, wkhT, wvhT, bq, bk, bv, q, k, vT);
    }
    q_norms<<<256, 256, 0, stream>>>(q, norms);
    topk_select<<<NB * NH, 256, 0, stream>>>(norms, cand_t, cand_cnt);
    {
        dim3 g(NB * NH, 4);
        fixup_norms<<<g, 256, 0, stream>>>(x, Wq, bq, cand_t, cand_cnt, n_exact);
    }
    fixup_select<<<NB * NH, 256, 0, stream>>>(n_exact, cand_t, cand_cnt, idx);
    {
        dim3 g(NB * NH, T_SEQ / 256);
        attn_scores<<<g, 256, 0, stream>>>(q, k, idx, S);
    }
    {
        dim3 g(NB * NH, U_SEL);
        attn_pv<<<g, 256, 0, stream>>>(S, vT, idx, sel_out);
    }
    init_out<<<(NB * T_SEQ * D_MODEL) / 256, 256, 0, stream>>>(out, bo);
    {
        dim3 g(NB * NH, U_SEL);
        scatter_proj<<<g, 256, 0, stream>>>(sel_out, idx, Wo, out);
    }
}

// Round 7
// 236.216 us; speedup vs baseline: 1.1356x; 1.1356x over previous
//
#include <hip/hip_runtime.h>

#define NB 2
#define T_SEQ 2048
#define D_MODEL 1024
#define NH 16
#define HD 64
#define U_SEL 38
#define CAND_CAP 96

typedef __attribute__((ext_vector_type(8))) short s16x8;
typedef __attribute__((ext_vector_type(4))) short s16x4;
typedef __attribute__((ext_vector_type(4))) float f32x4;
typedef unsigned short ushort_t;

__device__ __forceinline__ unsigned short f2bf(float f) {
    unsigned u = __float_as_uint(f);
    u += 0x7FFFu + ((u >> 16) & 1u);          // RNE
    return (unsigned short)(u >> 16);
}
__device__ __forceinline__ float bf2f(unsigned short h) {
    return __uint_as_float(((unsigned)h) << 16);
}

__device__ __forceinline__ void async_copy16(const void* g, void* l) {
    __builtin_amdgcn_global_load_lds(
        (const __attribute__((address_space(1))) void*)g,
        (__attribute__((address_space(3))) void*)l, 16, 0, 0);
}

// ---------------------------------------------------------------------------
// prep: blocks [0,2048): x -> xh (bf16). blocks [2048,2816): W -> W^T bf16.
// ---------------------------------------------------------------------------
__global__ __launch_bounds__(256) void prep(
    const float* __restrict__ x,
    const float* __restrict__ Wq, const float* __restrict__ Wk, const float* __restrict__ Wv,
    ushort_t* __restrict__ xh,
    ushort_t* __restrict__ wqhT, ushort_t* __restrict__ wkhT, ushort_t* __restrict__ wvhT)
{
    __shared__ float T[64][68];
    const int tid = threadIdx.x;
    if (blockIdx.x < 2048) {
        const size_t i0 = ((size_t)blockIdx.x * 256 + tid) * 8;
        const f32x4 a = *(const f32x4*)(x + i0);
        const f32x4 b = *(const f32x4*)(x + i0 + 4);
        const float f[8] = {a.x, a.y, a.z, a.w, b.x, b.y, b.z, b.w};
        s16x8 hi;
        #pragma unroll
        for (int e = 0; e < 8; ++e) hi[e] = (short)f2bf(f[e]);
        *(s16x8*)(xh + i0) = hi;
        return;
    }
    const int id2 = blockIdx.x - 2048;
    const int z = id2 >> 8;
    const int rem = id2 & 255;
    const int k0 = (rem & 15) * 64, n0 = (rem >> 4) * 64;
    const float* W = (z == 0) ? Wq : (z == 1) ? Wk : Wv;

    #pragma unroll
    for (int i = 0; i < 4; ++i) {
        const int r = (tid >> 4) + i * 16, c = (tid & 15) * 4;
        *(f32x4*)&T[r][c] = *(const f32x4*)&W[(size_t)(k0 + r) * D_MODEL + n0 + c];
    }
    __syncthreads();

    const int n = tid >> 2, kq = (tid & 3) * 16;
    s16x8 hi0, hi1;
    #pragma unroll
    for (int j = 0; j < 16; ++j) {
        const float f = T[kq + j][n];
        if (j < 8) hi0[j] = (short)f2bf(f);
        else       hi1[j - 8] = (short)f2bf(f);
    }
    ushort_t* oh = (z == 0) ? wqhT : (z == 1) ? wkhT : wvhT;
    const size_t ob = (size_t)(n0 + n) * D_MODEL + k0 + kq;
    *(s16x8*)(oh + ob) = hi0;
    *(s16x8*)(oh + ob + 8) = hi1;
}

// ---------------------------------------------------------------------------
// qkv_mfma: 128x128 tile, BK=32, 4 waves, global_load_lds width 16.
// Three uniform 32-step jobs: z0 Q=xh@WqhT -> f32 (+bq);  z1 K bf16 (+bk);
// z2 V -> vT bf16 transposed [bh*64+d][t] (+bv).
// ---------------------------------------------------------------------------
#define GBM 128
#define GBN 128
#define GBK 32

__global__ __launch_bounds__(256) void qkv_mfma(
    const ushort_t* __restrict__ xh,
    const ushort_t* __restrict__ wqhT, const ushort_t* __restrict__ wkhT,
    const ushort_t* __restrict__ wvhT,
    const float* __restrict__ bq, const float* __restrict__ bk, const float* __restrict__ bv,
    float* __restrict__ qo, ushort_t* __restrict__ ko, ushort_t* __restrict__ vT)
{
    const int z = blockIdx.z;
    __shared__ ushort_t Ah[GBM * GBK];
    __shared__ ushort_t Bh[GBN * GBK];

    const int tid = threadIdx.x;
    const int lane = tid & 63;
    const int wid = tid >> 6;
    const int wr = wid >> 1, wc = wid & 1;
    const size_t rowBase = (size_t)blockIdx.x * GBM;
    const size_t colBase = (size_t)blockIdx.y * GBN;

    const ushort_t* B0 = (z == 0) ? wqhT : (z == 1) ? wkhT : wvhT;
    const int srow = tid >> 2;
    const int skq  = (tid & 3) * 8;

    f32x4 acc[4][4] = {};

    for (int kk = 0; kk < 32; ++kk) {
        const int k0 = kk * GBK;
        async_copy16(xh + (rowBase + srow) * D_MODEL + k0 + skq,      &Ah[tid * 8]);
        async_copy16(xh + (rowBase + 64 + srow) * D_MODEL + k0 + skq, &Ah[2048 + tid * 8]);
        async_copy16(B0 + (colBase + srow) * D_MODEL + k0 + skq,      &Bh[tid * 8]);
        async_copy16(B0 + (colBase + 64 + srow) * D_MODEL + k0 + skq, &Bh[2048 + tid * 8]);
        __syncthreads();

        s16x8 af[4], bf[4];
        #pragma unroll
        for (int i = 0; i < 4; ++i)
            af[i] = *(const s16x8*)&Ah[(wr * 64 + i * 16 + (lane & 15)) * GBK + (lane >> 4) * 8];
        #pragma unroll
        for (int j = 0; j < 4; ++j)
            bf[j] = *(const s16x8*)&Bh[(wc * 64 + j * 16 + (lane & 15)) * GBK + (lane >> 4) * 8];
        #pragma unroll
        for (int i = 0; i < 4; ++i)
            #pragma unroll
            for (int j = 0; j < 4; ++j)
                acc[i][j] = __builtin_amdgcn_mfma_f32_16x16x32_bf16(af[i], bf[j], acc[i][j], 0, 0, 0);
        __syncthreads();
    }

    // epilogue: C/D layout col=lane&15, row=(lane>>4)*4+r
    const int cB = (int)colBase + wc * 64 + (lane & 15);
    const int rL = wr * 64 + ((lane >> 4) << 2);
    const int rB = (int)rowBase + rL;
    if (z == 0) {
        #pragma unroll
        for (int j = 0; j < 4; ++j) {
            const float bj = bq[cB + j * 16];
            #pragma unroll
            for (int i = 0; i < 4; ++i)
                #pragma unroll
                for (int r = 0; r < 4; ++r)
                    qo[(size_t)(rB + i * 16 + r) * D_MODEL + cB + j * 16] = acc[i][j][r] + bj;
        }
    } else if (z == 1) {
        #pragma unroll
        for (int j = 0; j < 4; ++j) {
            const float bj = bk[cB + j * 16];
            #pragma unroll
            for (int i = 0; i < 4; ++i)
                #pragma unroll
                for (int r = 0; r < 4; ++r)
                    ko[(size_t)(rB + i * 16 + r) * D_MODEL + cB + j * 16] = f2bf(acc[i][j][r] + bj);
        }
    } else {
        const int bb = (int)(rowBase >> 11);
        const int tBase = (int)(rowBase & (T_SEQ - 1)) + rL;
        #pragma unroll
        for (int j = 0; j < 4; ++j) {
            const int dg = cB + j * 16;
            const float bj = bv[dg];
            ushort_t* vrow = vT + ((size_t)(bb * NH) * HD + dg) * T_SEQ;
            #pragma unroll
            for (int i = 0; i < 4; ++i) {
                s16x4 pk;
                #pragma unroll
                for (int r = 0; r < 4; ++r)
                    pk[r] = (short)f2bf(acc[i][j][r] + bj);
                *(s16x4*)&vrow[tBase + i * 16] = pk;
            }
        }
    }
}

// ---------------------------------------------------------------------------
// q_norms: approximate L1 norms from the f32 Q buffer.
// ---------------------------------------------------------------------------
__global__ __launch_bounds__(256) void q_norms(
    const float* __restrict__ qo, float* __restrict__ norms)
{
    const int gid = blockIdx.x * 256 + threadIdx.x;     // 0..65535
    const int h = gid & 15;
    const int t = (gid >> 4) & (T_SEQ - 1);
    const int b = gid >> 15;
    const float* qr = qo + ((size_t)(b * T_SEQ + t)) * D_MODEL + h * HD;
    float s = 0.f;
    #pragma unroll
    for (int d0 = 0; d0 < HD; d0 += 4) {
        const f32x4 a = *(const f32x4*)(qr + d0);
        s += fabsf(a.x) + fabsf(a.y) + fabsf(a.z) + fabsf(a.w);
    }
    norms[(size_t)(b * NH + h) * T_SEQ + t] = s;
}

// ---------------------------------------------------------------------------
// topk_select: 3-pass radix gives v38 (38th largest approx norm); emit the
// candidate band {t : norm >= v38 - 0.4} (conservative vs bf16 norm error).
// ---------------------------------------------------------------------------
__global__ __launch_bounds__(256) void topk_select(
    const float* __restrict__ norms, int* __restrict__ cand_t, int* __restrict__ cand_cnt)
{
    const int bh = blockIdx.x;
    const int tid = threadIdx.x;
    const int lane = tid & 63;
    const int w = tid >> 6;

    __shared__ unsigned keys[T_SEQ];
    __shared__ unsigned hist[2048];
    __shared__ unsigned wsum[4];
    __shared__ unsigned bc_bin, bc_above;
    __shared__ int cnt;

    const float* nr = norms + (size_t)bh * T_SEQ;
    #pragma unroll
    for (int j = 0; j < 8; ++j)
        keys[tid + j * 256] = __float_as_uint(nr[tid + j * 256]);

    const int  shifts[3] = {21, 10, 0};
    const unsigned binm[3]  = {0x7FFu, 0x7FFu, 0x3FFu};
    const unsigned prefm[3] = {0x00000000u, 0xFFE00000u, 0xFFFFFC00u};

    unsigned prefix = 0;
    unsigned K_rem = U_SEL;

    for (int p = 0; p < 3; ++p) {
        #pragma unroll
        for (int j = 0; j < 8; ++j) hist[tid + j * 256] = 0;
        __syncthreads();
        #pragma unroll
        for (int j = 0; j < 8; ++j) {
            const unsigned k = keys[tid + j * 256];
            if ((k & prefm[p]) == prefix)
                atomicAdd(&hist[(k >> shifts[p]) & binm[p]], 1u);
        }
        __syncthreads();

        unsigned s = 0;
        #pragma unroll
        for (int e = 0; e < 8; ++e) s += hist[tid * 8 + e];
        unsigned v = s;
        #pragma unroll
        for (int off = 1; off < 64; off <<= 1) {
            const unsigned o = __shfl_down((int)v, off);
            if (lane + off < 64) v += o;
        }
        if (lane == 0) wsum[w] = v;
        __syncthreads();
        unsigned suf = v;
        for (int ww = w + 1; ww < 4; ++ww) suf += wsum[ww];
        const unsigned suf_next = suf - s;

        if (suf >= K_rem && suf_next < K_rem) {
            unsigned acc = suf_next;
            #pragma unroll
            for (int e = 7; e >= 0; --e) {
                const unsigned nb = hist[tid * 8 + e];
                if (acc + nb >= K_rem) { bc_bin = tid * 8 + e; bc_above = acc; break; }
                acc += nb;
            }
        }
        __syncthreads();
        prefix |= bc_bin << shifts[p];
        K_rem -= bc_above;
        __syncthreads();
    }

    const float thr = __uint_as_float(prefix) - 0.4f;
    if (tid == 0) cnt = 0;
    __syncthreads();
    #pragma unroll
    for (int j = 0; j < 8; ++j) {
        const int i = tid + j * 256;
        if (__uint_as_float(keys[i]) >= thr) {
            const int s = atomicAdd(&cnt, 1);
            if (s < CAND_CAP) cand_t[bh * CAND_CAP + s] = i;
        }
    }
    __syncthreads();
    if (tid == 0) cand_cnt[bh] = cnt < CAND_CAP ? cnt : CAND_CAP;
}

// ---------------------------------------------------------------------------
// fixup_norms: one block per (bh, candidate). Exact f32 q-row norm from x, Wq.
// x row staged in LDS (4 KB); thread (d=tid&63, kq=tid>>6) accumulates its
// k-quarter with coalesced Wq reads (wave = 256 B contiguous per k).
// ---------------------------------------------------------------------------
__global__ __launch_bounds__(256) void fixup_norms(
    const float* __restrict__ x, const float* __restrict__ Wq,
    const float* __restrict__ bq, const int* __restrict__ cand_t,
    const int* __restrict__ cand_cnt, float* __restrict__ n_exact)
{
    const int bh = blockIdx.x, c = blockIdx.y;
    const int b = bh >> 4, h = bh & 15;
    if (c >= cand_cnt[bh]) return;
    const int t = cand_t[bh * CAND_CAP + c];
    const int tid = threadIdx.x, d = tid & 63, kq = tid >> 6;

    __shared__ float xs[D_MODEL];
    __shared__ float part[4][HD];

    *(f32x4*)&xs[tid * 4] = *(const f32x4*)&x[((size_t)(b * T_SEQ + t)) * D_MODEL + tid * 4];
    __syncthreads();

    const float* wp = Wq + (size_t)(kq * 256) * D_MODEL + h * HD + d;
    const float* xp = &xs[kq * 256];
    float a0 = 0.f, a1 = 0.f, a2 = 0.f, a3 = 0.f;
    #pragma unroll 4
    for (int k = 0; k < 256; k += 4) {
        a0 += xp[k]     * wp[(k)     * D_MODEL];
        a1 += xp[k + 1] * wp[(k + 1) * D_MODEL];
        a2 += xp[k + 2] * wp[(k + 2) * D_MODEL];
        a3 += xp[k + 3] * wp[(k + 3) * D_MODEL];
    }
    part[kq][d] = (a0 + a1) + (a2 + a3);
    __syncthreads();
    if (tid < 64) {
        float v = fabsf(part[0][tid] + part[1][tid] + part[2][tid] + part[3][tid]
                        + bq[h * HD + tid]);
        #pragma unroll
        for (int off = 1; off < 64; off <<= 1) v += __shfl_xor(v, off);
        if (tid == 0) n_exact[bh * CAND_CAP + c] = v;
    }
}

// ---------------------------------------------------------------------------
// fixup_select: top-38 among candidates by (exact norm, -t). Deterministic.
// ---------------------------------------------------------------------------
__global__ __launch_bounds__(256) void fixup_select(
    const float* __restrict__ n_exact, const int* __restrict__ cand_t,
    const int* __restrict__ cand_cnt, int* __restrict__ idx_out)
{
    const int bh = blockIdx.x;
    const int tid = threadIdx.x, lane = tid & 63, w = tid >> 6;
    const int nc = cand_cnt[bh];

    __shared__ float nv[CAND_CAP];
    __shared__ int   tv[CAND_CAP];
    __shared__ float wv[4]; __shared__ int wt[4]; __shared__ int wsl[4];

    if (tid < CAND_CAP) {
        nv[tid] = (tid < nc) ? n_exact[bh * CAND_CAP + tid] : -1e30f;
        tv[tid] = (tid < nc) ? cand_t[bh * CAND_CAP + tid] : 0x7FFFFFFF;
    }
    __syncthreads();

    for (int r = 0; r < U_SEL; ++r) {
        float v; int t, sl;
        if (tid < CAND_CAP) { v = nv[tid]; t = tv[tid]; sl = tid; }
        else { v = -1e30f; t = 0x7FFFFFFF; sl = 0; }
        #pragma unroll
        for (int off = 1; off < 64; off <<= 1) {
            const float ov = __shfl_xor(v, off);
            const int   ot = __shfl_xor(t, off);
            const int   osl = __shfl_xor(sl, off);
            if (ov > v || (ov == v && ot < t)) { v = ov; t = ot; sl = osl; }
        }
        if (lane == 0) { wv[w] = v; wt[w] = t; wsl[w] = sl; }
        __syncthreads();
        if (tid == 0) {
            float bvv = wv[0]; int btt = wt[0]; int bsl = wsl[0];
            #pragma unroll
            for (int ww = 1; ww < 4; ++ww)
                if (wv[ww] > bvv || (wv[ww] == bvv && wt[ww] < btt)) {
                    bvv = wv[ww]; btt = wt[ww]; bsl = wsl[ww];
                }
            idx_out[bh * U_SEL + r] = btt;
            nv[bsl] = -1e30f;
        }
        __syncthreads();
    }
}

// ---------------------------------------------------------------------------
// attn_fused: one block per (bh,u). Scores (q.k over t<=qi) -> LDS, block
// softmax, then PV along the contiguous t axis of transposed V.
// ---------------------------------------------------------------------------
__global__ __launch_bounds__(256) void attn_fused(
    const float* __restrict__ q, const ushort_t* __restrict__ kk_,
    const ushort_t* __restrict__ vT, const int* __restrict__ idx,
    float* __restrict__ sel_out)
{
    const int bh = blockIdx.x, u = blockIdx.y;
    const int b = bh >> 4, h = bh & 15;
    const int tid = threadIdx.x;
    const int d = tid & 63;
    const int qtr = tid >> 6;
    const int qi = idx[bh * U_SEL + u];
    const int nk = qi + 1;
    const int pad8 = (nk + 7) & ~7;

    __shared__ float qs[HD];
    __shared__ float sc[T_SEQ];
    __shared__ float red[256];
    __shared__ float part[4][HD];

    if (tid < HD)
        qs[tid] = q[((size_t)(b * T_SEQ + qi)) * D_MODEL + h * HD + tid] * 0.125f;
    __syncthreads();

    // scores + local max
    float lm = -1e30f;
    const ushort_t* kbase = kk_ + (size_t)b * T_SEQ * D_MODEL + h * HD;
    for (int t = tid; t < nk; t += 256) {
        const ushort_t* kp = kbase + (size_t)t * D_MODEL;
        float s0 = 0.f, s1 = 0.f;
        #pragma unroll
        for (int d0 = 0; d0 < 64; d0 += 16) {
            const s16x8 r0 = *(const s16x8*)(kp + d0);
            const s16x8 r1 = *(const s16x8*)(kp + d0 + 8);
            #pragma unroll
            for (int e = 0; e < 8; ++e) {
                s0 += qs[d0 + e]     * bf2f((unsigned short)r0[e]);
                s1 += qs[d0 + 8 + e] * bf2f((unsigned short)r1[e]);
            }
        }
        const float s = s0 + s1;
        sc[t] = s;
        lm = fmaxf(lm, s);
    }
    red[tid] = lm;
    __syncthreads();
    for (int s = 128; s > 0; s >>= 1) {
        if (tid < s) red[tid] = fmaxf(red[tid], red[tid + s]);
        __syncthreads();
    }
    const float m = red[0];
    __syncthreads();

    // exp + sum (+ zero 8-pad)
    float ls = 0.f;
    for (int t = tid; t < nk; t += 256) { const float p = __expf(sc[t] - m); sc[t] = p; ls += p; }
    if (tid < 7) { const int t = nk + tid; if (t < pad8) sc[t] = 0.f; }
    red[tid] = ls;
    __syncthreads();
    for (int s = 128; s > 0; s >>= 1) {
        if (tid < s) red[tid] += red[tid + s];
        __syncthreads();
    }
    const float l = red[0];

    // PV along contiguous t
    const ushort_t* vrow = vT + ((size_t)(bh * HD + d)) * T_SEQ;
    float a0 = 0.f, a1 = 0.f;
    #pragma unroll
    for (int mm = 0; mm < 4; ++mm) {
        const int base = mm * 512 + qtr * 128;
        if (base >= nk) break;
        const int bend = base + 128 < pad8 ? base + 128 : pad8;
        for (int t = base; t < bend; t += 8) {
            const s16x8 v8 = *(const s16x8*)(vrow + t);
            const f32x4 p0 = *(const f32x4*)&sc[t];
            const f32x4 p1 = *(const f32x4*)&sc[t + 4];
            a0 += p0.x * bf2f((unsigned short)v8[0]) + p0.y * bf2f((unsigned short)v8[1])
                + p0.z * bf2f((unsigned short)v8[2]) + p0.w * bf2f((unsigned short)v8[3]);
            a1 += p1.x * bf2f((unsigned short)v8[4]) + p1.y * bf2f((unsigned short)v8[5])
                + p1.z * bf2f((unsigned short)v8[6]) + p1.w * bf2f((unsigned short)v8[7]);
        }
    }
    part[qtr][d] = a0 + a1;
    __syncthreads();
    if (tid < HD)
        sel_out[((size_t)(bh * U_SEL + u)) * HD + tid] =
            (part[0][tid] + part[1][tid] + part[2][tid] + part[3][tid]) / l;
}

// ---------------------------------------------------------------------------
__global__ __launch_bounds__(256) void init_out(
    float* __restrict__ out, const float* __restrict__ bo)
{
    const size_t i = (size_t)blockIdx.x * 256 + threadIdx.x;
    out[i] = bo[i & (D_MODEL - 1)];
}

__global__ __launch_bounds__(256) void scatter_proj(
    const float* __restrict__ sel_out, const int* __restrict__ idx,
    const float* __restrict__ Wo, float* __restrict__ out)
{
    const int bh = blockIdx.x;
    const int ui = blockIdx.y;
    const int b = bh >> 4, h = bh & 15;
    const int t = idx[bh * U_SEL + ui];
    const int tid = threadIdx.x;

    __shared__ float s[HD];
    if (tid < HD) s[tid] = sel_out[((size_t)(bh * U_SEL + ui)) * HD + tid];
    __syncthreads();

    const int c0 = tid * 4;
    float a0 = 0.f, a1 = 0.f, a2 = 0.f, a3 = 0.f;
    #pragma unroll 8
    for (int r = 0; r < HD; ++r) {
        const float sv = s[r];
        const f32x4 w4 = *(const f32x4*)&Wo[((size_t)(h * HD + r)) * D_MODEL + c0];
        a0 += sv * w4.x; a1 += sv * w4.y; a2 += sv * w4.z; a3 += sv * w4.w;
    }
    float* op = &out[((size_t)(b * T_SEQ + t)) * D_MODEL + c0];
    atomicAdd(&op[0], a0);
    atomicAdd(&op[1], a1);
    atomicAdd(&op[2], a2);
    atomicAdd(&op[3], a3);
}

// ---------------------------------------------------------------------------
extern "C" void kernel_launch(void* const* d_in, const int* in_sizes, int n_in,
                              void* d_out, int out_size, void* d_ws, size_t ws_size,
                              hipStream_t stream)
{
    const float* x  = (const float*)d_in[0];
    const float* Wq = (const float*)d_in[1];
    const float* bq = (const float*)d_in[2];
    const float* Wk = (const float*)d_in[3];
    const float* bk = (const float*)d_in[4];
    const float* Wv = (const float*)d_in[5];
    const float* bv = (const float*)d_in[6];
    const float* Wo = (const float*)d_in[7];
    const float* bo = (const float*)d_in[8];
    float* out = (float*)d_out;

    // workspace layout (~31 MB)
    char* ws = (char*)d_ws;
    ushort_t* xh      = (ushort_t*)(ws);                              //  8 MB
    ushort_t* wqhT    = (ushort_t*)(ws + (8u << 20));                 //  2 MB
    ushort_t* wkhT    = (ushort_t*)(ws + (10u << 20));                //  2 MB
    ushort_t* wvhT    = (ushort_t*)(ws + (12u << 20));                //  2 MB
    ushort_t* k       = (ushort_t*)(ws + (14u << 20));                //  8 MB
    ushort_t* vT      = (ushort_t*)(ws + (22u << 20));                //  8 MB
    float*    norms   = (float*)(ws + (30u << 20));                   // 256 KB
    int*      cand_t  = (int*)(ws + (30u << 20) + (256u << 10));      // 12 KB
    int*      cand_cnt= (int*)(ws + (30u << 20) + (272u << 10));      // 128 B
    float*    n_exact = (float*)(ws + (30u << 20) + (276u << 10));    // 12 KB
    int*      idx     = (int*)(ws + (30u << 20) + (292u << 10));      // ~5 KB
    float*    sel_out = (float*)(ws + (30u << 20) + (300u << 10));    // 304 KB
    float*    q       = (float*)d_out;   // Q lives in d_out until init_out

    prep<<<2048 + 768, 256, 0, stream>>>(x, Wq, Wk, Wv, xh, wqhT, wkhT, wvhT);
    {
        dim3 g((NB * T_SEQ) / GBM, D_MODEL / GBN, 3);
        qkv_mfma<<<g, 256, 0, stream>>>(xh, wqhT, wkhT, wvhT, bq, bk, bv, q, k, vT);
    }
    q_norms<<<256, 256, 0, stream>>>(q, norms);
    topk_select<<<NB * NH, 256, 0, stream>>>(norms, cand_t, cand_cnt);
    {
        dim3 g(NB * NH, CAND_CAP);
        fixup_norms<<<g, 256, 0, stream>>>(x, Wq, bq, cand_t, cand_cnt, n_exact);
    }
    fixup_select<<<NB * NH, 256, 0, stream>>>(n_exact, cand_t, cand_cnt, idx);
    {
        dim3 g(NB * NH, U_SEL);
        attn_fused<<<g, 256, 0, stream>>>(q, k, vT, idx, sel_out);
    }
    init_out<<<(NB * T_SEQ * D_MODEL) / 256, 256, 0, stream>>>(out, bo);
    {
        dim3 g(NB * NH, U_SEL);
        scatter_proj<<<g, 256, 0, stream>>>(sel_out, idx, Wo, out);
    }
}

// Round 8
// 210.761 us; speedup vs baseline: 1.2728x; 1.1208x over previous
//
#include <hip/hip_runtime.h>

#define NB 2
#define T_SEQ 2048
#define D_MODEL 1024
#define NH 16
#define HD 64
#define U_SEL 38
#define CAND_CAP 96

typedef __attribute__((ext_vector_type(8))) short s16x8;
typedef __attribute__((ext_vector_type(4))) short s16x4;
typedef __attribute__((ext_vector_type(4))) float f32x4;
typedef unsigned short ushort_t;

__device__ __forceinline__ unsigned short f2bf(float f) {
    unsigned u = __float_as_uint(f);
    u += 0x7FFFu + ((u >> 16) & 1u);          // RNE
    return (unsigned short)(u >> 16);
}
__device__ __forceinline__ float bf2f(unsigned short h) {
    return __uint_as_float(((unsigned)h) << 16);
}

__device__ __forceinline__ void async_copy16(const void* g, void* l) {
    __builtin_amdgcn_global_load_lds(
        (const __attribute__((address_space(1))) void*)g,
        (__attribute__((address_space(3))) void*)l, 16, 0, 0);
}

// ---------------------------------------------------------------------------
// prep: blocks [0,2048): x -> xh (bf16). blocks [2048,2816): W -> W^T bf16.
// ---------------------------------------------------------------------------
__global__ __launch_bounds__(256) void prep(
    const float* __restrict__ x,
    const float* __restrict__ Wq, const float* __restrict__ Wk, const float* __restrict__ Wv,
    ushort_t* __restrict__ xh,
    ushort_t* __restrict__ wqhT, ushort_t* __restrict__ wkhT, ushort_t* __restrict__ wvhT)
{
    __shared__ float T[64][68];
    const int tid = threadIdx.x;
    if (blockIdx.x < 2048) {
        const size_t i0 = ((size_t)blockIdx.x * 256 + tid) * 8;
        const f32x4 a = *(const f32x4*)(x + i0);
        const f32x4 b = *(const f32x4*)(x + i0 + 4);
        const float f[8] = {a.x, a.y, a.z, a.w, b.x, b.y, b.z, b.w};
        s16x8 hi;
        #pragma unroll
        for (int e = 0; e < 8; ++e) hi[e] = (short)f2bf(f[e]);
        *(s16x8*)(xh + i0) = hi;
        return;
    }
    const int id2 = blockIdx.x - 2048;
    const int z = id2 >> 8;
    const int rem = id2 & 255;
    const int k0 = (rem & 15) * 64, n0 = (rem >> 4) * 64;
    const float* W = (z == 0) ? Wq : (z == 1) ? Wk : Wv;

    #pragma unroll
    for (int i = 0; i < 4; ++i) {
        const int r = (tid >> 4) + i * 16, c = (tid & 15) * 4;
        *(f32x4*)&T[r][c] = *(const f32x4*)&W[(size_t)(k0 + r) * D_MODEL + n0 + c];
    }
    __syncthreads();

    const int n = tid >> 2, kq = (tid & 3) * 16;
    s16x8 hi0, hi1;
    #pragma unroll
    for (int j = 0; j < 16; ++j) {
        const float f = T[kq + j][n];
        if (j < 8) hi0[j] = (short)f2bf(f);
        else       hi1[j - 8] = (short)f2bf(f);
    }
    ushort_t* oh = (z == 0) ? wqhT : (z == 1) ? wkhT : wvhT;
    const size_t ob = (size_t)(n0 + n) * D_MODEL + k0 + kq;
    *(s16x8*)(oh + ob) = hi0;
    *(s16x8*)(oh + ob + 8) = hi1;
}

// ---------------------------------------------------------------------------
// qkv_mfma: 128x128 tile, BK=32, 4 waves, global_load_lds width 16.
// Three uniform 32-step jobs: z0 Q=xh@WqhT -> f32 (+bq);  z1 K bf16 (+bk);
// z2 V -> vT bf16 transposed [bh*64+d][t] (+bv).
// ---------------------------------------------------------------------------
#define GBM 128
#define GBN 128
#define GBK 32

__global__ __launch_bounds__(256) void qkv_mfma(
    const ushort_t* __restrict__ xh,
    const ushort_t* __restrict__ wqhT, const ushort_t* __restrict__ wkhT,
    const ushort_t* __restrict__ wvhT,
    const float* __restrict__ bq, const float* __restrict__ bk, const float* __restrict__ bv,
    float* __restrict__ qo, ushort_t* __restrict__ ko, ushort_t* __restrict__ vT)
{
    const int z = blockIdx.z;
    __shared__ ushort_t Ah[GBM * GBK];
    __shared__ ushort_t Bh[GBN * GBK];

    const int tid = threadIdx.x;
    const int lane = tid & 63;
    const int wid = tid >> 6;
    const int wr = wid >> 1, wc = wid & 1;
    const size_t rowBase = (size_t)blockIdx.x * GBM;
    const size_t colBase = (size_t)blockIdx.y * GBN;

    const ushort_t* B0 = (z == 0) ? wqhT : (z == 1) ? wkhT : wvhT;
    const int srow = tid >> 2;
    const int skq  = (tid & 3) * 8;

    f32x4 acc[4][4] = {};

    for (int kk = 0; kk < 32; ++kk) {
        const int k0 = kk * GBK;
        async_copy16(xh + (rowBase + srow) * D_MODEL + k0 + skq,      &Ah[tid * 8]);
        async_copy16(xh + (rowBase + 64 + srow) * D_MODEL + k0 + skq, &Ah[2048 + tid * 8]);
        async_copy16(B0 + (colBase + srow) * D_MODEL + k0 + skq,      &Bh[tid * 8]);
        async_copy16(B0 + (colBase + 64 + srow) * D_MODEL + k0 + skq, &Bh[2048 + tid * 8]);
        __syncthreads();

        s16x8 af[4], bf[4];
        #pragma unroll
        for (int i = 0; i < 4; ++i)
            af[i] = *(const s16x8*)&Ah[(wr * 64 + i * 16 + (lane & 15)) * GBK + (lane >> 4) * 8];
        #pragma unroll
        for (int j = 0; j < 4; ++j)
            bf[j] = *(const s16x8*)&Bh[(wc * 64 + j * 16 + (lane & 15)) * GBK + (lane >> 4) * 8];
        #pragma unroll
        for (int i = 0; i < 4; ++i)
            #pragma unroll
            for (int j = 0; j < 4; ++j)
                acc[i][j] = __builtin_amdgcn_mfma_f32_16x16x32_bf16(af[i], bf[j], acc[i][j], 0, 0, 0);
        __syncthreads();
    }

    // epilogue: C/D layout col=lane&15, row=(lane>>4)*4+r
    const int cB = (int)colBase + wc * 64 + (lane & 15);
    const int rL = wr * 64 + ((lane >> 4) << 2);
    const int rB = (int)rowBase + rL;
    if (z == 0) {
        #pragma unroll
        for (int j = 0; j < 4; ++j) {
            const float bj = bq[cB + j * 16];
            #pragma unroll
            for (int i = 0; i < 4; ++i)
                #pragma unroll
                for (int r = 0; r < 4; ++r)
                    qo[(size_t)(rB + i * 16 + r) * D_MODEL + cB + j * 16] = acc[i][j][r] + bj;
        }
    } else if (z == 1) {
        #pragma unroll
        for (int j = 0; j < 4; ++j) {
            const float bj = bk[cB + j * 16];
            #pragma unroll
            for (int i = 0; i < 4; ++i)
                #pragma unroll
                for (int r = 0; r < 4; ++r)
                    ko[(size_t)(rB + i * 16 + r) * D_MODEL + cB + j * 16] = f2bf(acc[i][j][r] + bj);
        }
    } else {
        const int bb = (int)(rowBase >> 11);
        const int tBase = (int)(rowBase & (T_SEQ - 1)) + rL;
        #pragma unroll
        for (int j = 0; j < 4; ++j) {
            const int dg = cB + j * 16;
            const float bj = bv[dg];
            ushort_t* vrow = vT + ((size_t)(bb * NH) * HD + dg) * T_SEQ;
            #pragma unroll
            for (int i = 0; i < 4; ++i) {
                s16x4 pk;
                #pragma unroll
                for (int r = 0; r < 4; ++r)
                    pk[r] = (short)f2bf(acc[i][j][r] + bj);
                *(s16x4*)&vrow[tBase + i * 16] = pk;
            }
        }
    }
}

// ---------------------------------------------------------------------------
// q_norms: approximate L1 norms from the f32 Q buffer.
// ---------------------------------------------------------------------------
__global__ __launch_bounds__(256) void q_norms(
    const float* __restrict__ qo, float* __restrict__ norms)
{
    const int gid = blockIdx.x * 256 + threadIdx.x;     // 0..65535
    const int h = gid & 15;
    const int t = (gid >> 4) & (T_SEQ - 1);
    const int b = gid >> 15;
    const float* qr = qo + ((size_t)(b * T_SEQ + t)) * D_MODEL + h * HD;
    float s = 0.f;
    #pragma unroll
    for (int d0 = 0; d0 < HD; d0 += 4) {
        const f32x4 a = *(const f32x4*)(qr + d0);
        s += fabsf(a.x) + fabsf(a.y) + fabsf(a.z) + fabsf(a.w);
    }
    norms[(size_t)(b * NH + h) * T_SEQ + t] = s;
}

// ---------------------------------------------------------------------------
// topk_select: 3-pass radix gives v38 (38th largest approx norm); emit the
// candidate band {t : norm >= v38 - 0.4} (conservative vs bf16 norm error).
// ---------------------------------------------------------------------------
__global__ __launch_bounds__(256) void topk_select(
    const float* __restrict__ norms, int* __restrict__ cand_t, int* __restrict__ cand_cnt)
{
    const int bh = blockIdx.x;
    const int tid = threadIdx.x;
    const int lane = tid & 63;
    const int w = tid >> 6;

    __shared__ unsigned keys[T_SEQ];
    __shared__ unsigned hist[2048];
    __shared__ unsigned wsum[4];
    __shared__ unsigned bc_bin, bc_above;
    __shared__ int cnt;

    const float* nr = norms + (size_t)bh * T_SEQ;
    #pragma unroll
    for (int j = 0; j < 8; ++j)
        keys[tid + j * 256] = __float_as_uint(nr[tid + j * 256]);

    const int  shifts[3] = {21, 10, 0};
    const unsigned binm[3]  = {0x7FFu, 0x7FFu, 0x3FFu};
    const unsigned prefm[3] = {0x00000000u, 0xFFE00000u, 0xFFFFFC00u};

    unsigned prefix = 0;
    unsigned K_rem = U_SEL;

    for (int p = 0; p < 3; ++p) {
        #pragma unroll
        for (int j = 0; j < 8; ++j) hist[tid + j * 256] = 0;
        __syncthreads();
        #pragma unroll
        for (int j = 0; j < 8; ++j) {
            const unsigned k = keys[tid + j * 256];
            if ((k & prefm[p]) == prefix)
                atomicAdd(&hist[(k >> shifts[p]) & binm[p]], 1u);
        }
        __syncthreads();

        unsigned s = 0;
        #pragma unroll
        for (int e = 0; e < 8; ++e) s += hist[tid * 8 + e];
        unsigned v = s;
        #pragma unroll
        for (int off = 1; off < 64; off <<= 1) {
            const unsigned o = __shfl_down((int)v, off);
            if (lane + off < 64) v += o;
        }
        if (lane == 0) wsum[w] = v;
        __syncthreads();
        unsigned suf = v;
        for (int ww = w + 1; ww < 4; ++ww) suf += wsum[ww];
        const unsigned suf_next = suf - s;

        if (suf >= K_rem && suf_next < K_rem) {
            unsigned acc = suf_next;
            #pragma unroll
            for (int e = 7; e >= 0; --e) {
                const unsigned nb = hist[tid * 8 + e];
                if (acc + nb >= K_rem) { bc_bin = tid * 8 + e; bc_above = acc; break; }
                acc += nb;
            }
        }
        __syncthreads();
        prefix |= bc_bin << shifts[p];
        K_rem -= bc_above;
        __syncthreads();
    }

    const float thr = __uint_as_float(prefix) - 0.4f;
    if (tid == 0) cnt = 0;
    __syncthreads();
    #pragma unroll
    for (int j = 0; j < 8; ++j) {
        const int i = tid + j * 256;
        if (__uint_as_float(keys[i]) >= thr) {
            const int s = atomicAdd(&cnt, 1);
            if (s < CAND_CAP) cand_t[bh * CAND_CAP + s] = i;
        }
    }
    __syncthreads();
    if (tid == 0) cand_cnt[bh] = cnt < CAND_CAP ? cnt : CAND_CAP;
}

// ---------------------------------------------------------------------------
// fixup_norms: one block per (bh, candidate). Exact f32 q-row norm from x, Wq.
// ---------------------------------------------------------------------------
__global__ __launch_bounds__(256) void fixup_norms(
    const float* __restrict__ x, const float* __restrict__ Wq,
    const float* __restrict__ bq, const int* __restrict__ cand_t,
    const int* __restrict__ cand_cnt, float* __restrict__ n_exact)
{
    const int bh = blockIdx.x, c = blockIdx.y;
    const int b = bh >> 4, h = bh & 15;
    if (c >= cand_cnt[bh]) return;
    const int t = cand_t[bh * CAND_CAP + c];
    const int tid = threadIdx.x, d = tid & 63, kq = tid >> 6;

    __shared__ float xs[D_MODEL];
    __shared__ float part[4][HD];

    *(f32x4*)&xs[tid * 4] = *(const f32x4*)&x[((size_t)(b * T_SEQ + t)) * D_MODEL + tid * 4];
    __syncthreads();

    const float* wp = Wq + (size_t)(kq * 256) * D_MODEL + h * HD + d;
    const float* xp = &xs[kq * 256];
    float a0 = 0.f, a1 = 0.f, a2 = 0.f, a3 = 0.f;
    #pragma unroll 4
    for (int k = 0; k < 256; k += 4) {
        a0 += xp[k]     * wp[(k)     * D_MODEL];
        a1 += xp[k + 1] * wp[(k + 1) * D_MODEL];
        a2 += xp[k + 2] * wp[(k + 2) * D_MODEL];
        a3 += xp[k + 3] * wp[(k + 3) * D_MODEL];
    }
    part[kq][d] = (a0 + a1) + (a2 + a3);
    __syncthreads();
    if (tid < 64) {
        float v = fabsf(part[0][tid] + part[1][tid] + part[2][tid] + part[3][tid]
                        + bq[h * HD + tid]);
        #pragma unroll
        for (int off = 1; off < 64; off <<= 1) v += __shfl_xor(v, off);
        if (tid == 0) n_exact[bh * CAND_CAP + c] = v;
    }
}

// ---------------------------------------------------------------------------
// fixup_select: top-38 among candidates by (exact norm, -t). Deterministic.
// ---------------------------------------------------------------------------
__global__ __launch_bounds__(256) void fixup_select(
    const float* __restrict__ n_exact, const int* __restrict__ cand_t,
    const int* __restrict__ cand_cnt, int* __restrict__ idx_out)
{
    const int bh = blockIdx.x;
    const int tid = threadIdx.x, lane = tid & 63, w = tid >> 6;
    const int nc = cand_cnt[bh];

    __shared__ float nv[CAND_CAP];
    __shared__ int   tv[CAND_CAP];
    __shared__ float wv[4]; __shared__ int wt[4]; __shared__ int wsl[4];

    if (tid < CAND_CAP) {
        nv[tid] = (tid < nc) ? n_exact[bh * CAND_CAP + tid] : -1e30f;
        tv[tid] = (tid < nc) ? cand_t[bh * CAND_CAP + tid] : 0x7FFFFFFF;
    }
    __syncthreads();

    for (int r = 0; r < U_SEL; ++r) {
        float v; int t, sl;
        if (tid < CAND_CAP) { v = nv[tid]; t = tv[tid]; sl = tid; }
        else { v = -1e30f; t = 0x7FFFFFFF; sl = 0; }
        #pragma unroll
        for (int off = 1; off < 64; off <<= 1) {
            const float ov = __shfl_xor(v, off);
            const int   ot = __shfl_xor(t, off);
            const int   osl = __shfl_xor(sl, off);
            if (ov > v || (ov == v && ot < t)) { v = ov; t = ot; sl = osl; }
        }
        if (lane == 0) { wv[w] = v; wt[w] = t; wsl[w] = sl; }
        __syncthreads();
        if (tid == 0) {
            float bvv = wv[0]; int btt = wt[0]; int bsl = wsl[0];
            #pragma unroll
            for (int ww = 1; ww < 4; ++ww)
                if (wv[ww] > bvv || (wv[ww] == bvv && wt[ww] < btt)) {
                    bvv = wv[ww]; btt = wt[ww]; bsl = wsl[ww];
                }
            idx_out[bh * U_SEL + r] = btt;
            nv[bsl] = -1e30f;
        }
        __syncthreads();
    }
}

// ---------------------------------------------------------------------------
// attn_scores: S[bh][u][t] = (q_sel . k_t) for t <= qi (q pre-scaled).
// Grid (32 bh, 8 t-chunks, 2 u-groups of 19). One thread per key row; K row
// held in 64 VGPRs, reused across the group's 19 queries (deep ILP).
// ---------------------------------------------------------------------------
__global__ __launch_bounds__(256) void attn_scores(
    const float* __restrict__ q, const ushort_t* __restrict__ kk_,
    const int* __restrict__ idx, float* __restrict__ S)
{
    const int bh = blockIdx.x, ch = blockIdx.y, ug = blockIdx.z;
    const int b = bh >> 4, h = bh & 15;
    const int tid = threadIdx.x;
    const int t = ch * 256 + tid;
    const int u0 = ug * 19;

    __shared__ float qs[19][HD];
    __shared__ int qis[19];

    if (tid < 19) qis[tid] = idx[bh * U_SEL + u0 + tid];
    __syncthreads();
    for (int e = tid; e < 19 * HD; e += 256) {
        const int u = e >> 6, d = e & 63;
        qs[u][d] = q[((size_t)(b * T_SEQ + qis[u])) * D_MODEL + h * HD + d] * 0.125f;
    }

    float kr[64];
    {
        const ushort_t* kp = kk_ + ((size_t)(b * T_SEQ + t)) * D_MODEL + h * HD;
        #pragma unroll
        for (int d0 = 0; d0 < 64; d0 += 8) {
            const s16x8 r = *(const s16x8*)(kp + d0);
            #pragma unroll
            for (int e = 0; e < 8; ++e) kr[d0 + e] = bf2f((unsigned short)r[e]);
        }
    }
    __syncthreads();

    const int wbase = ch * 256 + (tid & ~63);   // wave's min t (uniform)
    for (int uu = 0; uu < 19; ++uu) {
        const int qi = qis[uu];
        if (wbase > qi) continue;               // wave-uniform skip
        float sp0 = 0.f, sp1 = 0.f, sp2 = 0.f, sp3 = 0.f;
        #pragma unroll
        for (int d0 = 0; d0 < 64; d0 += 16) {
            const f32x4 q0 = *(const f32x4*)&qs[uu][d0];
            const f32x4 q1 = *(const f32x4*)&qs[uu][d0 + 4];
            const f32x4 q2 = *(const f32x4*)&qs[uu][d0 + 8];
            const f32x4 q3 = *(const f32x4*)&qs[uu][d0 + 12];
            sp0 += q0.x * kr[d0] + q0.y * kr[d0 + 1] + q0.z * kr[d0 + 2] + q0.w * kr[d0 + 3];
            sp1 += q1.x * kr[d0 + 4] + q1.y * kr[d0 + 5] + q1.z * kr[d0 + 6] + q1.w * kr[d0 + 7];
            sp2 += q2.x * kr[d0 + 8] + q2.y * kr[d0 + 9] + q2.z * kr[d0 + 10] + q2.w * kr[d0 + 11];
            sp3 += q3.x * kr[d0 + 12] + q3.y * kr[d0 + 13] + q3.z * kr[d0 + 14] + q3.w * kr[d0 + 15];
        }
        S[((size_t)(bh * U_SEL + u0 + uu)) * T_SEQ + t] = sp0 + sp1 + sp2 + sp3;
    }
}

// ---------------------------------------------------------------------------
// attn_pv: one block per (bh,u). Softmax over S[0..qi] (LDS), PV along the
// contiguous t axis of transposed V.
// ---------------------------------------------------------------------------
__global__ __launch_bounds__(256) void attn_pv(
    const float* __restrict__ S, const ushort_t* __restrict__ vT,
    const int* __restrict__ idx, float* __restrict__ sel_out)
{
    const int bh = blockIdx.x, u = blockIdx.y;
    const int tid = threadIdx.x;
    const int d = tid & 63;
    const int qtr = tid >> 6;
    const int qi = idx[bh * U_SEL + u];
    const int nk = qi + 1;
    const int pad8 = (nk + 7) & ~7;
    const float* Srow = S + ((size_t)(bh * U_SEL + u)) * T_SEQ;

    __shared__ float sc[T_SEQ];
    __shared__ float red[256];
    __shared__ float part[4][HD];

    float lm = -1e30f;
    for (int t = tid; t < nk; t += 256) { const float s = Srow[t]; sc[t] = s; lm = fmaxf(lm, s); }
    red[tid] = lm;
    __syncthreads();
    for (int s = 128; s > 0; s >>= 1) {
        if (tid < s) red[tid] = fmaxf(red[tid], red[tid + s]);
        __syncthreads();
    }
    const float m = red[0];
    __syncthreads();

    float ls = 0.f;
    for (int t = tid; t < nk; t += 256) { const float p = __expf(sc[t] - m); sc[t] = p; ls += p; }
    if (tid < 7) { const int t = nk + tid; if (t < pad8) sc[t] = 0.f; }
    red[tid] = ls;
    __syncthreads();
    for (int s = 128; s > 0; s >>= 1) {
        if (tid < s) red[tid] += red[tid + s];
        __syncthreads();
    }
    const float l = red[0];

    const ushort_t* vrow = vT + ((size_t)(bh * HD + d)) * T_SEQ;
    float a0 = 0.f, a1 = 0.f;
    #pragma unroll
    for (int mm = 0; mm < 4; ++mm) {
        const int base = mm * 512 + qtr * 128;
        if (base >= nk) break;
        const int bend = base + 128 < pad8 ? base + 128 : pad8;
        for (int t = base; t < bend; t += 8) {
            const s16x8 v8 = *(const s16x8*)(vrow + t);
            const f32x4 p0 = *(const f32x4*)&sc[t];
            const f32x4 p1 = *(const f32x4*)&sc[t + 4];
            a0 += p0.x * bf2f((unsigned short)v8[0]) + p0.y * bf2f((unsigned short)v8[1])
                + p0.z * bf2f((unsigned short)v8[2]) + p0.w * bf2f((unsigned short)v8[3]);
            a1 += p1.x * bf2f((unsigned short)v8[4]) + p1.y * bf2f((unsigned short)v8[5])
                + p1.z * bf2f((unsigned short)v8[6]) + p1.w * bf2f((unsigned short)v8[7]);
        }
    }
    part[qtr][d] = a0 + a1;
    __syncthreads();
    if (tid < HD)
        sel_out[((size_t)(bh * U_SEL + u)) * HD + tid] =
            (part[0][tid] + part[1][tid] + part[2][tid] + part[3][tid]) / l;
}

// ---------------------------------------------------------------------------
__global__ __launch_bounds__(256) void init_out(
    float* __restrict__ out, const float* __restrict__ bo)
{
    const size_t i = (size_t)blockIdx.x * 256 + threadIdx.x;
    out[i] = bo[i & (D_MODEL - 1)];
}

__global__ __launch_bounds__(256) void scatter_proj(
    const float* __restrict__ sel_out, const int* __restrict__ idx,
    const float* __restrict__ Wo, float* __restrict__ out)
{
    const int bh = blockIdx.x;
    const int ui = blockIdx.y;
    const int b = bh >> 4, h = bh & 15;
    const int t = idx[bh * U_SEL + ui];
    const int tid = threadIdx.x;

    __shared__ float s[HD];
    if (tid < HD) s[tid] = sel_out[((size_t)(bh * U_SEL + ui)) * HD + tid];
    __syncthreads();

    const int c0 = tid * 4;
    float a0 = 0.f, a1 = 0.f, a2 = 0.f, a3 = 0.f;
    #pragma unroll 8
    for (int r = 0; r < HD; ++r) {
        const float sv = s[r];
        const f32x4 w4 = *(const f32x4*)&Wo[((size_t)(h * HD + r)) * D_MODEL + c0];
        a0 += sv * w4.x; a1 += sv * w4.y; a2 += sv * w4.z; a3 += sv * w4.w;
    }
    float* op = &out[((size_t)(b * T_SEQ + t)) * D_MODEL + c0];
    atomicAdd(&op[0], a0);
    atomicAdd(&op[1], a1);
    atomicAdd(&op[2], a2);
    atomicAdd(&op[3], a3);
}

// ---------------------------------------------------------------------------
extern "C" void kernel_launch(void* const* d_in, const int* in_sizes, int n_in,
                              void* d_out, int out_size, void* d_ws, size_t ws_size,
                              hipStream_t stream)
{
    const float* x  = (const float*)d_in[0];
    const float* Wq = (const float*)d_in[1];
    const float* bq = (const float*)d_in[2];
    const float* Wk = (const float*)d_in[3];
    const float* bk = (const float*)d_in[4];
    const float* Wv = (const float*)d_in[5];
    const float* bv = (const float*)d_in[6];
    const float* Wo = (const float*)d_in[7];
    const float* bo = (const float*)d_in[8];
    float* out = (float*)d_out;

    // workspace layout (~41 MB; ws >= 58 MB proven in round 5)
    char* ws = (char*)d_ws;
    ushort_t* xh      = (ushort_t*)(ws);                              //  8 MB
    ushort_t* wqhT    = (ushort_t*)(ws + (8u << 20));                 //  2 MB
    ushort_t* wkhT    = (ushort_t*)(ws + (10u << 20));                //  2 MB
    ushort_t* wvhT    = (ushort_t*)(ws + (12u << 20));                //  2 MB
    ushort_t* k       = (ushort_t*)(ws + (14u << 20));                //  8 MB
    ushort_t* vT      = (ushort_t*)(ws + (22u << 20));                //  8 MB
    float*    norms   = (float*)(ws + (30u << 20));                   // 256 KB
    int*      cand_t  = (int*)(ws + (30u << 20) + (256u << 10));      // 12 KB
    int*      cand_cnt= (int*)(ws + (30u << 20) + (272u << 10));      // 128 B
    float*    n_exact = (float*)(ws + (30u << 20) + (276u << 10));    // 12 KB
    int*      idx     = (int*)(ws + (30u << 20) + (292u << 10));      // ~5 KB
    float*    sel_out = (float*)(ws + (30u << 20) + (300u << 10));    // 304 KB
    float*    S       = (float*)(ws + (31u << 20));                   // 10 MB
    float*    q       = (float*)d_out;   // Q lives in d_out until init_out

    prep<<<2048 + 768, 256, 0, stream>>>(x, Wq, Wk, Wv, xh, wqhT, wkhT, wvhT);
    {
        dim3 g((NB * T_SEQ) / GBM, D_MODEL / GBN, 3);
        qkv_mfma<<<g, 256, 0, stream>>>(xh, wqhT, wkhT, wvhT, bq, bk, bv, q, k, vT);
    }
    q_norms<<<256, 256, 0, stream>>>(q, norms);
    topk_select<<<NB * NH, 256, 0, stream>>>(norms, cand_t, cand_cnt);
    {
        dim3 g(NB * NH, CAND_CAP);
        fixup_norms<<<g, 256, 0, stream>>>(x, Wq, bq, cand_t, cand_cnt, n_exact);
    }
    fixup_select<<<NB * NH, 256, 0, stream>>>(n_exact, cand_t, cand_cnt, idx);
    {
        dim3 g(NB * NH, T_SEQ / 256, 2);
        attn_scores<<<g, 256, 0, stream>>>(q, k, idx, S);
    }
    {
        dim3 g(NB * NH, U_SEL);
        attn_pv<<<g, 256, 0, stream>>>(S, vT, idx, sel_out);
    }
    init_out<<<(NB * T_SEQ * D_MODEL) / 256, 256, 0, stream>>>(out, bo);
    {
        dim3 g(NB * NH, U_SEL);
        scatter_proj<<<g, 256, 0, stream>>>(sel_out, idx, Wo, out);
    }
}

// Round 9
// 204.263 us; speedup vs baseline: 1.3133x; 1.0318x over previous
//
#include <hip/hip_runtime.h>

#define NB 2
#define T_SEQ 2048
#define D_MODEL 1024
#define NH 16
#define HD 64
#define U_SEL 38
#define CAND_CAP 96

typedef __attribute__((ext_vector_type(8))) short s16x8;
typedef __attribute__((ext_vector_type(4))) short s16x4;
typedef __attribute__((ext_vector_type(4))) float f32x4;
typedef unsigned short ushort_t;

__device__ __forceinline__ unsigned short f2bf(float f) {
    unsigned u = __float_as_uint(f);
    u += 0x7FFFu + ((u >> 16) & 1u);          // RNE
    return (unsigned short)(u >> 16);
}
__device__ __forceinline__ float bf2f(unsigned short h) {
    return __uint_as_float(((unsigned)h) << 16);
}

__device__ __forceinline__ void async_copy16(const void* g, void* l) {
    __builtin_amdgcn_global_load_lds(
        (const __attribute__((address_space(1))) void*)g,
        (__attribute__((address_space(3))) void*)l, 16, 0, 0);
}

// ---------------------------------------------------------------------------
// prep: blocks [0,2048): x -> xh (bf16). blocks [2048,2816): W -> W^T bf16.
// ---------------------------------------------------------------------------
__global__ __launch_bounds__(256) void prep(
    const float* __restrict__ x,
    const float* __restrict__ Wq, const float* __restrict__ Wk, const float* __restrict__ Wv,
    ushort_t* __restrict__ xh,
    ushort_t* __restrict__ wqhT, ushort_t* __restrict__ wkhT, ushort_t* __restrict__ wvhT)
{
    __shared__ float T[64][68];
    const int tid = threadIdx.x;
    if (blockIdx.x < 2048) {
        const size_t i0 = ((size_t)blockIdx.x * 256 + tid) * 8;
        const f32x4 a = *(const f32x4*)(x + i0);
        const f32x4 b = *(const f32x4*)(x + i0 + 4);
        const float f[8] = {a.x, a.y, a.z, a.w, b.x, b.y, b.z, b.w};
        s16x8 hi;
        #pragma unroll
        for (int e = 0; e < 8; ++e) hi[e] = (short)f2bf(f[e]);
        *(s16x8*)(xh + i0) = hi;
        return;
    }
    const int id2 = blockIdx.x - 2048;
    const int z = id2 >> 8;
    const int rem = id2 & 255;
    const int k0 = (rem & 15) * 64, n0 = (rem >> 4) * 64;
    const float* W = (z == 0) ? Wq : (z == 1) ? Wk : Wv;

    #pragma unroll
    for (int i = 0; i < 4; ++i) {
        const int r = (tid >> 4) + i * 16, c = (tid & 15) * 4;
        *(f32x4*)&T[r][c] = *(const f32x4*)&W[(size_t)(k0 + r) * D_MODEL + n0 + c];
    }
    __syncthreads();

    const int n = tid >> 2, kq = (tid & 3) * 16;
    s16x8 hi0, hi1;
    #pragma unroll
    for (int j = 0; j < 16; ++j) {
        const float f = T[kq + j][n];
        if (j < 8) hi0[j] = (short)f2bf(f);
        else       hi1[j - 8] = (short)f2bf(f);
    }
    ushort_t* oh = (z == 0) ? wqhT : (z == 1) ? wkhT : wvhT;
    const size_t ob = (size_t)(n0 + n) * D_MODEL + k0 + kq;
    *(s16x8*)(oh + ob) = hi0;
    *(s16x8*)(oh + ob + 8) = hi1;
}

// ---------------------------------------------------------------------------
// qkv_mfma: 128x128 tile, BK=32, 4 waves, global_load_lds width 16 with
// pre-swizzled SOURCE (slot' = (slot + row/2) & 3 -> 2-way LDS conflicts).
//  z0: Q bf16 (+bq) AND per-(b,h,t) L1 norms from f32 accumulators.
//  z1: K bf16 (+bk).  z2: V -> vT bf16 transposed [bh*64+d][t] (+bv).
// ---------------------------------------------------------------------------
#define GBM 128
#define GBN 128
#define GBK 32

__global__ __launch_bounds__(256) void qkv_mfma(
    const ushort_t* __restrict__ xh,
    const ushort_t* __restrict__ wqhT, const ushort_t* __restrict__ wkhT,
    const ushort_t* __restrict__ wvhT,
    const float* __restrict__ bq, const float* __restrict__ bk, const float* __restrict__ bv,
    ushort_t* __restrict__ qb, ushort_t* __restrict__ ko, ushort_t* __restrict__ vT,
    float* __restrict__ norms)
{
    const int z = blockIdx.z;
    __shared__ ushort_t Ah[GBM * GBK];
    __shared__ ushort_t Bh[GBN * GBK];

    const int tid = threadIdx.x;
    const int lane = tid & 63;
    const int wid = tid >> 6;
    const int wr = wid >> 1, wc = wid & 1;
    const size_t rowBase = (size_t)blockIdx.x * GBM;
    const size_t colBase = (size_t)blockIdx.y * GBN;

    const ushort_t* B0 = (z == 0) ? wqhT : (z == 1) ? wkhT : wvhT;
    const int srow = tid >> 2;                       // 0..63
    const int sl0  = ((tid & 3) - (srow >> 1)) & 3;  // logical slot for this dest
    const int skq  = sl0 * 8;

    // read-side physical slots (per fragment row)
    int aph[4], bph[4];
    #pragma unroll
    for (int i = 0; i < 4; ++i) {
        const int arow = wr * 64 + i * 16 + (lane & 15);
        aph[i] = arow * GBK + ((((lane >> 4) + (arow >> 1)) & 3) << 3);
        const int brow = wc * 64 + i * 16 + (lane & 15);
        bph[i] = brow * GBK + ((((lane >> 4) + (brow >> 1)) & 3) << 3);
    }

    f32x4 acc[4][4] = {};

    for (int kk = 0; kk < 32; ++kk) {
        const int k0 = kk * GBK;
        async_copy16(xh + (rowBase + srow) * D_MODEL + k0 + skq,      &Ah[tid * 8]);
        async_copy16(xh + (rowBase + 64 + srow) * D_MODEL + k0 + skq, &Ah[2048 + tid * 8]);
        async_copy16(B0 + (colBase + srow) * D_MODEL + k0 + skq,      &Bh[tid * 8]);
        async_copy16(B0 + (colBase + 64 + srow) * D_MODEL + k0 + skq, &Bh[2048 + tid * 8]);
        __syncthreads();

        s16x8 af[4], bf[4];
        #pragma unroll
        for (int i = 0; i < 4; ++i) af[i] = *(const s16x8*)&Ah[aph[i]];
        #pragma unroll
        for (int j = 0; j < 4; ++j) bf[j] = *(const s16x8*)&Bh[bph[j]];
        #pragma unroll
        for (int i = 0; i < 4; ++i)
            #pragma unroll
            for (int j = 0; j < 4; ++j)
                acc[i][j] = __builtin_amdgcn_mfma_f32_16x16x32_bf16(af[i], bf[j], acc[i][j], 0, 0, 0);
        __syncthreads();
    }

    // epilogue: C/D layout col=lane&15, row=(lane>>4)*4+r
    const int cB = (int)colBase + wc * 64 + (lane & 15);
    const int rL = wr * 64 + ((lane >> 4) << 2);
    const int rB = (int)rowBase + rL;
    if (z == 0) {
        float bjv[4];
        #pragma unroll
        for (int j = 0; j < 4; ++j) bjv[j] = bq[cB + j * 16];
        // ---- fused L1 norms: sum |q| over this wave's head (64 cols) ----
        const int bb = (int)(rowBase >> 11);
        const int hw = cB >> 6;                      // head index (0..15)
        #pragma unroll
        for (int i = 0; i < 4; ++i) {
            float nr[4];
            #pragma unroll
            for (int r = 0; r < 4; ++r) {
                float s = 0.f;
                #pragma unroll
                for (int j = 0; j < 4; ++j) s += fabsf(acc[i][j][r] + bjv[j]);
                nr[r] = s;
            }
            #pragma unroll
            for (int off = 1; off < 16; off <<= 1) {
                #pragma unroll
                for (int r = 0; r < 4; ++r) nr[r] += __shfl_xor(nr[r], off);
            }
            if ((lane & 15) == 0) {
                const int trow = (int)(rowBase & (T_SEQ - 1)) + wr * 64 + i * 16 + ((lane >> 4) << 2);
                f32x4 nv; nv.x = nr[0]; nv.y = nr[1]; nv.z = nr[2]; nv.w = nr[3];
                *(f32x4*)&norms[(size_t)(bb * NH + hw) * T_SEQ + trow] = nv;
            }
        }
        // ---- Q store (bf16) ----
        #pragma unroll
        for (int j = 0; j < 4; ++j)
            #pragma unroll
            for (int i = 0; i < 4; ++i)
                #pragma unroll
                for (int r = 0; r < 4; ++r)
                    qb[(size_t)(rB + i * 16 + r) * D_MODEL + cB + j * 16] = f2bf(acc[i][j][r] + bjv[j]);
    } else if (z == 1) {
        #pragma unroll
        for (int j = 0; j < 4; ++j) {
            const float bj = bk[cB + j * 16];
            #pragma unroll
            for (int i = 0; i < 4; ++i)
                #pragma unroll
                for (int r = 0; r < 4; ++r)
                    ko[(size_t)(rB + i * 16 + r) * D_MODEL + cB + j * 16] = f2bf(acc[i][j][r] + bj);
        }
    } else {
        const int bb = (int)(rowBase >> 11);
        const int tBase = (int)(rowBase & (T_SEQ - 1)) + rL;
        #pragma unroll
        for (int j = 0; j < 4; ++j) {
            const int dg = cB + j * 16;
            const float bj = bv[dg];
            ushort_t* vrow = vT + ((size_t)(bb * NH) * HD + dg) * T_SEQ;
            #pragma unroll
            for (int i = 0; i < 4; ++i) {
                s16x4 pk;
                #pragma unroll
                for (int r = 0; r < 4; ++r)
                    pk[r] = (short)f2bf(acc[i][j][r] + bj);
                *(s16x4*)&vrow[tBase + i * 16] = pk;
            }
        }
    }
}

// ---------------------------------------------------------------------------
// topk_select: zero this bh's selmask chunk, then 3-pass radix -> v38; emit
// the candidate band {t : norm >= v38 - 0.4}.
// ---------------------------------------------------------------------------
__global__ __launch_bounds__(256) void topk_select(
    const float* __restrict__ norms, int* __restrict__ cand_t, int* __restrict__ cand_cnt,
    unsigned* __restrict__ selmask)
{
    const int bh = blockIdx.x;
    const int tid = threadIdx.x;
    const int lane = tid & 63;
    const int w = tid >> 6;

    if (tid < 128) selmask[bh * 128 + tid] = 0u;   // 32*128 = 4096 rows total

    __shared__ unsigned keys[T_SEQ];
    __shared__ unsigned hist[2048];
    __shared__ unsigned wsum[4];
    __shared__ unsigned bc_bin, bc_above;
    __shared__ int cnt;

    const float* nr = norms + (size_t)bh * T_SEQ;
    #pragma unroll
    for (int j = 0; j < 8; ++j)
        keys[tid + j * 256] = __float_as_uint(nr[tid + j * 256]);

    const int  shifts[3] = {21, 10, 0};
    const unsigned binm[3]  = {0x7FFu, 0x7FFu, 0x3FFu};
    const unsigned prefm[3] = {0x00000000u, 0xFFE00000u, 0xFFFFFC00u};

    unsigned prefix = 0;
    unsigned K_rem = U_SEL;

    for (int p = 0; p < 3; ++p) {
        #pragma unroll
        for (int j = 0; j < 8; ++j) hist[tid + j * 256] = 0;
        __syncthreads();
        #pragma unroll
        for (int j = 0; j < 8; ++j) {
            const unsigned k = keys[tid + j * 256];
            if ((k & prefm[p]) == prefix)
                atomicAdd(&hist[(k >> shifts[p]) & binm[p]], 1u);
        }
        __syncthreads();

        unsigned s = 0;
        #pragma unroll
        for (int e = 0; e < 8; ++e) s += hist[tid * 8 + e];
        unsigned v = s;
        #pragma unroll
        for (int off = 1; off < 64; off <<= 1) {
            const unsigned o = __shfl_down((int)v, off);
            if (lane + off < 64) v += o;
        }
        if (lane == 0) wsum[w] = v;
        __syncthreads();
        unsigned suf = v;
        for (int ww = w + 1; ww < 4; ++ww) suf += wsum[ww];
        const unsigned suf_next = suf - s;

        if (suf >= K_rem && suf_next < K_rem) {
            unsigned acc = suf_next;
            #pragma unroll
            for (int e = 7; e >= 0; --e) {
                const unsigned nb = hist[tid * 8 + e];
                if (acc + nb >= K_rem) { bc_bin = tid * 8 + e; bc_above = acc; break; }
                acc += nb;
            }
        }
        __syncthreads();
        prefix |= bc_bin << shifts[p];
        K_rem -= bc_above;
        __syncthreads();
    }

    const float thr = __uint_as_float(prefix) - 0.4f;
    if (tid == 0) cnt = 0;
    __syncthreads();
    #pragma unroll
    for (int j = 0; j < 8; ++j) {
        const int i = tid + j * 256;
        if (__uint_as_float(keys[i]) >= thr) {
            const int s = atomicAdd(&cnt, 1);
            if (s < CAND_CAP) cand_t[bh * CAND_CAP + s] = i;
        }
    }
    __syncthreads();
    if (tid == 0) cand_cnt[bh] = cnt < CAND_CAP ? cnt : CAND_CAP;
}

// ---------------------------------------------------------------------------
// fixup_norms: one block per (bh, candidate). Exact f32 q-row norm from x, Wq.
// ---------------------------------------------------------------------------
__global__ __launch_bounds__(256) void fixup_norms(
    const float* __restrict__ x, const float* __restrict__ Wq,
    const float* __restrict__ bq, const int* __restrict__ cand_t,
    const int* __restrict__ cand_cnt, float* __restrict__ n_exact)
{
    const int bh = blockIdx.x, c = blockIdx.y;
    const int b = bh >> 4, h = bh & 15;
    if (c >= cand_cnt[bh]) return;
    const int t = cand_t[bh * CAND_CAP + c];
    const int tid = threadIdx.x, d = tid & 63, kq = tid >> 6;

    __shared__ float xs[D_MODEL];
    __shared__ float part[4][HD];

    *(f32x4*)&xs[tid * 4] = *(const f32x4*)&x[((size_t)(b * T_SEQ + t)) * D_MODEL + tid * 4];
    __syncthreads();

    const float* wp = Wq + (size_t)(kq * 256) * D_MODEL + h * HD + d;
    const float* xp = &xs[kq * 256];
    float a0 = 0.f, a1 = 0.f, a2 = 0.f, a3 = 0.f;
    #pragma unroll 4
    for (int k = 0; k < 256; k += 4) {
        a0 += xp[k]     * wp[(k)     * D_MODEL];
        a1 += xp[k + 1] * wp[(k + 1) * D_MODEL];
        a2 += xp[k + 2] * wp[(k + 2) * D_MODEL];
        a3 += xp[k + 3] * wp[(k + 3) * D_MODEL];
    }
    part[kq][d] = (a0 + a1) + (a2 + a3);
    __syncthreads();
    if (tid < 64) {
        float v = fabsf(part[0][tid] + part[1][tid] + part[2][tid] + part[3][tid]
                        + bq[h * HD + tid]);
        #pragma unroll
        for (int off = 1; off < 64; off <<= 1) v += __shfl_xor(v, off);
        if (tid == 0) n_exact[bh * CAND_CAP + c] = v;
    }
}

// ---------------------------------------------------------------------------
// fixup_select: top-38 among candidates by (exact norm, -t); also record
// per-(b,t) head ownership (mask + u slot) for the gather-style out kernel.
// ---------------------------------------------------------------------------
__global__ __launch_bounds__(256) void fixup_select(
    const float* __restrict__ n_exact, const int* __restrict__ cand_t,
    const int* __restrict__ cand_cnt, int* __restrict__ idx_out,
    unsigned* __restrict__ selmask, int* __restrict__ selu)
{
    const int bh = blockIdx.x;
    const int tid = threadIdx.x, lane = tid & 63, w = tid >> 6;
    const int nc = cand_cnt[bh];
    const int b = bh >> 4, h = bh & 15;

    __shared__ float nv[CAND_CAP];
    __shared__ int   tv[CAND_CAP];
    __shared__ float wv[4]; __shared__ int wt[4]; __shared__ int wsl[4];

    if (tid < CAND_CAP) {
        nv[tid] = (tid < nc) ? n_exact[bh * CAND_CAP + tid] : -1e30f;
        tv[tid] = (tid < nc) ? cand_t[bh * CAND_CAP + tid] : 0x7FFFFFFF;
    }
    __syncthreads();

    for (int r = 0; r < U_SEL; ++r) {
        float v; int t, sl;
        if (tid < CAND_CAP) { v = nv[tid]; t = tv[tid]; sl = tid; }
        else { v = -1e30f; t = 0x7FFFFFFF; sl = 0; }
        #pragma unroll
        for (int off = 1; off < 64; off <<= 1) {
            const float ov = __shfl_xor(v, off);
            const int   ot = __shfl_xor(t, off);
            const int   osl = __shfl_xor(sl, off);
            if (ov > v || (ov == v && ot < t)) { v = ov; t = ot; sl = osl; }
        }
        if (lane == 0) { wv[w] = v; wt[w] = t; wsl[w] = sl; }
        __syncthreads();
        if (tid == 0) {
            float bvv = wv[0]; int btt = wt[0]; int bsl = wsl[0];
            #pragma unroll
            for (int ww = 1; ww < 4; ++ww)
                if (wv[ww] > bvv || (wv[ww] == bvv && wt[ww] < btt)) {
                    bvv = wv[ww]; btt = wt[ww]; bsl = wsl[ww];
                }
            idx_out[bh * U_SEL + r] = btt;
            nv[bsl] = -1e30f;
            const int row = (b << 11) + btt;
            atomicOr(&selmask[row], 1u << h);
            selu[row * NH + h] = r;
        }
        __syncthreads();
    }
}

// ---------------------------------------------------------------------------
// attn_scores: S[bh][u][t] = (q_sel . k_t) for t <= qi (q pre-scaled, bf16).
// Grid (32 bh, 8 t-chunks, 2 u-groups of 19). K row in 64 VGPRs, reused.
// ---------------------------------------------------------------------------
__global__ __launch_bounds__(256) void attn_scores(
    const ushort_t* __restrict__ qb, const ushort_t* __restrict__ kk_,
    const int* __restrict__ idx, float* __restrict__ S)
{
    const int bh = blockIdx.x, ch = blockIdx.y, ug = blockIdx.z;
    const int b = bh >> 4, h = bh & 15;
    const int tid = threadIdx.x;
    const int t = ch * 256 + tid;
    const int u0 = ug * 19;

    __shared__ float qs[19][HD];
    __shared__ int qis[19];

    if (tid < 19) qis[tid] = idx[bh * U_SEL + u0 + tid];
    __syncthreads();
    for (int e = tid; e < 19 * HD; e += 256) {
        const int u = e >> 6, d = e & 63;
        qs[u][d] = bf2f(qb[((size_t)(b * T_SEQ + qis[u])) * D_MODEL + h * HD + d]) * 0.125f;
    }

    float kr[64];
    {
        const ushort_t* kp = kk_ + ((size_t)(b * T_SEQ + t)) * D_MODEL + h * HD;
        #pragma unroll
        for (int d0 = 0; d0 < 64; d0 += 8) {
            const s16x8 r = *(const s16x8*)(kp + d0);
            #pragma unroll
            for (int e = 0; e < 8; ++e) kr[d0 + e] = bf2f((unsigned short)r[e]);
        }
    }
    __syncthreads();

    const int wbase = ch * 256 + (tid & ~63);   // wave's min t (uniform)
    for (int uu = 0; uu < 19; ++uu) {
        const int qi = qis[uu];
        if (wbase > qi) continue;               // wave-uniform skip
        float sp0 = 0.f, sp1 = 0.f, sp2 = 0.f, sp3 = 0.f;
        #pragma unroll
        for (int d0 = 0; d0 < 64; d0 += 16) {
            const f32x4 q0 = *(const f32x4*)&qs[uu][d0];
            const f32x4 q1 = *(const f32x4*)&qs[uu][d0 + 4];
            const f32x4 q2 = *(const f32x4*)&qs[uu][d0 + 8];
            const f32x4 q3 = *(const f32x4*)&qs[uu][d0 + 12];
            sp0 += q0.x * kr[d0] + q0.y * kr[d0 + 1] + q0.z * kr[d0 + 2] + q0.w * kr[d0 + 3];
            sp1 += q1.x * kr[d0 + 4] + q1.y * kr[d0 + 5] + q1.z * kr[d0 + 6] + q1.w * kr[d0 + 7];
            sp2 += q2.x * kr[d0 + 8] + q2.y * kr[d0 + 9] + q2.z * kr[d0 + 10] + q2.w * kr[d0 + 11];
            sp3 += q3.x * kr[d0 + 12] + q3.y * kr[d0 + 13] + q3.z * kr[d0 + 14] + q3.w * kr[d0 + 15];
        }
        S[((size_t)(bh * U_SEL + u0 + uu)) * T_SEQ + t] = sp0 + sp1 + sp2 + sp3;
    }
}

// ---------------------------------------------------------------------------
// attn_pv: one block per (bh,u). Softmax over S[0..qi] (LDS), PV along the
// contiguous t axis of transposed V.
// ---------------------------------------------------------------------------
__global__ __launch_bounds__(256) void attn_pv(
    const float* __restrict__ S, const ushort_t* __restrict__ vT,
    const int* __restrict__ idx, float* __restrict__ sel_out)
{
    const int bh = blockIdx.x, u = blockIdx.y;
    const int tid = threadIdx.x;
    const int d = tid & 63;
    const int qtr = tid >> 6;
    const int qi = idx[bh * U_SEL + u];
    const int nk = qi + 1;
    const int pad8 = (nk + 7) & ~7;
    const float* Srow = S + ((size_t)(bh * U_SEL + u)) * T_SEQ;

    __shared__ float sc[T_SEQ];
    __shared__ float red[256];
    __shared__ float part[4][HD];

    float lm = -1e30f;
    for (int t = tid; t < nk; t += 256) { const float s = Srow[t]; sc[t] = s; lm = fmaxf(lm, s); }
    red[tid] = lm;
    __syncthreads();
    for (int s = 128; s > 0; s >>= 1) {
        if (tid < s) red[tid] = fmaxf(red[tid], red[tid + s]);
        __syncthreads();
    }
    const float m = red[0];
    __syncthreads();

    float ls = 0.f;
    for (int t = tid; t < nk; t += 256) { const float p = __expf(sc[t] - m); sc[t] = p; ls += p; }
    if (tid < 7) { const int t = nk + tid; if (t < pad8) sc[t] = 0.f; }
    red[tid] = ls;
    __syncthreads();
    for (int s = 128; s > 0; s >>= 1) {
        if (tid < s) red[tid] += red[tid + s];
        __syncthreads();
    }
    const float l = red[0];

    const ushort_t* vrow = vT + ((size_t)(bh * HD + d)) * T_SEQ;
    float a0 = 0.f, a1 = 0.f;
    #pragma unroll
    for (int mm = 0; mm < 4; ++mm) {
        const int base = mm * 512 + qtr * 128;
        if (base >= nk) break;
        const int bend = base + 128 < pad8 ? base + 128 : pad8;
        for (int t = base; t < bend; t += 8) {
            const s16x8 v8 = *(const s16x8*)(vrow + t);
            const f32x4 p0 = *(const f32x4*)&sc[t];
            const f32x4 p1 = *(const f32x4*)&sc[t + 4];
            a0 += p0.x * bf2f((unsigned short)v8[0]) + p0.y * bf2f((unsigned short)v8[1])
                + p0.z * bf2f((unsigned short)v8[2]) + p0.w * bf2f((unsigned short)v8[3]);
            a1 += p1.x * bf2f((unsigned short)v8[4]) + p1.y * bf2f((unsigned short)v8[5])
                + p1.z * bf2f((unsigned short)v8[6]) + p1.w * bf2f((unsigned short)v8[7]);
        }
    }
    part[qtr][d] = a0 + a1;
    __syncthreads();
    if (tid < HD)
        sel_out[((size_t)(bh * U_SEL + u)) * HD + tid] =
            (part[0][tid] + part[1][tid] + part[2][tid] + part[3][tid]) / l;
}

// ---------------------------------------------------------------------------
// out_proj: one block per output row (b,t). out = bo + sum over owning heads
// (ascending h -> deterministic) of sel_out[bh,u] @ Wo[h*64:(h+1)*64, :].
// ---------------------------------------------------------------------------
__global__ __launch_bounds__(256) void out_proj(
    const float* __restrict__ sel_out, const float* __restrict__ Wo,
    const float* __restrict__ bo, const unsigned* __restrict__ selmask,
    const int* __restrict__ selu, float* __restrict__ out)
{
    const int row = blockIdx.x;               // 0..4095
    const int b = row >> 11;
    const int tid = threadIdx.x;
    const int c0 = tid * 4;

    __shared__ float s[HD];
    f32x4 o = *(const f32x4*)&bo[c0];
    unsigned mask = selmask[row];

    while (mask) {
        const int h = __ffs(mask) - 1;
        mask &= mask - 1;
        const int u = selu[row * NH + h];
        if (tid < HD)
            s[tid] = sel_out[((size_t)((b * NH + h) * U_SEL + u)) * HD + tid];
        __syncthreads();
        #pragma unroll 8
        for (int r = 0; r < HD; ++r) {
            const float sv = s[r];
            const f32x4 w4 = *(const f32x4*)&Wo[((size_t)(h * HD + r)) * D_MODEL + c0];
            o.x += sv * w4.x; o.y += sv * w4.y; o.z += sv * w4.z; o.w += sv * w4.w;
        }
        __syncthreads();
    }
    *(f32x4*)&out[(size_t)row * D_MODEL + c0] = o;
}

// ---------------------------------------------------------------------------
extern "C" void kernel_launch(void* const* d_in, const int* in_sizes, int n_in,
                              void* d_out, int out_size, void* d_ws, size_t ws_size,
                              hipStream_t stream)
{
    const float* x  = (const float*)d_in[0];
    const float* Wq = (const float*)d_in[1];
    const float* bq = (const float*)d_in[2];
    const float* Wk = (const float*)d_in[3];
    const float* bk = (const float*)d_in[4];
    const float* Wv = (const float*)d_in[5];
    const float* bv = (const float*)d_in[6];
    const float* Wo = (const float*)d_in[7];
    const float* bo = (const float*)d_in[8];
    float* out = (float*)d_out;

    // workspace layout (~49 MB; ws >= 58 MB proven in round 5)
    char* ws = (char*)d_ws;
    ushort_t* xh      = (ushort_t*)(ws);                              //  8 MB
    ushort_t* wqhT    = (ushort_t*)(ws + (8u << 20));                 //  2 MB
    ushort_t* wkhT    = (ushort_t*)(ws + (10u << 20));                //  2 MB
    ushort_t* wvhT    = (ushort_t*)(ws + (12u << 20));                //  2 MB
    ushort_t* k       = (ushort_t*)(ws + (14u << 20));                //  8 MB
    ushort_t* vT      = (ushort_t*)(ws + (22u << 20));                //  8 MB
    ushort_t* qb      = (ushort_t*)(ws + (30u << 20));                //  8 MB (Q bf16)
    float*    S       = (float*)(ws + (38u << 20));                   // 10 MB
    float*    norms   = (float*)(ws + (48u << 20));                   // 256 KB
    int*      cand_t  = (int*)(ws + (48u << 20) + (256u << 10));      // 12 KB
    int*      cand_cnt= (int*)(ws + (48u << 20) + (272u << 10));      // 128 B
    float*    n_exact = (float*)(ws + (48u << 20) + (276u << 10));    // 12 KB
    int*      idx     = (int*)(ws + (48u << 20) + (292u << 10));      // ~5 KB
    float*    sel_out = (float*)(ws + (48u << 20) + (300u << 10));    // 304 KB
    unsigned* selmask = (unsigned*)(ws + (48u << 20) + (640u << 10)); // 16 KB
    int*      selu    = (int*)(ws + (48u << 20) + (656u << 10));      // 256 KB

    prep<<<2048 + 768, 256, 0, stream>>>(x, Wq, Wk, Wv, xh, wqhT, wkhT, wvhT);
    {
        dim3 g((NB * T_SEQ) / GBM, D_MODEL / GBN, 3);
        qkv_mfma<<<g, 256, 0, stream>>>(xh, wqhT, wkhT, wvhT, bq, bk, bv,
                                        qb, k, vT, norms);
    }
    topk_select<<<NB * NH, 256, 0, stream>>>(norms, cand_t, cand_cnt, selmask);
    {
        dim3 g(NB * NH, CAND_CAP);
        fixup_norms<<<g, 256, 0, stream>>>(x, Wq, bq, cand_t, cand_cnt, n_exact);
    }
    fixup_select<<<NB * NH, 256, 0, stream>>>(n_exact, cand_t, cand_cnt, idx, selmask, selu);
    {
        dim3 g(NB * NH, T_SEQ / 256, 2);
        attn_scores<<<g, 256, 0, stream>>>(qb, k, idx, S);
    }
    {
        dim3 g(NB * NH, U_SEL);
        attn_pv<<<g, 256, 0, stream>>>(S, vT, idx, sel_out);
    }
    out_proj<<<NB * T_SEQ, 256, 0, stream>>>(sel_out, Wo, bo, selmask, selu, out);
}

// Round 10
// 194.195 us; speedup vs baseline: 1.3814x; 1.0518x over previous
//
#include <hip/hip_runtime.h>

#define NB 2
#define T_SEQ 2048
#define D_MODEL 1024
#define NH 16
#define HD 64
#define U_SEL 38
#define CAND_CAP 96
#define NCH 8          // t-chunks of 256 in scores/stats

typedef __attribute__((ext_vector_type(8))) short s16x8;
typedef __attribute__((ext_vector_type(4))) short s16x4;
typedef __attribute__((ext_vector_type(4))) float f32x4;
typedef unsigned short ushort_t;

__device__ __forceinline__ unsigned short f2bf(float f) {
    unsigned u = __float_as_uint(f);
    u += 0x7FFFu + ((u >> 16) & 1u);          // RNE
    return (unsigned short)(u >> 16);
}
__device__ __forceinline__ float bf2f(unsigned short h) {
    return __uint_as_float(((unsigned)h) << 16);
}

__device__ __forceinline__ void async_copy16(const void* g, void* l) {
    __builtin_amdgcn_global_load_lds(
        (const __attribute__((address_space(1))) void*)g,
        (__attribute__((address_space(3))) void*)l, 16, 0, 0);
}

// ---------------------------------------------------------------------------
// prep: blocks [0,2048): x -> xh (bf16). blocks [2048,2816): W -> W^T bf16.
// ---------------------------------------------------------------------------
__global__ __launch_bounds__(256) void prep(
    const float* __restrict__ x,
    const float* __restrict__ Wq, const float* __restrict__ Wk, const float* __restrict__ Wv,
    ushort_t* __restrict__ xh,
    ushort_t* __restrict__ wqhT, ushort_t* __restrict__ wkhT, ushort_t* __restrict__ wvhT)
{
    __shared__ float T[64][68];
    const int tid = threadIdx.x;
    if (blockIdx.x < 2048) {
        const size_t i0 = ((size_t)blockIdx.x * 256 + tid) * 8;
        const f32x4 a = *(const f32x4*)(x + i0);
        const f32x4 b = *(const f32x4*)(x + i0 + 4);
        const float f[8] = {a.x, a.y, a.z, a.w, b.x, b.y, b.z, b.w};
        s16x8 hi;
        #pragma unroll
        for (int e = 0; e < 8; ++e) hi[e] = (short)f2bf(f[e]);
        *(s16x8*)(xh + i0) = hi;
        return;
    }
    const int id2 = blockIdx.x - 2048;
    const int z = id2 >> 8;
    const int rem = id2 & 255;
    const int k0 = (rem & 15) * 64, n0 = (rem >> 4) * 64;
    const float* W = (z == 0) ? Wq : (z == 1) ? Wk : Wv;

    #pragma unroll
    for (int i = 0; i < 4; ++i) {
        const int r = (tid >> 4) + i * 16, c = (tid & 15) * 4;
        *(f32x4*)&T[r][c] = *(const f32x4*)&W[(size_t)(k0 + r) * D_MODEL + n0 + c];
    }
    __syncthreads();

    const int n = tid >> 2, kq = (tid & 3) * 16;
    s16x8 hi0, hi1;
    #pragma unroll
    for (int j = 0; j < 16; ++j) {
        const float f = T[kq + j][n];
        if (j < 8) hi0[j] = (short)f2bf(f);
        else       hi1[j - 8] = (short)f2bf(f);
    }
    ushort_t* oh = (z == 0) ? wqhT : (z == 1) ? wkhT : wvhT;
    const size_t ob = (size_t)(n0 + n) * D_MODEL + k0 + kq;
    *(s16x8*)(oh + ob) = hi0;
    *(s16x8*)(oh + ob + 8) = hi1;
}

// ---------------------------------------------------------------------------
// qkv_mfma: 128x128 tile, BK=32, 4 waves, global_load_lds width 16, source-
// swizzled (2-way LDS conflicts, verified 0 SQ_LDS_BANK_CONFLICT in r9).
// __launch_bounds__(256,4): force <=128 unified regs/wave -> 16 waves/CU.
//  z0: Q bf16 (+bq) AND per-(b,h,t) L1 norms.  z1: K bf16.  z2: V -> vT.
// ---------------------------------------------------------------------------
#define GBM 128
#define GBN 128
#define GBK 32

__global__ __launch_bounds__(256, 4) void qkv_mfma(
    const ushort_t* __restrict__ xh,
    const ushort_t* __restrict__ wqhT, const ushort_t* __restrict__ wkhT,
    const ushort_t* __restrict__ wvhT,
    const float* __restrict__ bq, const float* __restrict__ bk, const float* __restrict__ bv,
    ushort_t* __restrict__ qb, ushort_t* __restrict__ ko, ushort_t* __restrict__ vT,
    float* __restrict__ norms)
{
    const int z = blockIdx.z;
    __shared__ ushort_t Ah[GBM * GBK];
    __shared__ ushort_t Bh[GBN * GBK];

    const int tid = threadIdx.x;
    const int lane = tid & 63;
    const int wid = tid >> 6;
    const int wr = wid >> 1, wc = wid & 1;
    const size_t rowBase = (size_t)blockIdx.x * GBM;
    const size_t colBase = (size_t)blockIdx.y * GBN;

    const ushort_t* B0 = (z == 0) ? wqhT : (z == 1) ? wkhT : wvhT;
    const int srow = tid >> 2;                       // 0..63
    const int sl0  = ((tid & 3) - (srow >> 1)) & 3;  // pre-swizzled source slot
    const int skq  = sl0 * 8;

    // incrementing global pointers (saves per-iter address VALU + regs)
    const ushort_t* pA0 = xh + (rowBase + srow) * D_MODEL + skq;
    const ushort_t* pA1 = pA0 + (size_t)64 * D_MODEL;
    const ushort_t* pB0 = B0 + (colBase + srow) * D_MODEL + skq;
    const ushort_t* pB1 = pB0 + (size_t)64 * D_MODEL;
    ushort_t* lA0 = &Ah[tid * 8];
    ushort_t* lA1 = &Ah[2048 + tid * 8];
    ushort_t* lB0 = &Bh[tid * 8];
    ushort_t* lB1 = &Bh[2048 + tid * 8];

    // read-side physical slots (same permutation as source swizzle)
    int aph[4], bph[4];
    #pragma unroll
    for (int i = 0; i < 4; ++i) {
        const int arow = wr * 64 + i * 16 + (lane & 15);
        aph[i] = arow * GBK + ((((lane >> 4) + (arow >> 1)) & 3) << 3);
        const int brow = wc * 64 + i * 16 + (lane & 15);
        bph[i] = brow * GBK + ((((lane >> 4) + (brow >> 1)) & 3) << 3);
    }

    f32x4 acc[4][4] = {};

    for (int kk = 0; kk < 32; ++kk) {
        async_copy16(pA0, lA0);
        async_copy16(pA1, lA1);
        async_copy16(pB0, lB0);
        async_copy16(pB1, lB1);
        pA0 += GBK; pA1 += GBK; pB0 += GBK; pB1 += GBK;
        __syncthreads();

        s16x8 bf[4];
        #pragma unroll
        for (int j = 0; j < 4; ++j) bf[j] = *(const s16x8*)&Bh[bph[j]];
        #pragma unroll
        for (int i = 0; i < 4; ++i) {
            const s16x8 af = *(const s16x8*)&Ah[aph[i]];   // single live A frag
            #pragma unroll
            for (int j = 0; j < 4; ++j)
                acc[i][j] = __builtin_amdgcn_mfma_f32_16x16x32_bf16(af, bf[j], acc[i][j], 0, 0, 0);
        }
        __syncthreads();
    }

    // epilogue: C/D layout col=lane&15, row=(lane>>4)*4+r
    const int cB = (int)colBase + wc * 64 + (lane & 15);
    const int rL = wr * 64 + ((lane >> 4) << 2);
    const int rB = (int)rowBase + rL;
    if (z == 0) {
        float bjv[4];
        #pragma unroll
        for (int j = 0; j < 4; ++j) bjv[j] = bq[cB + j * 16];
        const int bb = (int)(rowBase >> 11);
        const int hw = cB >> 6;
        #pragma unroll
        for (int i = 0; i < 4; ++i) {
            float nr[4];
            #pragma unroll
            for (int r = 0; r < 4; ++r) {
                float s = 0.f;
                #pragma unroll
                for (int j = 0; j < 4; ++j) s += fabsf(acc[i][j][r] + bjv[j]);
                nr[r] = s;
            }
            #pragma unroll
            for (int off = 1; off < 16; off <<= 1) {
                #pragma unroll
                for (int r = 0; r < 4; ++r) nr[r] += __shfl_xor(nr[r], off);
            }
            if ((lane & 15) == 0) {
                const int trow = (int)(rowBase & (T_SEQ - 1)) + wr * 64 + i * 16 + ((lane >> 4) << 2);
                f32x4 nv; nv.x = nr[0]; nv.y = nr[1]; nv.z = nr[2]; nv.w = nr[3];
                *(f32x4*)&norms[(size_t)(bb * NH + hw) * T_SEQ + trow] = nv;
            }
        }
        #pragma unroll
        for (int j = 0; j < 4; ++j)
            #pragma unroll
            for (int i = 0; i < 4; ++i)
                #pragma unroll
                for (int r = 0; r < 4; ++r)
                    qb[(size_t)(rB + i * 16 + r) * D_MODEL + cB + j * 16] = f2bf(acc[i][j][r] + bjv[j]);
    } else if (z == 1) {
        #pragma unroll
        for (int j = 0; j < 4; ++j) {
            const float bj = bk[cB + j * 16];
            #pragma unroll
            for (int i = 0; i < 4; ++i)
                #pragma unroll
                for (int r = 0; r < 4; ++r)
                    ko[(size_t)(rB + i * 16 + r) * D_MODEL + cB + j * 16] = f2bf(acc[i][j][r] + bj);
        }
    } else {
        const int bb = (int)(rowBase >> 11);
        const int tBase = (int)(rowBase & (T_SEQ - 1)) + rL;
        #pragma unroll
        for (int j = 0; j < 4; ++j) {
            const int dg = cB + j * 16;
            const float bj = bv[dg];
            ushort_t* vrow = vT + ((size_t)(bb * NH) * HD + dg) * T_SEQ;
            #pragma unroll
            for (int i = 0; i < 4; ++i) {
                s16x4 pk;
                #pragma unroll
                for (int r = 0; r < 4; ++r)
                    pk[r] = (short)f2bf(acc[i][j][r] + bj);
                *(s16x4*)&vrow[tBase + i * 16] = pk;
            }
        }
    }
}

// ---------------------------------------------------------------------------
// topk_select: zero selmask; 3-pass radix -> v38; emit band {n >= v38 - 0.4}.
// ---------------------------------------------------------------------------
__global__ __launch_bounds__(256) void topk_select(
    const float* __restrict__ norms, int* __restrict__ cand_t, int* __restrict__ cand_cnt,
    unsigned* __restrict__ selmask)
{
    const int bh = blockIdx.x;
    const int tid = threadIdx.x;
    const int lane = tid & 63;
    const int w = tid >> 6;

    if (tid < 128) selmask[bh * 128 + tid] = 0u;

    __shared__ unsigned keys[T_SEQ];
    __shared__ unsigned hist[2048];
    __shared__ unsigned wsum[4];
    __shared__ unsigned bc_bin, bc_above;
    __shared__ int cnt;

    const float* nr = norms + (size_t)bh * T_SEQ;
    #pragma unroll
    for (int j = 0; j < 8; ++j)
        keys[tid + j * 256] = __float_as_uint(nr[tid + j * 256]);

    const int  shifts[3] = {21, 10, 0};
    const unsigned binm[3]  = {0x7FFu, 0x7FFu, 0x3FFu};
    const unsigned prefm[3] = {0x00000000u, 0xFFE00000u, 0xFFFFFC00u};

    unsigned prefix = 0;
    unsigned K_rem = U_SEL;

    for (int p = 0; p < 3; ++p) {
        #pragma unroll
        for (int j = 0; j < 8; ++j) hist[tid + j * 256] = 0;
        __syncthreads();
        #pragma unroll
        for (int j = 0; j < 8; ++j) {
            const unsigned k = keys[tid + j * 256];
            if ((k & prefm[p]) == prefix)
                atomicAdd(&hist[(k >> shifts[p]) & binm[p]], 1u);
        }
        __syncthreads();

        unsigned s = 0;
        #pragma unroll
        for (int e = 0; e < 8; ++e) s += hist[tid * 8 + e];
        unsigned v = s;
        #pragma unroll
        for (int off = 1; off < 64; off <<= 1) {
            const unsigned o = __shfl_down((int)v, off);
            if (lane + off < 64) v += o;
        }
        if (lane == 0) wsum[w] = v;
        __syncthreads();
        unsigned suf = v;
        for (int ww = w + 1; ww < 4; ++ww) suf += wsum[ww];
        const unsigned suf_next = suf - s;

        if (suf >= K_rem && suf_next < K_rem) {
            unsigned acc = suf_next;
            #pragma unroll
            for (int e = 7; e >= 0; --e) {
                const unsigned nb = hist[tid * 8 + e];
                if (acc + nb >= K_rem) { bc_bin = tid * 8 + e; bc_above = acc; break; }
                acc += nb;
            }
        }
        __syncthreads();
        prefix |= bc_bin << shifts[p];
        K_rem -= bc_above;
        __syncthreads();
    }

    const float thr = __uint_as_float(prefix) - 0.4f;
    if (tid == 0) cnt = 0;
    __syncthreads();
    #pragma unroll
    for (int j = 0; j < 8; ++j) {
        const int i = tid + j * 256;
        if (__uint_as_float(keys[i]) >= thr) {
            const int s = atomicAdd(&cnt, 1);
            if (s < CAND_CAP) cand_t[bh * CAND_CAP + s] = i;
        }
    }
    __syncthreads();
    if (tid == 0) cand_cnt[bh] = cnt < CAND_CAP ? cnt : CAND_CAP;
}

// ---------------------------------------------------------------------------
// fixup_norms: one block per (bh, candidate). Exact f32 q-row norm from x, Wq.
// ---------------------------------------------------------------------------
__global__ __launch_bounds__(256) void fixup_norms(
    const float* __restrict__ x, const float* __restrict__ Wq,
    const float* __restrict__ bq, const int* __restrict__ cand_t,
    const int* __restrict__ cand_cnt, float* __restrict__ n_exact)
{
    const int bh = blockIdx.x, c = blockIdx.y;
    const int b = bh >> 4, h = bh & 15;
    if (c >= cand_cnt[bh]) return;
    const int t = cand_t[bh * CAND_CAP + c];
    const int tid = threadIdx.x, d = tid & 63, kq = tid >> 6;

    __shared__ float xs[D_MODEL];
    __shared__ float part[4][HD];

    *(f32x4*)&xs[tid * 4] = *(const f32x4*)&x[((size_t)(b * T_SEQ + t)) * D_MODEL + tid * 4];
    __syncthreads();

    const float* wp = Wq + (size_t)(kq * 256) * D_MODEL + h * HD + d;
    const float* xp = &xs[kq * 256];
    float a0 = 0.f, a1 = 0.f, a2 = 0.f, a3 = 0.f;
    #pragma unroll 4
    for (int k = 0; k < 256; k += 4) {
        a0 += xp[k]     * wp[(k)     * D_MODEL];
        a1 += xp[k + 1] * wp[(k + 1) * D_MODEL];
        a2 += xp[k + 2] * wp[(k + 2) * D_MODEL];
        a3 += xp[k + 3] * wp[(k + 3) * D_MODEL];
    }
    part[kq][d] = (a0 + a1) + (a2 + a3);
    __syncthreads();
    if (tid < 64) {
        float v = fabsf(part[0][tid] + part[1][tid] + part[2][tid] + part[3][tid]
                        + bq[h * HD + tid]);
        #pragma unroll
        for (int off = 1; off < 64; off <<= 1) v += __shfl_xor(v, off);
        if (tid == 0) n_exact[bh * CAND_CAP + c] = v;
    }
}

// ---------------------------------------------------------------------------
// fixup_select: top-38 among candidates by (exact norm, -t); record per-(b,t)
// head ownership for out_proj.
// ---------------------------------------------------------------------------
__global__ __launch_bounds__(256) void fixup_select(
    const float* __restrict__ n_exact, const int* __restrict__ cand_t,
    const int* __restrict__ cand_cnt, int* __restrict__ idx_out,
    unsigned* __restrict__ selmask, int* __restrict__ selu)
{
    const int bh = blockIdx.x;
    const int tid = threadIdx.x, lane = tid & 63, w = tid >> 6;
    const int nc = cand_cnt[bh];
    const int b = bh >> 4, h = bh & 15;

    __shared__ float nv[CAND_CAP];
    __shared__ int   tv[CAND_CAP];
    __shared__ float wv[4]; __shared__ int wt[4]; __shared__ int wsl[4];

    if (tid < CAND_CAP) {
        nv[tid] = (tid < nc) ? n_exact[bh * CAND_CAP + tid] : -1e30f;
        tv[tid] = (tid < nc) ? cand_t[bh * CAND_CAP + tid] : 0x7FFFFFFF;
    }
    __syncthreads();

    for (int r = 0; r < U_SEL; ++r) {
        float v; int t, sl;
        if (tid < CAND_CAP) { v = nv[tid]; t = tv[tid]; sl = tid; }
        else { v = -1e30f; t = 0x7FFFFFFF; sl = 0; }
        #pragma unroll
        for (int off = 1; off < 64; off <<= 1) {
            const float ov = __shfl_xor(v, off);
            const int   ot = __shfl_xor(t, off);
            const int   osl = __shfl_xor(sl, off);
            if (ov > v || (ov == v && ot < t)) { v = ov; t = ot; sl = osl; }
        }
        if (lane == 0) { wv[w] = v; wt[w] = t; wsl[w] = sl; }
        __syncthreads();
        if (tid == 0) {
            float bvv = wv[0]; int btt = wt[0]; int bsl = wsl[0];
            #pragma unroll
            for (int ww = 1; ww < 4; ++ww)
                if (wv[ww] > bvv || (wv[ww] == bvv && wt[ww] < btt)) {
                    bvv = wv[ww]; btt = wt[ww]; bsl = wsl[ww];
                }
            idx_out[bh * U_SEL + r] = btt;
            nv[bsl] = -1e30f;
            const int row = (b << 11) + btt;
            atomicOr(&selmask[row], 1u << h);
            selu[row * NH + h] = r;
        }
        __syncthreads();
    }
}

// ---------------------------------------------------------------------------
// attn_scores: S + per-(u,chunk) softmax stats (max, sumexp w/ chunk max).
// Grid (32 bh, 8 t-chunks, 2 u-groups of 19). K row in 64 VGPRs, reused.
// ---------------------------------------------------------------------------
__global__ __launch_bounds__(256) void attn_scores(
    const ushort_t* __restrict__ qb, const ushort_t* __restrict__ kk_,
    const int* __restrict__ idx, float* __restrict__ S,
    float* __restrict__ mstat, float* __restrict__ lstat)
{
    const int bh = blockIdx.x, ch = blockIdx.y, ug = blockIdx.z;
    const int b = bh >> 4, h = bh & 15;
    const int tid = threadIdx.x;
    const int lane = tid & 63;
    const int w = tid >> 6;
    const int t = ch * 256 + tid;
    const int u0 = ug * 19;

    __shared__ float qs[19][HD];
    __shared__ int qis[19];
    __shared__ float mpart[19][4];
    __shared__ float lpart[19][4];

    if (tid < 19) qis[tid] = idx[bh * U_SEL + u0 + tid];
    if (tid < 76) { mpart[tid >> 2][tid & 3] = -1e30f; lpart[tid >> 2][tid & 3] = 0.f; }
    __syncthreads();
    for (int e = tid; e < 19 * HD; e += 256) {
        const int u = e >> 6, d = e & 63;
        qs[u][d] = bf2f(qb[((size_t)(b * T_SEQ + qis[u])) * D_MODEL + h * HD + d]) * 0.125f;
    }

    float kr[64];
    {
        const ushort_t* kp = kk_ + ((size_t)(b * T_SEQ + t)) * D_MODEL + h * HD;
        #pragma unroll
        for (int d0 = 0; d0 < 64; d0 += 8) {
            const s16x8 r = *(const s16x8*)(kp + d0);
            #pragma unroll
            for (int e = 0; e < 8; ++e) kr[d0 + e] = bf2f((unsigned short)r[e]);
        }
    }
    __syncthreads();

    const int wbase = ch * 256 + (tid & ~63);   // wave's min t (uniform)
    for (int uu = 0; uu < 19; ++uu) {
        const int qi = qis[uu];
        if (wbase > qi) continue;               // wave-uniform skip
        float sp0 = 0.f, sp1 = 0.f, sp2 = 0.f, sp3 = 0.f;
        #pragma unroll
        for (int d0 = 0; d0 < 64; d0 += 16) {
            const f32x4 q0 = *(const f32x4*)&qs[uu][d0];
            const f32x4 q1 = *(const f32x4*)&qs[uu][d0 + 4];
            const f32x4 q2 = *(const f32x4*)&qs[uu][d0 + 8];
            const f32x4 q3 = *(const f32x4*)&qs[uu][d0 + 12];
            sp0 += q0.x * kr[d0] + q0.y * kr[d0 + 1] + q0.z * kr[d0 + 2] + q0.w * kr[d0 + 3];
            sp1 += q1.x * kr[d0 + 4] + q1.y * kr[d0 + 5] + q1.z * kr[d0 + 6] + q1.w * kr[d0 + 7];
            sp2 += q2.x * kr[d0 + 8] + q2.y * kr[d0 + 9] + q2.z * kr[d0 + 10] + q2.w * kr[d0 + 11];
            sp3 += q3.x * kr[d0 + 12] + q3.y * kr[d0 + 13] + q3.z * kr[d0 + 14] + q3.w * kr[d0 + 15];
        }
        const float s = sp0 + sp1 + sp2 + sp3;
        S[((size_t)(bh * U_SEL + u0 + uu)) * T_SEQ + t] = s;
        // wave stats over valid lanes (t <= qi); wave has >=1 valid lane here
        const float sm = (t <= qi) ? s : -1e30f;
        float mw = sm;
        #pragma unroll
        for (int off = 1; off < 64; off <<= 1) mw = fmaxf(mw, __shfl_xor(mw, off));
        float p = (t <= qi) ? __expf(s - mw) : 0.f;
        #pragma unroll
        for (int off = 1; off < 64; off <<= 1) p += __shfl_xor(p, off);
        if (lane == 0) { mpart[uu][w] = mw; lpart[uu][w] = p; }
    }
    __syncthreads();
    if (tid < 19) {
        float M = -1e30f;
        #pragma unroll
        for (int ww = 0; ww < 4; ++ww) M = fmaxf(M, mpart[tid][ww]);
        float L = 0.f;
        #pragma unroll
        for (int ww = 0; ww < 4; ++ww) {
            const float mw = mpart[tid][ww];
            if (mw > -1e29f) L += lpart[tid][ww] * __expf(mw - M);
        }
        const size_t si = (size_t)(bh * U_SEL + u0 + tid) * NCH + ch;
        mstat[si] = M;
        lstat[si] = L;
    }
}

// ---------------------------------------------------------------------------
// attn_pv: one block per (bh,u). Stats-merged M,L (no block reductions);
// single exp pass into LDS; PV along contiguous t of transposed V.
// ---------------------------------------------------------------------------
__global__ __launch_bounds__(256) void attn_pv(
    const float* __restrict__ S, const ushort_t* __restrict__ vT,
    const int* __restrict__ idx, const float* __restrict__ mstat,
    const float* __restrict__ lstat, float* __restrict__ sel_out)
{
    const int bh = blockIdx.x, u = blockIdx.y;
    const int tid = threadIdx.x;
    const int d = tid & 63;
    const int qtr = tid >> 6;
    const int qi = idx[bh * U_SEL + u];
    const int nk = qi + 1;
    const int pad8 = (nk + 7) & ~7;
    const float* Srow = S + ((size_t)(bh * U_SEL + u)) * T_SEQ;

    __shared__ float sc[T_SEQ];
    __shared__ float part[4][HD];

    // merge chunk stats (redundant across threads; 16 floats from L1)
    const float* mp = mstat + (size_t)(bh * U_SEL + u) * NCH;
    const float* lp = lstat + (size_t)(bh * U_SEL + u) * NCH;
    float M = -1e30f;
    #pragma unroll
    for (int c = 0; c < NCH; ++c) M = fmaxf(M, mp[c]);
    float L = 0.f;
    #pragma unroll
    for (int c = 0; c < NCH; ++c) {
        const float mc = mp[c];
        if (mc > -1e29f) L += lp[c] * __expf(mc - M);
    }

    // single pass: p = exp(s - M) into LDS
    for (int t = tid; t < nk; t += 256) sc[t] = __expf(Srow[t] - M);
    if (tid < 7) { const int t = nk + tid; if (t < pad8) sc[t] = 0.f; }
    __syncthreads();

    // PV along contiguous t
    const ushort_t* vrow = vT + ((size_t)(bh * HD + d)) * T_SEQ;
    float a0 = 0.f, a1 = 0.f;
    #pragma unroll
    for (int mm = 0; mm < 4; ++mm) {
        const int base = mm * 512 + qtr * 128;
        if (base >= nk) break;
        const int bend = base + 128 < pad8 ? base + 128 : pad8;
        for (int t = base; t < bend; t += 8) {
            const s16x8 v8 = *(const s16x8*)(vrow + t);
            const f32x4 p0 = *(const f32x4*)&sc[t];
            const f32x4 p1 = *(const f32x4*)&sc[t + 4];
            a0 += p0.x * bf2f((unsigned short)v8[0]) + p0.y * bf2f((unsigned short)v8[1])
                + p0.z * bf2f((unsigned short)v8[2]) + p0.w * bf2f((unsigned short)v8[3]);
            a1 += p1.x * bf2f((unsigned short)v8[4]) + p1.y * bf2f((unsigned short)v8[5])
                + p1.z * bf2f((unsigned short)v8[6]) + p1.w * bf2f((unsigned short)v8[7]);
        }
    }
    part[qtr][d] = a0 + a1;
    __syncthreads();
    if (tid < HD)
        sel_out[((size_t)(bh * U_SEL + u)) * HD + tid] =
            (part[0][tid] + part[1][tid] + part[2][tid] + part[3][tid]) / L;
}

// ---------------------------------------------------------------------------
// out_proj: one block per output row (b,t). out = bo + sum over owning heads.
// ---------------------------------------------------------------------------
__global__ __launch_bounds__(256) void out_proj(
    const float* __restrict__ sel_out, const float* __restrict__ Wo,
    const float* __restrict__ bo, const unsigned* __restrict__ selmask,
    const int* __restrict__ selu, float* __restrict__ out)
{
    const int row = blockIdx.x;               // 0..4095
    const int b = row >> 11;
    const int tid = threadIdx.x;
    const int c0 = tid * 4;

    __shared__ float s[HD];
    f32x4 o = *(const f32x4*)&bo[c0];
    unsigned mask = selmask[row];

    while (mask) {
        const int h = __ffs(mask) - 1;
        mask &= mask - 1;
        const int u = selu[row * NH + h];
        if (tid < HD)
            s[tid] = sel_out[((size_t)((b * NH + h) * U_SEL + u)) * HD + tid];
        __syncthreads();
        #pragma unroll 8
        for (int r = 0; r < HD; ++r) {
            const float sv = s[r];
            const f32x4 w4 = *(const f32x4*)&Wo[((size_t)(h * HD + r)) * D_MODEL + c0];
            o.x += sv * w4.x; o.y += sv * w4.y; o.z += sv * w4.z; o.w += sv * w4.w;
        }
        __syncthreads();
    }
    *(f32x4*)&out[(size_t)row * D_MODEL + c0] = o;
}

// ---------------------------------------------------------------------------
extern "C" void kernel_launch(void* const* d_in, const int* in_sizes, int n_in,
                              void* d_out, int out_size, void* d_ws, size_t ws_size,
                              hipStream_t stream)
{
    const float* x  = (const float*)d_in[0];
    const float* Wq = (const float*)d_in[1];
    const float* bq = (const float*)d_in[2];
    const float* Wk = (const float*)d_in[3];
    const float* bk = (const float*)d_in[4];
    const float* Wv = (const float*)d_in[5];
    const float* bv = (const float*)d_in[6];
    const float* Wo = (const float*)d_in[7];
    const float* bo = (const float*)d_in[8];
    float* out = (float*)d_out;

    // workspace layout (~49 MB; ws >= 58 MB proven in round 5)
    char* ws = (char*)d_ws;
    ushort_t* xh      = (ushort_t*)(ws);                              //  8 MB
    ushort_t* wqhT    = (ushort_t*)(ws + (8u << 20));                 //  2 MB
    ushort_t* wkhT    = (ushort_t*)(ws + (10u << 20));                //  2 MB
    ushort_t* wvhT    = (ushort_t*)(ws + (12u << 20));                //  2 MB
    ushort_t* k       = (ushort_t*)(ws + (14u << 20));                //  8 MB
    ushort_t* vT      = (ushort_t*)(ws + (22u << 20));                //  8 MB
    ushort_t* qb      = (ushort_t*)(ws + (30u << 20));                //  8 MB (Q bf16)
    float*    S       = (float*)(ws + (38u << 20));                   // 10 MB
    float*    norms   = (float*)(ws + (48u << 20));                   // 256 KB
    int*      cand_t  = (int*)(ws + (48u << 20) + (256u << 10));      // 12 KB
    int*      cand_cnt= (int*)(ws + (48u << 20) + (272u << 10));      // 128 B
    float*    n_exact = (float*)(ws + (48u << 20) + (276u << 10));    // 12 KB
    int*      idx     = (int*)(ws + (48u << 20) + (292u << 10));      // ~5 KB
    float*    sel_out = (float*)(ws + (48u << 20) + (300u << 10));    // 304 KB
    unsigned* selmask = (unsigned*)(ws + (48u << 20) + (640u << 10)); // 16 KB
    int*      selu    = (int*)(ws + (48u << 20) + (656u << 10));      // 256 KB
    float*    mstat   = (float*)(ws + (48u << 20) + (912u << 10));    // 38 KB
    float*    lstat   = (float*)(ws + (48u << 20) + (960u << 10));    // 38 KB

    prep<<<2048 + 768, 256, 0, stream>>>(x, Wq, Wk, Wv, xh, wqhT, wkhT, wvhT);
    {
        dim3 g((NB * T_SEQ) / GBM, D_MODEL / GBN, 3);
        qkv_mfma<<<g, 256, 0, stream>>>(xh, wqhT, wkhT, wvhT, bq, bk, bv,
                                        qb, k, vT, norms);
    }
    topk_select<<<NB * NH, 256, 0, stream>>>(norms, cand_t, cand_cnt, selmask);
    {
        dim3 g(NB * NH, CAND_CAP);
        fixup_norms<<<g, 256, 0, stream>>>(x, Wq, bq, cand_t, cand_cnt, n_exact);
    }
    fixup_select<<<NB * NH, 256, 0, stream>>>(n_exact, cand_t, cand_cnt, idx, selmask, selu);
    {
        dim3 g(NB * NH, T_SEQ / 256, 2);
        attn_scores<<<g, 256, 0, stream>>>(qb, k, idx, S, mstat, lstat);
    }
    {
        dim3 g(NB * NH, U_SEL);
        attn_pv<<<g, 256, 0, stream>>>(S, vT, idx, mstat, lstat, sel_out);
    }
    out_proj<<<NB * T_SEQ, 256, 0, stream>>>(sel_out, Wo, bo, selmask, selu, out);
}

// Round 11
// 161.768 us; speedup vs baseline: 1.6583x; 1.2004x over previous
//
#include <hip/hip_runtime.h>

#define NB 2
#define T_SEQ 2048
#define D_MODEL 1024
#define NH 16
#define HD 64
#define U_SEL 38
#define CAND_CAP 96
#define NCH 8          // t-chunks of 256 in scores/stats

typedef __attribute__((ext_vector_type(8))) short s16x8;
typedef __attribute__((ext_vector_type(4))) short s16x4;
typedef __attribute__((ext_vector_type(4))) float f32x4;
typedef unsigned short ushort_t;

__device__ __forceinline__ unsigned short f2bf(float f) {
    unsigned u = __float_as_uint(f);
    u += 0x7FFFu + ((u >> 16) & 1u);          // RNE
    return (unsigned short)(u >> 16);
}
__device__ __forceinline__ float bf2f(unsigned short h) {
    return __uint_as_float(((unsigned)h) << 16);
}

__device__ __forceinline__ void async_copy16(const void* g, void* l) {
    __builtin_amdgcn_global_load_lds(
        (const __attribute__((address_space(1))) void*)g,
        (__attribute__((address_space(3))) void*)l, 16, 0, 0);
}

// ---------------------------------------------------------------------------
// prep: blocks [0,2048): x -> xh (bf16). blocks [2048,2816): W -> W^T bf16.
// ---------------------------------------------------------------------------
__global__ __launch_bounds__(256) void prep(
    const float* __restrict__ x,
    const float* __restrict__ Wq, const float* __restrict__ Wk, const float* __restrict__ Wv,
    ushort_t* __restrict__ xh,
    ushort_t* __restrict__ wqhT, ushort_t* __restrict__ wkhT, ushort_t* __restrict__ wvhT)
{
    __shared__ float T[64][68];
    const int tid = threadIdx.x;
    if (blockIdx.x < 2048) {
        const size_t i0 = ((size_t)blockIdx.x * 256 + tid) * 8;
        const f32x4 a = *(const f32x4*)(x + i0);
        const f32x4 b = *(const f32x4*)(x + i0 + 4);
        const float f[8] = {a.x, a.y, a.z, a.w, b.x, b.y, b.z, b.w};
        s16x8 hi;
        #pragma unroll
        for (int e = 0; e < 8; ++e) hi[e] = (short)f2bf(f[e]);
        *(s16x8*)(xh + i0) = hi;
        return;
    }
    const int id2 = blockIdx.x - 2048;
    const int z = id2 >> 8;
    const int rem = id2 & 255;
    const int k0 = (rem & 15) * 64, n0 = (rem >> 4) * 64;
    const float* W = (z == 0) ? Wq : (z == 1) ? Wk : Wv;

    #pragma unroll
    for (int i = 0; i < 4; ++i) {
        const int r = (tid >> 4) + i * 16, c = (tid & 15) * 4;
        *(f32x4*)&T[r][c] = *(const f32x4*)&W[(size_t)(k0 + r) * D_MODEL + n0 + c];
    }
    __syncthreads();

    const int n = tid >> 2, kq = (tid & 3) * 16;
    s16x8 hi0, hi1;
    #pragma unroll
    for (int j = 0; j < 16; ++j) {
        const float f = T[kq + j][n];
        if (j < 8) hi0[j] = (short)f2bf(f);
        else       hi1[j - 8] = (short)f2bf(f);
    }
    ushort_t* oh = (z == 0) ? wqhT : (z == 1) ? wkhT : wvhT;
    const size_t ob = (size_t)(n0 + n) * D_MODEL + k0 + kq;
    *(s16x8*)(oh + ob) = hi0;
    *(s16x8*)(oh + ob + 8) = hi1;
}

// ---------------------------------------------------------------------------
// qkv_mfma: 128x128 tile, BK=32, 4 waves, global_load_lds width 16, source-
// swizzled (0 bank conflicts, r9), __launch_bounds__(256,4) (occupancy, r10).
//  z0: Q bf16 (+bq) AND per-(b,h,t) L1 norms.  z1: K bf16.  z2: V -> vT.
// ---------------------------------------------------------------------------
#define GBM 128
#define GBN 128
#define GBK 32

__global__ __launch_bounds__(256, 4) void qkv_mfma(
    const ushort_t* __restrict__ xh,
    const ushort_t* __restrict__ wqhT, const ushort_t* __restrict__ wkhT,
    const ushort_t* __restrict__ wvhT,
    const float* __restrict__ bq, const float* __restrict__ bk, const float* __restrict__ bv,
    ushort_t* __restrict__ qb, ushort_t* __restrict__ ko, ushort_t* __restrict__ vT,
    float* __restrict__ norms)
{
    const int z = blockIdx.z;
    __shared__ ushort_t Ah[GBM * GBK];
    __shared__ ushort_t Bh[GBN * GBK];

    const int tid = threadIdx.x;
    const int lane = tid & 63;
    const int wid = tid >> 6;
    const int wr = wid >> 1, wc = wid & 1;
    const size_t rowBase = (size_t)blockIdx.x * GBM;
    const size_t colBase = (size_t)blockIdx.y * GBN;

    const ushort_t* B0 = (z == 0) ? wqhT : (z == 1) ? wkhT : wvhT;
    const int srow = tid >> 2;                       // 0..63
    const int sl0  = ((tid & 3) - (srow >> 1)) & 3;  // pre-swizzled source slot
    const int skq  = sl0 * 8;

    const ushort_t* pA0 = xh + (rowBase + srow) * D_MODEL + skq;
    const ushort_t* pA1 = pA0 + (size_t)64 * D_MODEL;
    const ushort_t* pB0 = B0 + (colBase + srow) * D_MODEL + skq;
    const ushort_t* pB1 = pB0 + (size_t)64 * D_MODEL;
    ushort_t* lA0 = &Ah[tid * 8];
    ushort_t* lA1 = &Ah[2048 + tid * 8];
    ushort_t* lB0 = &Bh[tid * 8];
    ushort_t* lB1 = &Bh[2048 + tid * 8];

    int aph[4], bph[4];
    #pragma unroll
    for (int i = 0; i < 4; ++i) {
        const int arow = wr * 64 + i * 16 + (lane & 15);
        aph[i] = arow * GBK + ((((lane >> 4) + (arow >> 1)) & 3) << 3);
        const int brow = wc * 64 + i * 16 + (lane & 15);
        bph[i] = brow * GBK + ((((lane >> 4) + (brow >> 1)) & 3) << 3);
    }

    f32x4 acc[4][4] = {};

    for (int kk = 0; kk < 32; ++kk) {
        async_copy16(pA0, lA0);
        async_copy16(pA1, lA1);
        async_copy16(pB0, lB0);
        async_copy16(pB1, lB1);
        pA0 += GBK; pA1 += GBK; pB0 += GBK; pB1 += GBK;
        __syncthreads();

        s16x8 bf[4];
        #pragma unroll
        for (int j = 0; j < 4; ++j) bf[j] = *(const s16x8*)&Bh[bph[j]];
        #pragma unroll
        for (int i = 0; i < 4; ++i) {
            const s16x8 af = *(const s16x8*)&Ah[aph[i]];
            #pragma unroll
            for (int j = 0; j < 4; ++j)
                acc[i][j] = __builtin_amdgcn_mfma_f32_16x16x32_bf16(af, bf[j], acc[i][j], 0, 0, 0);
        }
        __syncthreads();
    }

    // epilogue: C/D layout col=lane&15, row=(lane>>4)*4+r
    const int cB = (int)colBase + wc * 64 + (lane & 15);
    const int rL = wr * 64 + ((lane >> 4) << 2);
    const int rB = (int)rowBase + rL;
    if (z == 0) {
        float bjv[4];
        #pragma unroll
        for (int j = 0; j < 4; ++j) bjv[j] = bq[cB + j * 16];
        const int bb = (int)(rowBase >> 11);
        const int hw = cB >> 6;
        #pragma unroll
        for (int i = 0; i < 4; ++i) {
            float nr[4];
            #pragma unroll
            for (int r = 0; r < 4; ++r) {
                float s = 0.f;
                #pragma unroll
                for (int j = 0; j < 4; ++j) s += fabsf(acc[i][j][r] + bjv[j]);
                nr[r] = s;
            }
            #pragma unroll
            for (int off = 1; off < 16; off <<= 1) {
                #pragma unroll
                for (int r = 0; r < 4; ++r) nr[r] += __shfl_xor(nr[r], off);
            }
            if ((lane & 15) == 0) {
                const int trow = (int)(rowBase & (T_SEQ - 1)) + wr * 64 + i * 16 + ((lane >> 4) << 2);
                f32x4 nv; nv.x = nr[0]; nv.y = nr[1]; nv.z = nr[2]; nv.w = nr[3];
                *(f32x4*)&norms[(size_t)(bb * NH + hw) * T_SEQ + trow] = nv;
            }
        }
        #pragma unroll
        for (int j = 0; j < 4; ++j)
            #pragma unroll
            for (int i = 0; i < 4; ++i)
                #pragma unroll
                for (int r = 0; r < 4; ++r)
                    qb[(size_t)(rB + i * 16 + r) * D_MODEL + cB + j * 16] = f2bf(acc[i][j][r] + bjv[j]);
    } else if (z == 1) {
        #pragma unroll
        for (int j = 0; j < 4; ++j) {
            const float bj = bk[cB + j * 16];
            #pragma unroll
            for (int i = 0; i < 4; ++i)
                #pragma unroll
                for (int r = 0; r < 4; ++r)
                    ko[(size_t)(rB + i * 16 + r) * D_MODEL + cB + j * 16] = f2bf(acc[i][j][r] + bj);
        }
    } else {
        const int bb = (int)(rowBase >> 11);
        const int tBase = (int)(rowBase & (T_SEQ - 1)) + rL;
        #pragma unroll
        for (int j = 0; j < 4; ++j) {
            const int dg = cB + j * 16;
            const float bj = bv[dg];
            ushort_t* vrow = vT + ((size_t)(bb * NH) * HD + dg) * T_SEQ;
            #pragma unroll
            for (int i = 0; i < 4; ++i) {
                s16x4 pk;
                #pragma unroll
                for (int r = 0; r < 4; ++r)
                    pk[r] = (short)f2bf(acc[i][j][r] + bj);
                *(s16x4*)&vrow[tBase + i * 16] = pk;
            }
        }
    }
}

// ---------------------------------------------------------------------------
// topk_select: zero selmask; 3-pass radix -> v38; emit band {n >= v38 - 0.4}.
// ---------------------------------------------------------------------------
__global__ __launch_bounds__(256) void topk_select(
    const float* __restrict__ norms, int* __restrict__ cand_t, int* __restrict__ cand_cnt,
    unsigned* __restrict__ selmask)
{
    const int bh = blockIdx.x;
    const int tid = threadIdx.x;
    const int lane = tid & 63;
    const int w = tid >> 6;

    if (tid < 128) selmask[bh * 128 + tid] = 0u;

    __shared__ unsigned keys[T_SEQ];
    __shared__ unsigned hist[2048];
    __shared__ unsigned wsum[4];
    __shared__ unsigned bc_bin, bc_above;
    __shared__ int cnt;

    const float* nr = norms + (size_t)bh * T_SEQ;
    #pragma unroll
    for (int j = 0; j < 8; ++j)
        keys[tid + j * 256] = __float_as_uint(nr[tid + j * 256]);

    const int  shifts[3] = {21, 10, 0};
    const unsigned binm[3]  = {0x7FFu, 0x7FFu, 0x3FFu};
    const unsigned prefm[3] = {0x00000000u, 0xFFE00000u, 0xFFFFFC00u};

    unsigned prefix = 0;
    unsigned K_rem = U_SEL;

    for (int p = 0; p < 3; ++p) {
        #pragma unroll
        for (int j = 0; j < 8; ++j) hist[tid + j * 256] = 0;
        __syncthreads();
        #pragma unroll
        for (int j = 0; j < 8; ++j) {
            const unsigned k = keys[tid + j * 256];
            if ((k & prefm[p]) == prefix)
                atomicAdd(&hist[(k >> shifts[p]) & binm[p]], 1u);
        }
        __syncthreads();

        unsigned s = 0;
        #pragma unroll
        for (int e = 0; e < 8; ++e) s += hist[tid * 8 + e];
        unsigned v = s;
        #pragma unroll
        for (int off = 1; off < 64; off <<= 1) {
            const unsigned o = __shfl_down((int)v, off);
            if (lane + off < 64) v += o;
        }
        if (lane == 0) wsum[w] = v;
        __syncthreads();
        unsigned suf = v;
        for (int ww = w + 1; ww < 4; ++ww) suf += wsum[ww];
        const unsigned suf_next = suf - s;

        if (suf >= K_rem && suf_next < K_rem) {
            unsigned acc = suf_next;
            #pragma unroll
            for (int e = 7; e >= 0; --e) {
                const unsigned nb = hist[tid * 8 + e];
                if (acc + nb >= K_rem) { bc_bin = tid * 8 + e; bc_above = acc; break; }
                acc += nb;
            }
        }
        __syncthreads();
        prefix |= bc_bin << shifts[p];
        K_rem -= bc_above;
        __syncthreads();
    }

    const float thr = __uint_as_float(prefix) - 0.4f;
    if (tid == 0) cnt = 0;
    __syncthreads();
    #pragma unroll
    for (int j = 0; j < 8; ++j) {
        const int i = tid + j * 256;
        if (__uint_as_float(keys[i]) >= thr) {
            const int s = atomicAdd(&cnt, 1);
            if (s < CAND_CAP) cand_t[bh * CAND_CAP + s] = i;
        }
    }
    __syncthreads();
    if (tid == 0) cand_cnt[bh] = cnt < CAND_CAP ? cnt : CAND_CAP;
}

// ---------------------------------------------------------------------------
// fixup_norms: one block per (bh, candidate). Exact f32 q-row norm from x, Wq.
// ---------------------------------------------------------------------------
__global__ __launch_bounds__(256) void fixup_norms(
    const float* __restrict__ x, const float* __restrict__ Wq,
    const float* __restrict__ bq, const int* __restrict__ cand_t,
    const int* __restrict__ cand_cnt, float* __restrict__ n_exact)
{
    const int bh = blockIdx.x, c = blockIdx.y;
    const int b = bh >> 4, h = bh & 15;
    if (c >= cand_cnt[bh]) return;
    const int t = cand_t[bh * CAND_CAP + c];
    const int tid = threadIdx.x, d = tid & 63, kq = tid >> 6;

    __shared__ float xs[D_MODEL];
    __shared__ float part[4][HD];

    *(f32x4*)&xs[tid * 4] = *(const f32x4*)&x[((size_t)(b * T_SEQ + t)) * D_MODEL + tid * 4];
    __syncthreads();

    const float* wp = Wq + (size_t)(kq * 256) * D_MODEL + h * HD + d;
    const float* xp = &xs[kq * 256];
    float a0 = 0.f, a1 = 0.f, a2 = 0.f, a3 = 0.f;
    #pragma unroll 4
    for (int k = 0; k < 256; k += 4) {
        a0 += xp[k]     * wp[(k)     * D_MODEL];
        a1 += xp[k + 1] * wp[(k + 1) * D_MODEL];
        a2 += xp[k + 2] * wp[(k + 2) * D_MODEL];
        a3 += xp[k + 3] * wp[(k + 3) * D_MODEL];
    }
    part[kq][d] = (a0 + a1) + (a2 + a3);
    __syncthreads();
    if (tid < 64) {
        float v = fabsf(part[0][tid] + part[1][tid] + part[2][tid] + part[3][tid]
                        + bq[h * HD + tid]);
        #pragma unroll
        for (int off = 1; off < 64; off <<= 1) v += __shfl_xor(v, off);
        if (tid == 0) n_exact[bh * CAND_CAP + c] = v;
    }
}

// ---------------------------------------------------------------------------
// fixup_select: PARALLEL rank-select. (n, -t) is a strict total order (t
// unique) -> rank_i = #{j : (n_j,-t_j) > (n_i,-t_i)} is a bijection; the
// top-38 are exactly rank < 38. One thread per candidate, no serial rounds.
// ---------------------------------------------------------------------------
__global__ __launch_bounds__(128) void fixup_select(
    const float* __restrict__ n_exact, const int* __restrict__ cand_t,
    const int* __restrict__ cand_cnt, int* __restrict__ idx_out,
    unsigned* __restrict__ selmask, int* __restrict__ selu)
{
    const int bh = blockIdx.x;
    const int tid = threadIdx.x;
    const int nc = cand_cnt[bh];
    const int b = bh >> 4, h = bh & 15;

    __shared__ float nv[CAND_CAP];
    __shared__ int   tv[CAND_CAP];

    if (tid < nc) {
        nv[tid] = n_exact[bh * CAND_CAP + tid];
        tv[tid] = cand_t[bh * CAND_CAP + tid];
    }
    __syncthreads();

    if (tid < nc) {
        const float ni = nv[tid];
        const int   ti = tv[tid];
        int rank = 0;
        for (int j = 0; j < nc; ++j) {
            const float njv = nv[j];
            const int   tj  = tv[j];
            rank += (njv > ni || (njv == ni && tj < ti)) ? 1 : 0;
        }
        if (rank < U_SEL) {
            idx_out[bh * U_SEL + rank] = ti;
            const int row = (b << 11) + ti;
            atomicOr(&selmask[row], 1u << h);
            selu[row * NH + h] = rank;
        }
    }
}

// ---------------------------------------------------------------------------
// attn_scores: S + per-(u,chunk) softmax stats (max, sumexp w/ chunk max).
// Grid (32 bh, 8 t-chunks, 2 u-groups of 19). K row in 64 VGPRs, reused.
// ---------------------------------------------------------------------------
__global__ __launch_bounds__(256) void attn_scores(
    const ushort_t* __restrict__ qb, const ushort_t* __restrict__ kk_,
    const int* __restrict__ idx, float* __restrict__ S,
    float* __restrict__ mstat, float* __restrict__ lstat)
{
    const int bh = blockIdx.x, ch = blockIdx.y, ug = blockIdx.z;
    const int b = bh >> 4, h = bh & 15;
    const int tid = threadIdx.x;
    const int lane = tid & 63;
    const int w = tid >> 6;
    const int t = ch * 256 + tid;
    const int u0 = ug * 19;

    __shared__ float qs[19][HD];
    __shared__ int qis[19];
    __shared__ float mpart[19][4];
    __shared__ float lpart[19][4];

    if (tid < 19) qis[tid] = idx[bh * U_SEL + u0 + tid];
    if (tid < 76) { mpart[tid >> 2][tid & 3] = -1e30f; lpart[tid >> 2][tid & 3] = 0.f; }
    __syncthreads();
    for (int e = tid; e < 19 * HD; e += 256) {
        const int u = e >> 6, d = e & 63;
        qs[u][d] = bf2f(qb[((size_t)(b * T_SEQ + qis[u])) * D_MODEL + h * HD + d]) * 0.125f;
    }

    float kr[64];
    {
        const ushort_t* kp = kk_ + ((size_t)(b * T_SEQ + t)) * D_MODEL + h * HD;
        #pragma unroll
        for (int d0 = 0; d0 < 64; d0 += 8) {
            const s16x8 r = *(const s16x8*)(kp + d0);
            #pragma unroll
            for (int e = 0; e < 8; ++e) kr[d0 + e] = bf2f((unsigned short)r[e]);
        }
    }
    __syncthreads();

    const int wbase = ch * 256 + (tid & ~63);   // wave's min t (uniform)
    for (int uu = 0; uu < 19; ++uu) {
        const int qi = qis[uu];
        if (wbase > qi) continue;               // wave-uniform skip
        float sp0 = 0.f, sp1 = 0.f, sp2 = 0.f, sp3 = 0.f;
        #pragma unroll
        for (int d0 = 0; d0 < 64; d0 += 16) {
            const f32x4 q0 = *(const f32x4*)&qs[uu][d0];
            const f32x4 q1 = *(const f32x4*)&qs[uu][d0 + 4];
            const f32x4 q2 = *(const f32x4*)&qs[uu][d0 + 8];
            const f32x4 q3 = *(const f32x4*)&qs[uu][d0 + 12];
            sp0 += q0.x * kr[d0] + q0.y * kr[d0 + 1] + q0.z * kr[d0 + 2] + q0.w * kr[d0 + 3];
            sp1 += q1.x * kr[d0 + 4] + q1.y * kr[d0 + 5] + q1.z * kr[d0 + 6] + q1.w * kr[d0 + 7];
            sp2 += q2.x * kr[d0 + 8] + q2.y * kr[d0 + 9] + q2.z * kr[d0 + 10] + q2.w * kr[d0 + 11];
            sp3 += q3.x * kr[d0 + 12] + q3.y * kr[d0 + 13] + q3.z * kr[d0 + 14] + q3.w * kr[d0 + 15];
        }
        const float s = sp0 + sp1 + sp2 + sp3;
        S[((size_t)(bh * U_SEL + u0 + uu)) * T_SEQ + t] = s;
        const float sm = (t <= qi) ? s : -1e30f;
        float mw = sm;
        #pragma unroll
        for (int off = 1; off < 64; off <<= 1) mw = fmaxf(mw, __shfl_xor(mw, off));
        float p = (t <= qi) ? __expf(s - mw) : 0.f;
        #pragma unroll
        for (int off = 1; off < 64; off <<= 1) p += __shfl_xor(p, off);
        if (lane == 0) { mpart[uu][w] = mw; lpart[uu][w] = p; }
    }
    __syncthreads();
    if (tid < 19) {
        float M = -1e30f;
        #pragma unroll
        for (int ww = 0; ww < 4; ++ww) M = fmaxf(M, mpart[tid][ww]);
        float L = 0.f;
        #pragma unroll
        for (int ww = 0; ww < 4; ++ww) {
            const float mw = mpart[tid][ww];
            if (mw > -1e29f) L += lpart[tid][ww] * __expf(mw - M);
        }
        const size_t si = (size_t)(bh * U_SEL + u0 + tid) * NCH + ch;
        mstat[si] = M;
        lstat[si] = L;
    }
}

// ---------------------------------------------------------------------------
// attn_pv: one block per (bh,u). Stats-merged M,L; single exp pass; PV along
// contiguous t of transposed V.
// ---------------------------------------------------------------------------
__global__ __launch_bounds__(256) void attn_pv(
    const float* __restrict__ S, const ushort_t* __restrict__ vT,
    const int* __restrict__ idx, const float* __restrict__ mstat,
    const float* __restrict__ lstat, float* __restrict__ sel_out)
{
    const int bh = blockIdx.x, u = blockIdx.y;
    const int tid = threadIdx.x;
    const int d = tid & 63;
    const int qtr = tid >> 6;
    const int qi = idx[bh * U_SEL + u];
    const int nk = qi + 1;
    const int pad8 = (nk + 7) & ~7;
    const float* Srow = S + ((size_t)(bh * U_SEL + u)) * T_SEQ;

    __shared__ float sc[T_SEQ];
    __shared__ float part[4][HD];

    const float* mp = mstat + (size_t)(bh * U_SEL + u) * NCH;
    const float* lp = lstat + (size_t)(bh * U_SEL + u) * NCH;
    float M = -1e30f;
    #pragma unroll
    for (int c = 0; c < NCH; ++c) M = fmaxf(M, mp[c]);
    float L = 0.f;
    #pragma unroll
    for (int c = 0; c < NCH; ++c) {
        const float mc = mp[c];
        if (mc > -1e29f) L += lp[c] * __expf(mc - M);
    }

    for (int t = tid; t < nk; t += 256) sc[t] = __expf(Srow[t] - M);
    if (tid < 7) { const int t = nk + tid; if (t < pad8) sc[t] = 0.f; }
    __syncthreads();

    const ushort_t* vrow = vT + ((size_t)(bh * HD + d)) * T_SEQ;
    float a0 = 0.f, a1 = 0.f;
    #pragma unroll
    for (int mm = 0; mm < 4; ++mm) {
        const int base = mm * 512 + qtr * 128;
        if (base >= nk) break;
        const int bend = base + 128 < pad8 ? base + 128 : pad8;
        for (int t = base; t < bend; t += 8) {
            const s16x8 v8 = *(const s16x8*)(vrow + t);
            const f32x4 p0 = *(const f32x4*)&sc[t];
            const f32x4 p1 = *(const f32x4*)&sc[t + 4];
            a0 += p0.x * bf2f((unsigned short)v8[0]) + p0.y * bf2f((unsigned short)v8[1])
                + p0.z * bf2f((unsigned short)v8[2]) + p0.w * bf2f((unsigned short)v8[3]);
            a1 += p1.x * bf2f((unsigned short)v8[4]) + p1.y * bf2f((unsigned short)v8[5])
                + p1.z * bf2f((unsigned short)v8[6]) + p1.w * bf2f((unsigned short)v8[7]);
        }
    }
    part[qtr][d] = a0 + a1;
    __syncthreads();
    if (tid < HD)
        sel_out[((size_t)(bh * U_SEL + u)) * HD + tid] =
            (part[0][tid] + part[1][tid] + part[2][tid] + part[3][tid]) / L;
}

// ---------------------------------------------------------------------------
// out_proj: one block per output row (b,t). out = bo + sum over owning heads.
// ---------------------------------------------------------------------------
__global__ __launch_bounds__(256) void out_proj(
    const float* __restrict__ sel_out, const float* __restrict__ Wo,
    const float* __restrict__ bo, const unsigned* __restrict__ selmask,
    const int* __restrict__ selu, float* __restrict__ out)
{
    const int row = blockIdx.x;               // 0..4095
    const int b = row >> 11;
    const int tid = threadIdx.x;
    const int c0 = tid * 4;

    __shared__ float s[HD];
    f32x4 o = *(const f32x4*)&bo[c0];
    unsigned mask = selmask[row];

    while (mask) {
        const int h = __ffs(mask) - 1;
        mask &= mask - 1;
        const int u = selu[row * NH + h];
        if (tid < HD)
            s[tid] = sel_out[((size_t)((b * NH + h) * U_SEL + u)) * HD + tid];
        __syncthreads();
        #pragma unroll 8
        for (int r = 0; r < HD; ++r) {
            const float sv = s[r];
            const f32x4 w4 = *(const f32x4*)&Wo[((size_t)(h * HD + r)) * D_MODEL + c0];
            o.x += sv * w4.x; o.y += sv * w4.y; o.z += sv * w4.z; o.w += sv * w4.w;
        }
        __syncthreads();
    }
    *(f32x4*)&out[(size_t)row * D_MODEL + c0] = o;
}

// ---------------------------------------------------------------------------
extern "C" void kernel_launch(void* const* d_in, const int* in_sizes, int n_in,
                              void* d_out, int out_size, void* d_ws, size_t ws_size,
                              hipStream_t stream)
{
    const float* x  = (const float*)d_in[0];
    const float* Wq = (const float*)d_in[1];
    const float* bq = (const float*)d_in[2];
    const float* Wk = (const float*)d_in[3];
    const float* bk = (const float*)d_in[4];
    const float* Wv = (const float*)d_in[5];
    const float* bv = (const float*)d_in[6];
    const float* Wo = (const float*)d_in[7];
    const float* bo = (const float*)d_in[8];
    float* out = (float*)d_out;

    // workspace layout (~49 MB; ws >= 58 MB proven in round 5)
    char* ws = (char*)d_ws;
    ushort_t* xh      = (ushort_t*)(ws);                              //  8 MB
    ushort_t* wqhT    = (ushort_t*)(ws + (8u << 20));                 //  2 MB
    ushort_t* wkhT    = (ushort_t*)(ws + (10u << 20));                //  2 MB
    ushort_t* wvhT    = (ushort_t*)(ws + (12u << 20));                //  2 MB
    ushort_t* k       = (ushort_t*)(ws + (14u << 20));                //  8 MB
    ushort_t* vT      = (ushort_t*)(ws + (22u << 20));                //  8 MB
    ushort_t* qb      = (ushort_t*)(ws + (30u << 20));                //  8 MB (Q bf16)
    float*    S       = (float*)(ws + (38u << 20));                   // 10 MB
    float*    norms   = (float*)(ws + (48u << 20));                   // 256 KB
    int*      cand_t  = (int*)(ws + (48u << 20) + (256u << 10));      // 12 KB
    int*      cand_cnt= (int*)(ws + (48u << 20) + (272u << 10));      // 128 B
    float*    n_exact = (float*)(ws + (48u << 20) + (276u << 10));    // 12 KB
    int*      idx     = (int*)(ws + (48u << 20) + (292u << 10));      // ~5 KB
    float*    sel_out = (float*)(ws + (48u << 20) + (300u << 10));    // 304 KB
    unsigned* selmask = (unsigned*)(ws + (48u << 20) + (640u << 10)); // 16 KB
    int*      selu    = (int*)(ws + (48u << 20) + (656u << 10));      // 256 KB
    float*    mstat   = (float*)(ws + (48u << 20) + (912u << 10));    // 38 KB
    float*    lstat   = (float*)(ws + (48u << 20) + (960u << 10));    // 38 KB

    prep<<<2048 + 768, 256, 0, stream>>>(x, Wq, Wk, Wv, xh, wqhT, wkhT, wvhT);
    {
        dim3 g((NB * T_SEQ) / GBM, D_MODEL / GBN, 3);
        qkv_mfma<<<g, 256, 0, stream>>>(xh, wqhT, wkhT, wvhT, bq, bk, bv,
                                        qb, k, vT, norms);
    }
    topk_select<<<NB * NH, 256, 0, stream>>>(norms, cand_t, cand_cnt, selmask);
    {
        dim3 g(NB * NH, CAND_CAP);
        fixup_norms<<<g, 256, 0, stream>>>(x, Wq, bq, cand_t, cand_cnt, n_exact);
    }
    fixup_select<<<NB * NH, 128, 0, stream>>>(n_exact, cand_t, cand_cnt, idx, selmask, selu);
    {
        dim3 g(NB * NH, T_SEQ / 256, 2);
        attn_scores<<<g, 256, 0, stream>>>(qb, k, idx, S, mstat, lstat);
    }
    {
        dim3 g(NB * NH, U_SEL);
        attn_pv<<<g, 256, 0, stream>>>(S, vT, idx, mstat, lstat, sel_out);
    }
    out_proj<<<NB * T_SEQ, 256, 0, stream>>>(sel_out, Wo, bo, selmask, selu, out);
}

// Round 12
// 150.664 us; speedup vs baseline: 1.7805x; 1.0737x over previous
//
#include <hip/hip_runtime.h>

#define NB 2
#define T_SEQ 2048
#define D_MODEL 1024
#define NH 16
#define HD 64
#define U_SEL 38
#define CAND_CAP 96
#define NCH 8          // t-chunks of 256 in scores/stats

typedef __attribute__((ext_vector_type(8))) short s16x8;
typedef __attribute__((ext_vector_type(4))) short s16x4;
typedef __attribute__((ext_vector_type(4))) float f32x4;
typedef unsigned short ushort_t;

__device__ __forceinline__ unsigned short f2bf(float f) {
    unsigned u = __float_as_uint(f);
    u += 0x7FFFu + ((u >> 16) & 1u);          // RNE
    return (unsigned short)(u >> 16);
}
__device__ __forceinline__ float bf2f(unsigned short h) {
    return __uint_as_float(((unsigned)h) << 16);
}

__device__ __forceinline__ void async_copy16(const void* g, void* l) {
    __builtin_amdgcn_global_load_lds(
        (const __attribute__((address_space(1))) void*)g,
        (__attribute__((address_space(3))) void*)l, 16, 0, 0);
}

// ---------------------------------------------------------------------------
// prep: blocks [0,2048): x -> xh (bf16). blocks [2048,2816): W -> W^T bf16.
// ---------------------------------------------------------------------------
__global__ __launch_bounds__(256) void prep(
    const float* __restrict__ x,
    const float* __restrict__ Wq, const float* __restrict__ Wk, const float* __restrict__ Wv,
    ushort_t* __restrict__ xh,
    ushort_t* __restrict__ wqhT, ushort_t* __restrict__ wkhT, ushort_t* __restrict__ wvhT)
{
    __shared__ float T[64][68];
    const int tid = threadIdx.x;
    if (blockIdx.x < 2048) {
        const size_t i0 = ((size_t)blockIdx.x * 256 + tid) * 8;
        const f32x4 a = *(const f32x4*)(x + i0);
        const f32x4 b = *(const f32x4*)(x + i0 + 4);
        const float f[8] = {a.x, a.y, a.z, a.w, b.x, b.y, b.z, b.w};
        s16x8 hi;
        #pragma unroll
        for (int e = 0; e < 8; ++e) hi[e] = (short)f2bf(f[e]);
        *(s16x8*)(xh + i0) = hi;
        return;
    }
    const int id2 = blockIdx.x - 2048;
    const int z = id2 >> 8;
    const int rem = id2 & 255;
    const int k0 = (rem & 15) * 64, n0 = (rem >> 4) * 64;
    const float* W = (z == 0) ? Wq : (z == 1) ? Wk : Wv;

    #pragma unroll
    for (int i = 0; i < 4; ++i) {
        const int r = (tid >> 4) + i * 16, c = (tid & 15) * 4;
        *(f32x4*)&T[r][c] = *(const f32x4*)&W[(size_t)(k0 + r) * D_MODEL + n0 + c];
    }
    __syncthreads();

    const int n = tid >> 2, kq = (tid & 3) * 16;
    s16x8 hi0, hi1;
    #pragma unroll
    for (int j = 0; j < 16; ++j) {
        const float f = T[kq + j][n];
        if (j < 8) hi0[j] = (short)f2bf(f);
        else       hi1[j - 8] = (short)f2bf(f);
    }
    ushort_t* oh = (z == 0) ? wqhT : (z == 1) ? wkhT : wvhT;
    const size_t ob = (size_t)(n0 + n) * D_MODEL + k0 + kq;
    *(s16x8*)(oh + ob) = hi0;
    *(s16x8*)(oh + ob + 8) = hi1;
}

// ---------------------------------------------------------------------------
// qkv_mfma: 128x128 tile, BK=32, 4 waves, global_load_lds width 16, source-
// swizzled (0 bank conflicts, r9), __launch_bounds__(256,4) (occupancy, r10).
//  z0: per-(b,h,t) L1 norms ONLY (no Q store — selected q rows come from
//      fixup_norms' exact recompute).  z1: K bf16.  z2: V -> vT transposed.
// ---------------------------------------------------------------------------
#define GBM 128
#define GBN 128
#define GBK 32

__global__ __launch_bounds__(256, 4) void qkv_mfma(
    const ushort_t* __restrict__ xh,
    const ushort_t* __restrict__ wqhT, const ushort_t* __restrict__ wkhT,
    const ushort_t* __restrict__ wvhT,
    const float* __restrict__ bq, const float* __restrict__ bk, const float* __restrict__ bv,
    ushort_t* __restrict__ ko, ushort_t* __restrict__ vT,
    float* __restrict__ norms)
{
    const int z = blockIdx.z;
    __shared__ ushort_t Ah[GBM * GBK];
    __shared__ ushort_t Bh[GBN * GBK];

    const int tid = threadIdx.x;
    const int lane = tid & 63;
    const int wid = tid >> 6;
    const int wr = wid >> 1, wc = wid & 1;
    const size_t rowBase = (size_t)blockIdx.x * GBM;
    const size_t colBase = (size_t)blockIdx.y * GBN;

    const ushort_t* B0 = (z == 0) ? wqhT : (z == 1) ? wkhT : wvhT;
    const int srow = tid >> 2;                       // 0..63
    const int sl0  = ((tid & 3) - (srow >> 1)) & 3;  // pre-swizzled source slot
    const int skq  = sl0 * 8;

    const ushort_t* pA0 = xh + (rowBase + srow) * D_MODEL + skq;
    const ushort_t* pA1 = pA0 + (size_t)64 * D_MODEL;
    const ushort_t* pB0 = B0 + (colBase + srow) * D_MODEL + skq;
    const ushort_t* pB1 = pB0 + (size_t)64 * D_MODEL;
    ushort_t* lA0 = &Ah[tid * 8];
    ushort_t* lA1 = &Ah[2048 + tid * 8];
    ushort_t* lB0 = &Bh[tid * 8];
    ushort_t* lB1 = &Bh[2048 + tid * 8];

    int aph[4], bph[4];
    #pragma unroll
    for (int i = 0; i < 4; ++i) {
        const int arow = wr * 64 + i * 16 + (lane & 15);
        aph[i] = arow * GBK + ((((lane >> 4) + (arow >> 1)) & 3) << 3);
        const int brow = wc * 64 + i * 16 + (lane & 15);
        bph[i] = brow * GBK + ((((lane >> 4) + (brow >> 1)) & 3) << 3);
    }

    f32x4 acc[4][4] = {};

    for (int kk = 0; kk < 32; ++kk) {
        async_copy16(pA0, lA0);
        async_copy16(pA1, lA1);
        async_copy16(pB0, lB0);
        async_copy16(pB1, lB1);
        pA0 += GBK; pA1 += GBK; pB0 += GBK; pB1 += GBK;
        __syncthreads();

        s16x8 bf[4];
        #pragma unroll
        for (int j = 0; j < 4; ++j) bf[j] = *(const s16x8*)&Bh[bph[j]];
        #pragma unroll
        for (int i = 0; i < 4; ++i) {
            const s16x8 af = *(const s16x8*)&Ah[aph[i]];
            #pragma unroll
            for (int j = 0; j < 4; ++j)
                acc[i][j] = __builtin_amdgcn_mfma_f32_16x16x32_bf16(af, bf[j], acc[i][j], 0, 0, 0);
        }
        __syncthreads();
    }

    // epilogue: C/D layout col=lane&15, row=(lane>>4)*4+r
    const int cB = (int)colBase + wc * 64 + (lane & 15);
    const int rL = wr * 64 + ((lane >> 4) << 2);
    const int rB = (int)rowBase + rL;
    if (z == 0) {
        float bjv[4];
        #pragma unroll
        for (int j = 0; j < 4; ++j) bjv[j] = bq[cB + j * 16];
        const int bb = (int)(rowBase >> 11);
        const int hw = cB >> 6;
        #pragma unroll
        for (int i = 0; i < 4; ++i) {
            float nr[4];
            #pragma unroll
            for (int r = 0; r < 4; ++r) {
                float s = 0.f;
                #pragma unroll
                for (int j = 0; j < 4; ++j) s += fabsf(acc[i][j][r] + bjv[j]);
                nr[r] = s;
            }
            #pragma unroll
            for (int off = 1; off < 16; off <<= 1) {
                #pragma unroll
                for (int r = 0; r < 4; ++r) nr[r] += __shfl_xor(nr[r], off);
            }
            if ((lane & 15) == 0) {
                const int trow = (int)(rowBase & (T_SEQ - 1)) + wr * 64 + i * 16 + ((lane >> 4) << 2);
                f32x4 nv; nv.x = nr[0]; nv.y = nr[1]; nv.z = nr[2]; nv.w = nr[3];
                *(f32x4*)&norms[(size_t)(bb * NH + hw) * T_SEQ + trow] = nv;
            }
        }
    } else if (z == 1) {
        #pragma unroll
        for (int j = 0; j < 4; ++j) {
            const float bj = bk[cB + j * 16];
            #pragma unroll
            for (int i = 0; i < 4; ++i)
                #pragma unroll
                for (int r = 0; r < 4; ++r)
                    ko[(size_t)(rB + i * 16 + r) * D_MODEL + cB + j * 16] = f2bf(acc[i][j][r] + bj);
        }
    } else {
        const int bb = (int)(rowBase >> 11);
        const int tBase = (int)(rowBase & (T_SEQ - 1)) + rL;
        #pragma unroll
        for (int j = 0; j < 4; ++j) {
            const int dg = cB + j * 16;
            const float bj = bv[dg];
            ushort_t* vrow = vT + ((size_t)(bb * NH) * HD + dg) * T_SEQ;
            #pragma unroll
            for (int i = 0; i < 4; ++i) {
                s16x4 pk;
                #pragma unroll
                for (int r = 0; r < 4; ++r)
                    pk[r] = (short)f2bf(acc[i][j][r] + bj);
                *(s16x4*)&vrow[tBase + i * 16] = pk;
            }
        }
    }
}

// ---------------------------------------------------------------------------
// topk_select: zero selmask; 3-pass radix -> v38; emit band {n >= v38 - 0.4}.
// ---------------------------------------------------------------------------
__global__ __launch_bounds__(256) void topk_select(
    const float* __restrict__ norms, int* __restrict__ cand_t, int* __restrict__ cand_cnt,
    unsigned* __restrict__ selmask)
{
    const int bh = blockIdx.x;
    const int tid = threadIdx.x;
    const int lane = tid & 63;
    const int w = tid >> 6;

    if (tid < 128) selmask[bh * 128 + tid] = 0u;

    __shared__ unsigned keys[T_SEQ];
    __shared__ unsigned hist[2048];
    __shared__ unsigned wsum[4];
    __shared__ unsigned bc_bin, bc_above;
    __shared__ int cnt;

    const float* nr = norms + (size_t)bh * T_SEQ;
    #pragma unroll
    for (int j = 0; j < 8; ++j)
        keys[tid + j * 256] = __float_as_uint(nr[tid + j * 256]);

    const int  shifts[3] = {21, 10, 0};
    const unsigned binm[3]  = {0x7FFu, 0x7FFu, 0x3FFu};
    const unsigned prefm[3] = {0x00000000u, 0xFFE00000u, 0xFFFFFC00u};

    unsigned prefix = 0;
    unsigned K_rem = U_SEL;

    for (int p = 0; p < 3; ++p) {
        #pragma unroll
        for (int j = 0; j < 8; ++j) hist[tid + j * 256] = 0;
        __syncthreads();
        #pragma unroll
        for (int j = 0; j < 8; ++j) {
            const unsigned k = keys[tid + j * 256];
            if ((k & prefm[p]) == prefix)
                atomicAdd(&hist[(k >> shifts[p]) & binm[p]], 1u);
        }
        __syncthreads();

        unsigned s = 0;
        #pragma unroll
        for (int e = 0; e < 8; ++e) s += hist[tid * 8 + e];
        unsigned v = s;
        #pragma unroll
        for (int off = 1; off < 64; off <<= 1) {
            const unsigned o = __shfl_down((int)v, off);
            if (lane + off < 64) v += o;
        }
        if (lane == 0) wsum[w] = v;
        __syncthreads();
        unsigned suf = v;
        for (int ww = w + 1; ww < 4; ++ww) suf += wsum[ww];
        const unsigned suf_next = suf - s;

        if (suf >= K_rem && suf_next < K_rem) {
            unsigned acc = suf_next;
            #pragma unroll
            for (int e = 7; e >= 0; --e) {
                const unsigned nb = hist[tid * 8 + e];
                if (acc + nb >= K_rem) { bc_bin = tid * 8 + e; bc_above = acc; break; }
                acc += nb;
            }
        }
        __syncthreads();
        prefix |= bc_bin << shifts[p];
        K_rem -= bc_above;
        __syncthreads();
    }

    const float thr = __uint_as_float(prefix) - 0.4f;
    if (tid == 0) cnt = 0;
    __syncthreads();
    #pragma unroll
    for (int j = 0; j < 8; ++j) {
        const int i = tid + j * 256;
        if (__uint_as_float(keys[i]) >= thr) {
            const int s = atomicAdd(&cnt, 1);
            if (s < CAND_CAP) cand_t[bh * CAND_CAP + s] = i;
        }
    }
    __syncthreads();
    if (tid == 0) cand_cnt[bh] = cnt < CAND_CAP ? cnt : CAND_CAP;
}

// ---------------------------------------------------------------------------
// fixup_norms: one block per (bh, candidate). Exact f32 q-row from x, Wq:
// stores BOTH the L1 norm and the exact q row (for attn_scores).
// ---------------------------------------------------------------------------
__global__ __launch_bounds__(256) void fixup_norms(
    const float* __restrict__ x, const float* __restrict__ Wq,
    const float* __restrict__ bq, const int* __restrict__ cand_t,
    const int* __restrict__ cand_cnt, float* __restrict__ n_exact,
    float* __restrict__ q_exact)
{
    const int bh = blockIdx.x, c = blockIdx.y;
    const int b = bh >> 4, h = bh & 15;
    if (c >= cand_cnt[bh]) return;
    const int t = cand_t[bh * CAND_CAP + c];
    const int tid = threadIdx.x, d = tid & 63, kq = tid >> 6;

    __shared__ float xs[D_MODEL];
    __shared__ float part[4][HD];

    *(f32x4*)&xs[tid * 4] = *(const f32x4*)&x[((size_t)(b * T_SEQ + t)) * D_MODEL + tid * 4];
    __syncthreads();

    const float* wp = Wq + (size_t)(kq * 256) * D_MODEL + h * HD + d;
    const float* xp = &xs[kq * 256];
    float a0 = 0.f, a1 = 0.f, a2 = 0.f, a3 = 0.f;
    #pragma unroll 4
    for (int k = 0; k < 256; k += 4) {
        a0 += xp[k]     * wp[(k)     * D_MODEL];
        a1 += xp[k + 1] * wp[(k + 1) * D_MODEL];
        a2 += xp[k + 2] * wp[(k + 2) * D_MODEL];
        a3 += xp[k + 3] * wp[(k + 3) * D_MODEL];
    }
    part[kq][d] = (a0 + a1) + (a2 + a3);
    __syncthreads();
    if (tid < 64) {
        const float qd = part[0][tid] + part[1][tid] + part[2][tid] + part[3][tid]
                       + bq[h * HD + tid];
        q_exact[((size_t)(bh * CAND_CAP + c)) * HD + tid] = qd;
        float v = fabsf(qd);
        #pragma unroll
        for (int off = 1; off < 64; off <<= 1) v += __shfl_xor(v, off);
        if (tid == 0) n_exact[bh * CAND_CAP + c] = v;
    }
}

// ---------------------------------------------------------------------------
// fixup_select: PARALLEL rank-select ((n,-t) strict total order). Also
// records rank -> candidate slot for attn_scores' q_exact gather.
// ---------------------------------------------------------------------------
__global__ __launch_bounds__(128) void fixup_select(
    const float* __restrict__ n_exact, const int* __restrict__ cand_t,
    const int* __restrict__ cand_cnt, int* __restrict__ idx_out,
    unsigned* __restrict__ selmask, int* __restrict__ selu,
    int* __restrict__ rank2c)
{
    const int bh = blockIdx.x;
    const int tid = threadIdx.x;
    const int nc = cand_cnt[bh];
    const int b = bh >> 4, h = bh & 15;

    __shared__ float nv[CAND_CAP];
    __shared__ int   tv[CAND_CAP];

    if (tid < nc) {
        nv[tid] = n_exact[bh * CAND_CAP + tid];
        tv[tid] = cand_t[bh * CAND_CAP + tid];
    }
    __syncthreads();

    if (tid < nc) {
        const float ni = nv[tid];
        const int   ti = tv[tid];
        int rank = 0;
        for (int j = 0; j < nc; ++j) {
            const float njv = nv[j];
            const int   tj  = tv[j];
            rank += (njv > ni || (njv == ni && tj < ti)) ? 1 : 0;
        }
        if (rank < U_SEL) {
            idx_out[bh * U_SEL + rank] = ti;
            rank2c[bh * U_SEL + rank] = tid;
            const int row = (b << 11) + ti;
            atomicOr(&selmask[row], 1u << h);
            selu[row * NH + h] = rank;
        }
    }
}

// ---------------------------------------------------------------------------
// attn_scores: S + per-(u,chunk) softmax stats. q from q_exact (exact f32).
// Grid (32 bh, 8 t-chunks, 2 u-groups of 19). K row in 64 VGPRs, reused.
// ---------------------------------------------------------------------------
__global__ __launch_bounds__(256) void attn_scores(
    const float* __restrict__ q_exact, const int* __restrict__ rank2c,
    const ushort_t* __restrict__ kk_, const int* __restrict__ idx,
    float* __restrict__ S, float* __restrict__ mstat, float* __restrict__ lstat)
{
    const int bh = blockIdx.x, ch = blockIdx.y, ug = blockIdx.z;
    const int b = bh >> 4, h = bh & 15;
    const int tid = threadIdx.x;
    const int lane = tid & 63;
    const int w = tid >> 6;
    const int t = ch * 256 + tid;
    const int u0 = ug * 19;

    __shared__ float qs[19][HD];
    __shared__ int qis[19];
    __shared__ int qcs[19];
    __shared__ float mpart[19][4];
    __shared__ float lpart[19][4];

    if (tid < 19) {
        qis[tid] = idx[bh * U_SEL + u0 + tid];
        qcs[tid] = rank2c[bh * U_SEL + u0 + tid];
    }
    if (tid < 76) { mpart[tid >> 2][tid & 3] = -1e30f; lpart[tid >> 2][tid & 3] = 0.f; }
    __syncthreads();
    for (int e = tid; e < 19 * HD; e += 256) {
        const int u = e >> 6, d = e & 63;
        qs[u][d] = q_exact[((size_t)(bh * CAND_CAP + qcs[u])) * HD + d] * 0.125f;
    }

    float kr[64];
    {
        const ushort_t* kp = kk_ + ((size_t)(b * T_SEQ + t)) * D_MODEL + h * HD;
        #pragma unroll
        for (int d0 = 0; d0 < 64; d0 += 8) {
            const s16x8 r = *(const s16x8*)(kp + d0);
            #pragma unroll
            for (int e = 0; e < 8; ++e) kr[d0 + e] = bf2f((unsigned short)r[e]);
        }
    }
    __syncthreads();

    const int wbase = ch * 256 + (tid & ~63);   // wave's min t (uniform)
    for (int uu = 0; uu < 19; ++uu) {
        const int qi = qis[uu];
        if (wbase > qi) continue;               // wave-uniform skip
        float sp0 = 0.f, sp1 = 0.f, sp2 = 0.f, sp3 = 0.f;
        #pragma unroll
        for (int d0 = 0; d0 < 64; d0 += 16) {
            const f32x4 q0 = *(const f32x4*)&qs[uu][d0];
            const f32x4 q1 = *(const f32x4*)&qs[uu][d0 + 4];
            const f32x4 q2 = *(const f32x4*)&qs[uu][d0 + 8];
            const f32x4 q3 = *(const f32x4*)&qs[uu][d0 + 12];
            sp0 += q0.x * kr[d0] + q0.y * kr[d0 + 1] + q0.z * kr[d0 + 2] + q0.w * kr[d0 + 3];
            sp1 += q1.x * kr[d0 + 4] + q1.y * kr[d0 + 5] + q1.z * kr[d0 + 6] + q1.w * kr[d0 + 7];
            sp2 += q2.x * kr[d0 + 8] + q2.y * kr[d0 + 9] + q2.z * kr[d0 + 10] + q2.w * kr[d0 + 11];
            sp3 += q3.x * kr[d0 + 12] + q3.y * kr[d0 + 13] + q3.z * kr[d0 + 14] + q3.w * kr[d0 + 15];
        }
        const float s = sp0 + sp1 + sp2 + sp3;
        S[((size_t)(bh * U_SEL + u0 + uu)) * T_SEQ + t] = s;
        const float sm = (t <= qi) ? s : -1e30f;
        float mw = sm;
        #pragma unroll
        for (int off = 1; off < 64; off <<= 1) mw = fmaxf(mw, __shfl_xor(mw, off));
        float p = (t <= qi) ? __expf(s - mw) : 0.f;
        #pragma unroll
        for (int off = 1; off < 64; off <<= 1) p += __shfl_xor(p, off);
        if (lane == 0) { mpart[uu][w] = mw; lpart[uu][w] = p; }
    }
    __syncthreads();
    if (tid < 19) {
        float M = -1e30f;
        #pragma unroll
        for (int ww = 0; ww < 4; ++ww) M = fmaxf(M, mpart[tid][ww]);
        float L = 0.f;
        #pragma unroll
        for (int ww = 0; ww < 4; ++ww) {
            const float mw = mpart[tid][ww];
            if (mw > -1e29f) L += lpart[tid][ww] * __expf(mw - M);
        }
        const size_t si = (size_t)(bh * U_SEL + u0 + tid) * NCH + ch;
        mstat[si] = M;
        lstat[si] = L;
    }
}

// ---------------------------------------------------------------------------
// attn_pv: one block per (bh,u). Wave-per-d structure: wave w owns 16 d-rows;
// per 512-t chunk lane l covers t in [tb+8l, tb+8l+8): S read + exp in regs
// (coalesced 2KB/wave), then 16 coalesced 1KB/wave vT reads with 8 FMA each
// into 16 accumulators; final 64-lane shuffle reduce per d. LDS-free.
// ---------------------------------------------------------------------------
__global__ __launch_bounds__(256) void attn_pv(
    const float* __restrict__ S, const ushort_t* __restrict__ vT,
    const int* __restrict__ idx, const float* __restrict__ mstat,
    const float* __restrict__ lstat, float* __restrict__ sel_out)
{
    const int bh = blockIdx.x, u = blockIdx.y;
    const int tid = threadIdx.x;
    const int lane = tid & 63;
    const int w = tid >> 6;
    const int qi = idx[bh * U_SEL + u];
    const int nk = qi + 1;
    const float* Srow = S + ((size_t)(bh * U_SEL + u)) * T_SEQ;

    // merge chunk stats (redundant across threads; 16 floats from L1)
    const float* mp = mstat + (size_t)(bh * U_SEL + u) * NCH;
    const float* lp = lstat + (size_t)(bh * U_SEL + u) * NCH;
    float M = -1e30f;
    #pragma unroll
    for (int c = 0; c < NCH; ++c) M = fmaxf(M, mp[c]);
    float L = 0.f;
    #pragma unroll
    for (int c = 0; c < NCH; ++c) {
        const float mc = mp[c];
        if (mc > -1e29f) L += lp[c] * __expf(mc - M);
    }

    float acc[16] = {};
    const ushort_t* vbase = vT + ((size_t)(bh * HD + w * 16)) * T_SEQ;

    for (int tb = 0; tb < nk; tb += 512) {
        const int t0 = tb + lane * 8;
        // p in registers: masked exp of coalesced S read (S row is full
        // T_SEQ capacity; beyond-nk entries may be garbage -> select, not mul)
        const f32x4 s0 = *(const f32x4*)(Srow + t0);
        const f32x4 s1 = *(const f32x4*)(Srow + t0 + 4);
        float p[8];
        p[0] = (t0 + 0 < nk) ? __expf(s0.x - M) : 0.f;
        p[1] = (t0 + 1 < nk) ? __expf(s0.y - M) : 0.f;
        p[2] = (t0 + 2 < nk) ? __expf(s0.z - M) : 0.f;
        p[3] = (t0 + 3 < nk) ? __expf(s0.w - M) : 0.f;
        p[4] = (t0 + 4 < nk) ? __expf(s1.x - M) : 0.f;
        p[5] = (t0 + 5 < nk) ? __expf(s1.y - M) : 0.f;
        p[6] = (t0 + 6 < nk) ? __expf(s1.z - M) : 0.f;
        p[7] = (t0 + 7 < nk) ? __expf(s1.w - M) : 0.f;

        #pragma unroll
        for (int dd = 0; dd < 16; ++dd) {
            const s16x8 v8 = *(const s16x8*)(vbase + (size_t)dd * T_SEQ + t0);
            acc[dd] += p[0] * bf2f((unsigned short)v8[0]) + p[1] * bf2f((unsigned short)v8[1])
                     + p[2] * bf2f((unsigned short)v8[2]) + p[3] * bf2f((unsigned short)v8[3])
                     + p[4] * bf2f((unsigned short)v8[4]) + p[5] * bf2f((unsigned short)v8[5])
                     + p[6] * bf2f((unsigned short)v8[6]) + p[7] * bf2f((unsigned short)v8[7]);
        }
    }

    float* orow = sel_out + ((size_t)(bh * U_SEL + u)) * HD + w * 16;
    #pragma unroll
    for (int dd = 0; dd < 16; ++dd) {
        float v = acc[dd];
        #pragma unroll
        for (int off = 1; off < 64; off <<= 1) v += __shfl_xor(v, off);
        if (lane == 0) orow[dd] = v / L;
    }
}

// ---------------------------------------------------------------------------
// out_proj: one block per output row (b,t). out = bo + sum over owning heads.
// ---------------------------------------------------------------------------
__global__ __launch_bounds__(256) void out_proj(
    const float* __restrict__ sel_out, const float* __restrict__ Wo,
    const float* __restrict__ bo, const unsigned* __restrict__ selmask,
    const int* __restrict__ selu, float* __restrict__ out)
{
    const int row = blockIdx.x;               // 0..4095
    const int b = row >> 11;
    const int tid = threadIdx.x;
    const int c0 = tid * 4;

    __shared__ float s[HD];
    f32x4 o = *(const f32x4*)&bo[c0];
    unsigned mask = selmask[row];

    while (mask) {
        const int h = __ffs(mask) - 1;
        mask &= mask - 1;
        const int u = selu[row * NH + h];
        if (tid < HD)
            s[tid] = sel_out[((size_t)((b * NH + h) * U_SEL + u)) * HD + tid];
        __syncthreads();
        #pragma unroll 8
        for (int r = 0; r < HD; ++r) {
            const float sv = s[r];
            const f32x4 w4 = *(const f32x4*)&Wo[((size_t)(h * HD + r)) * D_MODEL + c0];
            o.x += sv * w4.x; o.y += sv * w4.y; o.z += sv * w4.z; o.w += sv * w4.w;
        }
        __syncthreads();
    }
    *(f32x4*)&out[(size_t)row * D_MODEL + c0] = o;
}

// ---------------------------------------------------------------------------
extern "C" void kernel_launch(void* const* d_in, const int* in_sizes, int n_in,
                              void* d_out, int out_size, void* d_ws, size_t ws_size,
                              hipStream_t stream)
{
    const float* x  = (const float*)d_in[0];
    const float* Wq = (const float*)d_in[1];
    const float* bq = (const float*)d_in[2];
    const float* Wk = (const float*)d_in[3];
    const float* bk = (const float*)d_in[4];
    const float* Wv = (const float*)d_in[5];
    const float* bv = (const float*)d_in[6];
    const float* Wo = (const float*)d_in[7];
    const float* bo = (const float*)d_in[8];
    float* out = (float*)d_out;

    // workspace layout (~50 MB; ws >= 58 MB proven in round 5)
    char* ws = (char*)d_ws;
    ushort_t* xh      = (ushort_t*)(ws);                              //  8 MB
    ushort_t* wqhT    = (ushort_t*)(ws + (8u << 20));                 //  2 MB
    ushort_t* wkhT    = (ushort_t*)(ws + (10u << 20));                //  2 MB
    ushort_t* wvhT    = (ushort_t*)(ws + (12u << 20));                //  2 MB
    ushort_t* k       = (ushort_t*)(ws + (14u << 20));                //  8 MB
    ushort_t* vT      = (ushort_t*)(ws + (22u << 20));                //  8 MB
    float*    S       = (float*)(ws + (38u << 20));                   // 10 MB
    float*    norms   = (float*)(ws + (48u << 20));                   // 256 KB
    int*      cand_t  = (int*)(ws + (48u << 20) + (256u << 10));      // 12 KB
    int*      cand_cnt= (int*)(ws + (48u << 20) + (272u << 10));      // 128 B
    float*    n_exact = (float*)(ws + (48u << 20) + (276u << 10));    // 12 KB
    int*      idx     = (int*)(ws + (48u << 20) + (292u << 10));      // ~5 KB
    float*    sel_out = (float*)(ws + (48u << 20) + (300u << 10));    // 304 KB
    unsigned* selmask = (unsigned*)(ws + (48u << 20) + (640u << 10)); // 16 KB
    int*      selu    = (int*)(ws + (48u << 20) + (656u << 10));      // 256 KB
    float*    mstat   = (float*)(ws + (48u << 20) + (912u << 10));    // 38 KB
    float*    lstat   = (float*)(ws + (48u << 20) + (960u << 10));    // 38 KB
    float*    q_exact = (float*)(ws + (49u << 20));                   // 786 KB
    int*      rank2c  = (int*)(ws + (49u << 20) + (800u << 10));      // ~5 KB

    prep<<<2048 + 768, 256, 0, stream>>>(x, Wq, Wk, Wv, xh, wqhT, wkhT, wvhT);
    {
        dim3 g((NB * T_SEQ) / GBM, D_MODEL / GBN, 3);
        qkv_mfma<<<g, 256, 0, stream>>>(xh, wqhT, wkhT, wvhT, bq, bk, bv,
                                        k, vT, norms);
    }
    topk_select<<<NB * NH, 256, 0, stream>>>(norms, cand_t, cand_cnt, selmask);
    {
        dim3 g(NB * NH, CAND_CAP);
        fixup_norms<<<g, 256, 0, stream>>>(x, Wq, bq, cand_t, cand_cnt, n_exact, q_exact);
    }
    fixup_select<<<NB * NH, 128, 0, stream>>>(n_exact, cand_t, cand_cnt, idx,
                                              selmask, selu, rank2c);
    {
        dim3 g(NB * NH, T_SEQ / 256, 2);
        attn_scores<<<g, 256, 0, stream>>>(q_exact, rank2c, k, idx, S, mstat, lstat);
    }
    {
        dim3 g(NB * NH, U_SEL);
        attn_pv<<<g, 256, 0, stream>>>(S, vT, idx, mstat, lstat, sel_out);
    }
    out_proj<<<NB * T_SEQ, 256, 0, stream>>>(sel_out, Wo, bo, selmask, selu, out);
}

// Round 13
// 150.508 us; speedup vs baseline: 1.7823x; 1.0010x over previous
//
#include <hip/hip_runtime.h>

#define NB 2
#define T_SEQ 2048
#define D_MODEL 1024
#define NH 16
#define HD 64
#define U_SEL 38
#define CAND_CAP 96
#define NCH 8          // t-chunks of 256 in scores/stats

typedef __attribute__((ext_vector_type(8))) short s16x8;
typedef __attribute__((ext_vector_type(4))) short s16x4;
typedef __attribute__((ext_vector_type(4))) float f32x4;
typedef unsigned short ushort_t;

__device__ __forceinline__ unsigned short f2bf(float f) {
    unsigned u = __float_as_uint(f);
    u += 0x7FFFu + ((u >> 16) & 1u);          // RNE
    return (unsigned short)(u >> 16);
}
__device__ __forceinline__ float bf2f(unsigned short h) {
    return __uint_as_float(((unsigned)h) << 16);
}

__device__ __forceinline__ void async_copy16(const void* g, void* l) {
    __builtin_amdgcn_global_load_lds(
        (const __attribute__((address_space(1))) void*)g,
        (__attribute__((address_space(3))) void*)l, 16, 0, 0);
}

// ---------------------------------------------------------------------------
// prep: blocks [0,2048): x -> xh (bf16). blocks [2048,2816): W -> W^T bf16.
// ---------------------------------------------------------------------------
__global__ __launch_bounds__(256) void prep(
    const float* __restrict__ x,
    const float* __restrict__ Wq, const float* __restrict__ Wk, const float* __restrict__ Wv,
    ushort_t* __restrict__ xh,
    ushort_t* __restrict__ wqhT, ushort_t* __restrict__ wkhT, ushort_t* __restrict__ wvhT)
{
    __shared__ float T[64][68];
    const int tid = threadIdx.x;
    if (blockIdx.x < 2048) {
        const size_t i0 = ((size_t)blockIdx.x * 256 + tid) * 8;
        const f32x4 a = *(const f32x4*)(x + i0);
        const f32x4 b = *(const f32x4*)(x + i0 + 4);
        const float f[8] = {a.x, a.y, a.z, a.w, b.x, b.y, b.z, b.w};
        s16x8 hi;
        #pragma unroll
        for (int e = 0; e < 8; ++e) hi[e] = (short)f2bf(f[e]);
        *(s16x8*)(xh + i0) = hi;
        return;
    }
    const int id2 = blockIdx.x - 2048;
    const int z = id2 >> 8;
    const int rem = id2 & 255;
    const int k0 = (rem & 15) * 64, n0 = (rem >> 4) * 64;
    const float* W = (z == 0) ? Wq : (z == 1) ? Wk : Wv;

    #pragma unroll
    for (int i = 0; i < 4; ++i) {
        const int r = (tid >> 4) + i * 16, c = (tid & 15) * 4;
        *(f32x4*)&T[r][c] = *(const f32x4*)&W[(size_t)(k0 + r) * D_MODEL + n0 + c];
    }
    __syncthreads();

    const int n = tid >> 2, kq = (tid & 3) * 16;
    s16x8 hi0, hi1;
    #pragma unroll
    for (int j = 0; j < 16; ++j) {
        const float f = T[kq + j][n];
        if (j < 8) hi0[j] = (short)f2bf(f);
        else       hi1[j - 8] = (short)f2bf(f);
    }
    ushort_t* oh = (z == 0) ? wqhT : (z == 1) ? wkhT : wvhT;
    const size_t ob = (size_t)(n0 + n) * D_MODEL + k0 + kq;
    *(s16x8*)(oh + ob) = hi0;
    *(s16x8*)(oh + ob + 8) = hi1;
}

// ---------------------------------------------------------------------------
// qkv_mfma: 128x128 tile, BK=64 (16 K-steps, half the barriers/drains of r12),
// 4 waves, global_load_lds width 16 with pre-swizzled SOURCE:
//   8 slots (16B) per 128B row; phys_slot = (slot + row) & 7  -> <=2-way LDS
//   aliasing on ds_read_b128 (free per m136). Read-side phys is lane-only
//   since row&7 == lane&7 for all fragment rows.
// __launch_bounds__(256,4): 16 waves/CU; LDS 32KB x 4 blocks = 128KB <= 160KB.
//  z0: per-(b,h,t) L1 norms only.  z1: K bf16.  z2: V -> vT transposed.
// ---------------------------------------------------------------------------
#define GBM 128
#define GBN 128
#define GBK 64

__global__ __launch_bounds__(256, 4) void qkv_mfma(
    const ushort_t* __restrict__ xh,
    const ushort_t* __restrict__ wqhT, const ushort_t* __restrict__ wkhT,
    const ushort_t* __restrict__ wvhT,
    const float* __restrict__ bq, const float* __restrict__ bk, const float* __restrict__ bv,
    ushort_t* __restrict__ ko, ushort_t* __restrict__ vT,
    float* __restrict__ norms)
{
    const int z = blockIdx.z;
    __shared__ ushort_t Ah[GBM * GBK];   // 16 KB
    __shared__ ushort_t Bh[GBN * GBK];   // 16 KB

    const int tid = threadIdx.x;
    const int lane = tid & 63;
    const int wid = tid >> 6;
    const int wr = wid >> 1, wc = wid & 1;
    const size_t rowBase = (size_t)blockIdx.x * GBM;
    const size_t colBase = (size_t)blockIdx.y * GBN;

    const ushort_t* B0 = (z == 0) ? wqhT : (z == 1) ? wkhT : wvhT;

    // staging: call i covers rows [i*32, i*32+32); thread -> row tid>>3,
    // phys slot tid&7. Source fetches logical slot sl = (phys - row) & 7.
    const int sl = ((tid & 7) - ((tid >> 3) & 7)) & 7;
    const ushort_t* pA = xh + (rowBase + (tid >> 3)) * D_MODEL + sl * 8;
    const ushort_t* pB = B0 + (colBase + (tid >> 3)) * D_MODEL + sl * 8;
    ushort_t* lA = &Ah[tid * 8];
    ushort_t* lB = &Bh[tid * 8];

    // fragment row offsets (elements); phys slot per ks is lane-only
    int arowoff[4], browoff[4];
    #pragma unroll
    for (int i = 0; i < 4; ++i) {
        arowoff[i] = (wr * 64 + i * 16 + (lane & 15)) * GBK;
        browoff[i] = (wc * 64 + i * 16 + (lane & 15)) * GBK;
    }
    const int ph0 = (((lane >> 4) + (lane & 7)) & 7) * 8;       // ks=0
    const int ph1 = (((lane >> 4) + 4 + (lane & 7)) & 7) * 8;   // ks=1

    f32x4 acc[4][4] = {};

    for (int kk = 0; kk < 16; ++kk) {
        const int k0 = kk * GBK;
        #pragma unroll
        for (int i = 0; i < 4; ++i) {
            async_copy16(pA + (size_t)i * 32 * D_MODEL + k0, lA + i * 2048);
            async_copy16(pB + (size_t)i * 32 * D_MODEL + k0, lB + i * 2048);
        }
        __syncthreads();

        #pragma unroll
        for (int ks = 0; ks < 2; ++ks) {
            const int po = ks ? ph1 : ph0;
            s16x8 bf4[4];
            #pragma unroll
            for (int j = 0; j < 4; ++j) bf4[j] = *(const s16x8*)&Bh[browoff[j] + po];
            #pragma unroll
            for (int i = 0; i < 4; ++i) {
                const s16x8 af = *(const s16x8*)&Ah[arowoff[i] + po];
                #pragma unroll
                for (int j = 0; j < 4; ++j)
                    acc[i][j] = __builtin_amdgcn_mfma_f32_16x16x32_bf16(af, bf4[j], acc[i][j], 0, 0, 0);
            }
        }
        __syncthreads();
    }

    // epilogue: C/D layout col=lane&15, row=(lane>>4)*4+r
    const int cB = (int)colBase + wc * 64 + (lane & 15);
    const int rL = wr * 64 + ((lane >> 4) << 2);
    const int rB = (int)rowBase + rL;
    if (z == 0) {
        float bjv[4];
        #pragma unroll
        for (int j = 0; j < 4; ++j) bjv[j] = bq[cB + j * 16];
        const int bb = (int)(rowBase >> 11);
        const int hw = cB >> 6;
        #pragma unroll
        for (int i = 0; i < 4; ++i) {
            float nr[4];
            #pragma unroll
            for (int r = 0; r < 4; ++r) {
                float s = 0.f;
                #pragma unroll
                for (int j = 0; j < 4; ++j) s += fabsf(acc[i][j][r] + bjv[j]);
                nr[r] = s;
            }
            #pragma unroll
            for (int off = 1; off < 16; off <<= 1) {
                #pragma unroll
                for (int r = 0; r < 4; ++r) nr[r] += __shfl_xor(nr[r], off);
            }
            if ((lane & 15) == 0) {
                const int trow = (int)(rowBase & (T_SEQ - 1)) + wr * 64 + i * 16 + ((lane >> 4) << 2);
                f32x4 nv; nv.x = nr[0]; nv.y = nr[1]; nv.z = nr[2]; nv.w = nr[3];
                *(f32x4*)&norms[(size_t)(bb * NH + hw) * T_SEQ + trow] = nv;
            }
        }
    } else if (z == 1) {
        #pragma unroll
        for (int j = 0; j < 4; ++j) {
            const float bj = bk[cB + j * 16];
            #pragma unroll
            for (int i = 0; i < 4; ++i)
                #pragma unroll
                for (int r = 0; r < 4; ++r)
                    ko[(size_t)(rB + i * 16 + r) * D_MODEL + cB + j * 16] = f2bf(acc[i][j][r] + bj);
        }
    } else {
        const int bb = (int)(rowBase >> 11);
        const int tBase = (int)(rowBase & (T_SEQ - 1)) + rL;
        #pragma unroll
        for (int j = 0; j < 4; ++j) {
            const int dg = cB + j * 16;
            const float bj = bv[dg];
            ushort_t* vrow = vT + ((size_t)(bb * NH) * HD + dg) * T_SEQ;
            #pragma unroll
            for (int i = 0; i < 4; ++i) {
                s16x4 pk;
                #pragma unroll
                for (int r = 0; r < 4; ++r)
                    pk[r] = (short)f2bf(acc[i][j][r] + bj);
                *(s16x4*)&vrow[tBase + i * 16] = pk;
            }
        }
    }
}

// ---------------------------------------------------------------------------
// topk_select: zero selmask; 3-pass radix -> v38; emit band {n >= v38 - 0.4}.
// ---------------------------------------------------------------------------
__global__ __launch_bounds__(256) void topk_select(
    const float* __restrict__ norms, int* __restrict__ cand_t, int* __restrict__ cand_cnt,
    unsigned* __restrict__ selmask)
{
    const int bh = blockIdx.x;
    const int tid = threadIdx.x;
    const int lane = tid & 63;
    const int w = tid >> 6;

    if (tid < 128) selmask[bh * 128 + tid] = 0u;

    __shared__ unsigned keys[T_SEQ];
    __shared__ unsigned hist[2048];
    __shared__ unsigned wsum[4];
    __shared__ unsigned bc_bin, bc_above;
    __shared__ int cnt;

    const float* nr = norms + (size_t)bh * T_SEQ;
    #pragma unroll
    for (int j = 0; j < 8; ++j)
        keys[tid + j * 256] = __float_as_uint(nr[tid + j * 256]);

    const int  shifts[3] = {21, 10, 0};
    const unsigned binm[3]  = {0x7FFu, 0x7FFu, 0x3FFu};
    const unsigned prefm[3] = {0x00000000u, 0xFFE00000u, 0xFFFFFC00u};

    unsigned prefix = 0;
    unsigned K_rem = U_SEL;

    for (int p = 0; p < 3; ++p) {
        #pragma unroll
        for (int j = 0; j < 8; ++j) hist[tid + j * 256] = 0;
        __syncthreads();
        #pragma unroll
        for (int j = 0; j < 8; ++j) {
            const unsigned k = keys[tid + j * 256];
            if ((k & prefm[p]) == prefix)
                atomicAdd(&hist[(k >> shifts[p]) & binm[p]], 1u);
        }
        __syncthreads();

        unsigned s = 0;
        #pragma unroll
        for (int e = 0; e < 8; ++e) s += hist[tid * 8 + e];
        unsigned v = s;
        #pragma unroll
        for (int off = 1; off < 64; off <<= 1) {
            const unsigned o = __shfl_down((int)v, off);
            if (lane + off < 64) v += o;
        }
        if (lane == 0) wsum[w] = v;
        __syncthreads();
        unsigned suf = v;
        for (int ww = w + 1; ww < 4; ++ww) suf += wsum[ww];
        const unsigned suf_next = suf - s;

        if (suf >= K_rem && suf_next < K_rem) {
            unsigned acc = suf_next;
            #pragma unroll
            for (int e = 7; e >= 0; --e) {
                const unsigned nb = hist[tid * 8 + e];
                if (acc + nb >= K_rem) { bc_bin = tid * 8 + e; bc_above = acc; break; }
                acc += nb;
            }
        }
        __syncthreads();
        prefix |= bc_bin << shifts[p];
        K_rem -= bc_above;
        __syncthreads();
    }

    const float thr = __uint_as_float(prefix) - 0.4f;
    if (tid == 0) cnt = 0;
    __syncthreads();
    #pragma unroll
    for (int j = 0; j < 8; ++j) {
        const int i = tid + j * 256;
        if (__uint_as_float(keys[i]) >= thr) {
            const int s = atomicAdd(&cnt, 1);
            if (s < CAND_CAP) cand_t[bh * CAND_CAP + s] = i;
        }
    }
    __syncthreads();
    if (tid == 0) cand_cnt[bh] = cnt < CAND_CAP ? cnt : CAND_CAP;
}

// ---------------------------------------------------------------------------
// fixup_norms: one block per (bh, candidate). Exact f32 q-row from x, Wq:
// stores BOTH the L1 norm and the exact q row (for attn_scores).
// ---------------------------------------------------------------------------
__global__ __launch_bounds__(256) void fixup_norms(
    const float* __restrict__ x, const float* __restrict__ Wq,
    const float* __restrict__ bq, const int* __restrict__ cand_t,
    const int* __restrict__ cand_cnt, float* __restrict__ n_exact,
    float* __restrict__ q_exact)
{
    const int bh = blockIdx.x, c = blockIdx.y;
    const int b = bh >> 4, h = bh & 15;
    if (c >= cand_cnt[bh]) return;
    const int t = cand_t[bh * CAND_CAP + c];
    const int tid = threadIdx.x, d = tid & 63, kq = tid >> 6;

    __shared__ float xs[D_MODEL];
    __shared__ float part[4][HD];

    *(f32x4*)&xs[tid * 4] = *(const f32x4*)&x[((size_t)(b * T_SEQ + t)) * D_MODEL + tid * 4];
    __syncthreads();

    const float* wp = Wq + (size_t)(kq * 256) * D_MODEL + h * HD + d;
    const float* xp = &xs[kq * 256];
    float a0 = 0.f, a1 = 0.f, a2 = 0.f, a3 = 0.f;
    #pragma unroll 4
    for (int k = 0; k < 256; k += 4) {
        a0 += xp[k]     * wp[(k)     * D_MODEL];
        a1 += xp[k + 1] * wp[(k + 1) * D_MODEL];
        a2 += xp[k + 2] * wp[(k + 2) * D_MODEL];
        a3 += xp[k + 3] * wp[(k + 3) * D_MODEL];
    }
    part[kq][d] = (a0 + a1) + (a2 + a3);
    __syncthreads();
    if (tid < 64) {
        const float qd = part[0][tid] + part[1][tid] + part[2][tid] + part[3][tid]
                       + bq[h * HD + tid];
        q_exact[((size_t)(bh * CAND_CAP + c)) * HD + tid] = qd;
        float v = fabsf(qd);
        #pragma unroll
        for (int off = 1; off < 64; off <<= 1) v += __shfl_xor(v, off);
        if (tid == 0) n_exact[bh * CAND_CAP + c] = v;
    }
}

// ---------------------------------------------------------------------------
// fixup_select: PARALLEL rank-select ((n,-t) strict total order). Also
// records rank -> candidate slot for attn_scores' q_exact gather.
// ---------------------------------------------------------------------------
__global__ __launch_bounds__(128) void fixup_select(
    const float* __restrict__ n_exact, const int* __restrict__ cand_t,
    const int* __restrict__ cand_cnt, int* __restrict__ idx_out,
    unsigned* __restrict__ selmask, int* __restrict__ selu,
    int* __restrict__ rank2c)
{
    const int bh = blockIdx.x;
    const int tid = threadIdx.x;
    const int nc = cand_cnt[bh];
    const int b = bh >> 4, h = bh & 15;

    __shared__ float nv[CAND_CAP];
    __shared__ int   tv[CAND_CAP];

    if (tid < nc) {
        nv[tid] = n_exact[bh * CAND_CAP + tid];
        tv[tid] = cand_t[bh * CAND_CAP + tid];
    }
    __syncthreads();

    if (tid < nc) {
        const float ni = nv[tid];
        const int   ti = tv[tid];
        int rank = 0;
        for (int j = 0; j < nc; ++j) {
            const float njv = nv[j];
            const int   tj  = tv[j];
            rank += (njv > ni || (njv == ni && tj < ti)) ? 1 : 0;
        }
        if (rank < U_SEL) {
            idx_out[bh * U_SEL + rank] = ti;
            rank2c[bh * U_SEL + rank] = tid;
            const int row = (b << 11) + ti;
            atomicOr(&selmask[row], 1u << h);
            selu[row * NH + h] = rank;
        }
    }
}

// ---------------------------------------------------------------------------
// attn_scores: S + per-(u,chunk) softmax stats. q from q_exact (exact f32).
// Grid (32 bh, 8 t-chunks, 2 u-groups of 19). K row in 64 VGPRs, reused.
// ---------------------------------------------------------------------------
__global__ __launch_bounds__(256) void attn_scores(
    const float* __restrict__ q_exact, const int* __restrict__ rank2c,
    const ushort_t* __restrict__ kk_, const int* __restrict__ idx,
    float* __restrict__ S, float* __restrict__ mstat, float* __restrict__ lstat)
{
    const int bh = blockIdx.x, ch = blockIdx.y, ug = blockIdx.z;
    const int b = bh >> 4, h = bh & 15;
    const int tid = threadIdx.x;
    const int lane = tid & 63;
    const int w = tid >> 6;
    const int t = ch * 256 + tid;
    const int u0 = ug * 19;

    __shared__ float qs[19][HD];
    __shared__ int qis[19];
    __shared__ int qcs[19];
    __shared__ float mpart[19][4];
    __shared__ float lpart[19][4];

    if (tid < 19) {
        qis[tid] = idx[bh * U_SEL + u0 + tid];
        qcs[tid] = rank2c[bh * U_SEL + u0 + tid];
    }
    if (tid < 76) { mpart[tid >> 2][tid & 3] = -1e30f; lpart[tid >> 2][tid & 3] = 0.f; }
    __syncthreads();
    for (int e = tid; e < 19 * HD; e += 256) {
        const int u = e >> 6, d = e & 63;
        qs[u][d] = q_exact[((size_t)(bh * CAND_CAP + qcs[u])) * HD + d] * 0.125f;
    }

    float kr[64];
    {
        const ushort_t* kp = kk_ + ((size_t)(b * T_SEQ + t)) * D_MODEL + h * HD;
        #pragma unroll
        for (int d0 = 0; d0 < 64; d0 += 8) {
            const s16x8 r = *(const s16x8*)(kp + d0);
            #pragma unroll
            for (int e = 0; e < 8; ++e) kr[d0 + e] = bf2f((unsigned short)r[e]);
        }
    }
    __syncthreads();

    const int wbase = ch * 256 + (tid & ~63);   // wave's min t (uniform)
    for (int uu = 0; uu < 19; ++uu) {
        const int qi = qis[uu];
        if (wbase > qi) continue;               // wave-uniform skip
        float sp0 = 0.f, sp1 = 0.f, sp2 = 0.f, sp3 = 0.f;
        #pragma unroll
        for (int d0 = 0; d0 < 64; d0 += 16) {
            const f32x4 q0 = *(const f32x4*)&qs[uu][d0];
            const f32x4 q1 = *(const f32x4*)&qs[uu][d0 + 4];
            const f32x4 q2 = *(const f32x4*)&qs[uu][d0 + 8];
            const f32x4 q3 = *(const f32x4*)&qs[uu][d0 + 12];
            sp0 += q0.x * kr[d0] + q0.y * kr[d0 + 1] + q0.z * kr[d0 + 2] + q0.w * kr[d0 + 3];
            sp1 += q1.x * kr[d0 + 4] + q1.y * kr[d0 + 5] + q1.z * kr[d0 + 6] + q1.w * kr[d0 + 7];
            sp2 += q2.x * kr[d0 + 8] + q2.y * kr[d0 + 9] + q2.z * kr[d0 + 10] + q2.w * kr[d0 + 11];
            sp3 += q3.x * kr[d0 + 12] + q3.y * kr[d0 + 13] + q3.z * kr[d0 + 14] + q3.w * kr[d0 + 15];
        }
        const float s = sp0 + sp1 + sp2 + sp3;
        S[((size_t)(bh * U_SEL + u0 + uu)) * T_SEQ + t] = s;
        const float sm = (t <= qi) ? s : -1e30f;
        float mw = sm;
        #pragma unroll
        for (int off = 1; off < 64; off <<= 1) mw = fmaxf(mw, __shfl_xor(mw, off));
        float p = (t <= qi) ? __expf(s - mw) : 0.f;
        #pragma unroll
        for (int off = 1; off < 64; off <<= 1) p += __shfl_xor(p, off);
        if (lane == 0) { mpart[uu][w] = mw; lpart[uu][w] = p; }
    }
    __syncthreads();
    if (tid < 19) {
        float M = -1e30f;
        #pragma unroll
        for (int ww = 0; ww < 4; ++ww) M = fmaxf(M, mpart[tid][ww]);
        float L = 0.f;
        #pragma unroll
        for (int ww = 0; ww < 4; ++ww) {
            const float mw = mpart[tid][ww];
            if (mw > -1e29f) L += lpart[tid][ww] * __expf(mw - M);
        }
        const size_t si = (size_t)(bh * U_SEL + u0 + tid) * NCH + ch;
        mstat[si] = M;
        lstat[si] = L;
    }
}

// ---------------------------------------------------------------------------
// attn_pv: one block per (bh,u). Wave-per-d structure: wave w owns 16 d-rows;
// per 512-t chunk lane l covers t in [tb+8l, tb+8l+8): coalesced S read +
// masked exp in regs, 16 coalesced vT reads with 8 FMA each, 64-lane reduce.
// ---------------------------------------------------------------------------
__global__ __launch_bounds__(256) void attn_pv(
    const float* __restrict__ S, const ushort_t* __restrict__ vT,
    const int* __restrict__ idx, const float* __restrict__ mstat,
    const float* __restrict__ lstat, float* __restrict__ sel_out)
{
    const int bh = blockIdx.x, u = blockIdx.y;
    const int tid = threadIdx.x;
    const int lane = tid & 63;
    const int w = tid >> 6;
    const int qi = idx[bh * U_SEL + u];
    const int nk = qi + 1;
    const float* Srow = S + ((size_t)(bh * U_SEL + u)) * T_SEQ;

    const float* mp = mstat + (size_t)(bh * U_SEL + u) * NCH;
    const float* lp = lstat + (size_t)(bh * U_SEL + u) * NCH;
    float M = -1e30f;
    #pragma unroll
    for (int c = 0; c < NCH; ++c) M = fmaxf(M, mp[c]);
    float L = 0.f;
    #pragma unroll
    for (int c = 0; c < NCH; ++c) {
        const float mc = mp[c];
        if (mc > -1e29f) L += lp[c] * __expf(mc - M);
    }

    float acc[16] = {};
    const ushort_t* vbase = vT + ((size_t)(bh * HD + w * 16)) * T_SEQ;

    for (int tb = 0; tb < nk; tb += 512) {
        const int t0 = tb + lane * 8;
        const f32x4 s0 = *(const f32x4*)(Srow + t0);
        const f32x4 s1 = *(const f32x4*)(Srow + t0 + 4);
        float p[8];
        p[0] = (t0 + 0 < nk) ? __expf(s0.x - M) : 0.f;
        p[1] = (t0 + 1 < nk) ? __expf(s0.y - M) : 0.f;
        p[2] = (t0 + 2 < nk) ? __expf(s0.z - M) : 0.f;
        p[3] = (t0 + 3 < nk) ? __expf(s0.w - M) : 0.f;
        p[4] = (t0 + 4 < nk) ? __expf(s1.x - M) : 0.f;
        p[5] = (t0 + 5 < nk) ? __expf(s1.y - M) : 0.f;
        p[6] = (t0 + 6 < nk) ? __expf(s1.z - M) : 0.f;
        p[7] = (t0 + 7 < nk) ? __expf(s1.w - M) : 0.f;

        #pragma unroll
        for (int dd = 0; dd < 16; ++dd) {
            const s16x8 v8 = *(const s16x8*)(vbase + (size_t)dd * T_SEQ + t0);
            acc[dd] += p[0] * bf2f((unsigned short)v8[0]) + p[1] * bf2f((unsigned short)v8[1])
                     + p[2] * bf2f((unsigned short)v8[2]) + p[3] * bf2f((unsigned short)v8[3])
                     + p[4] * bf2f((unsigned short)v8[4]) + p[5] * bf2f((unsigned short)v8[5])
                     + p[6] * bf2f((unsigned short)v8[6]) + p[7] * bf2f((unsigned short)v8[7]);
        }
    }

    float* orow = sel_out + ((size_t)(bh * U_SEL + u)) * HD + w * 16;
    #pragma unroll
    for (int dd = 0; dd < 16; ++dd) {
        float v = acc[dd];
        #pragma unroll
        for (int off = 1; off < 64; off <<= 1) v += __shfl_xor(v, off);
        if (lane == 0) orow[dd] = v / L;
    }
}

// ---------------------------------------------------------------------------
// out_proj: one block per output row (b,t). out = bo + sum over owning heads.
// ---------------------------------------------------------------------------
__global__ __launch_bounds__(256) void out_proj(
    const float* __restrict__ sel_out, const float* __restrict__ Wo,
    const float* __restrict__ bo, const unsigned* __restrict__ selmask,
    const int* __restrict__ selu, float* __restrict__ out)
{
    const int row = blockIdx.x;               // 0..4095
    const int b = row >> 11;
    const int tid = threadIdx.x;
    const int c0 = tid * 4;

    __shared__ float s[HD];
    f32x4 o = *(const f32x4*)&bo[c0];
    unsigned mask = selmask[row];

    while (mask) {
        const int h = __ffs(mask) - 1;
        mask &= mask - 1;
        const int u = selu[row * NH + h];
        if (tid < HD)
            s[tid] = sel_out[((size_t)((b * NH + h) * U_SEL + u)) * HD + tid];
        __syncthreads();
        #pragma unroll 8
        for (int r = 0; r < HD; ++r) {
            const float sv = s[r];
            const f32x4 w4 = *(const f32x4*)&Wo[((size_t)(h * HD + r)) * D_MODEL + c0];
            o.x += sv * w4.x; o.y += sv * w4.y; o.z += sv * w4.z; o.w += sv * w4.w;
        }
        __syncthreads();
    }
    *(f32x4*)&out[(size_t)row * D_MODEL + c0] = o;
}

// ---------------------------------------------------------------------------
extern "C" void kernel_launch(void* const* d_in, const int* in_sizes, int n_in,
                              void* d_out, int out_size, void* d_ws, size_t ws_size,
                              hipStream_t stream)
{
    const float* x  = (const float*)d_in[0];
    const float* Wq = (const float*)d_in[1];
    const float* bq = (const float*)d_in[2];
    const float* Wk = (const float*)d_in[3];
    const float* bk = (const float*)d_in[4];
    const float* Wv = (const float*)d_in[5];
    const float* bv = (const float*)d_in[6];
    const float* Wo = (const float*)d_in[7];
    const float* bo = (const float*)d_in[8];
    float* out = (float*)d_out;

    // workspace layout (~50 MB; ws >= 58 MB proven in round 5)
    char* ws = (char*)d_ws;
    ushort_t* xh      = (ushort_t*)(ws);                              //  8 MB
    ushort_t* wqhT    = (ushort_t*)(ws + (8u << 20));                 //  2 MB
    ushort_t* wkhT    = (ushort_t*)(ws + (10u << 20));                //  2 MB
    ushort_t* wvhT    = (ushort_t*)(ws + (12u << 20));                //  2 MB
    ushort_t* k       = (ushort_t*)(ws + (14u << 20));                //  8 MB
    ushort_t* vT      = (ushort_t*)(ws + (22u << 20));                //  8 MB
    float*    S       = (float*)(ws + (38u << 20));                   // 10 MB
    float*    norms   = (float*)(ws + (48u << 20));                   // 256 KB
    int*      cand_t  = (int*)(ws + (48u << 20) + (256u << 10));      // 12 KB
    int*      cand_cnt= (int*)(ws + (48u << 20) + (272u << 10));      // 128 B
    float*    n_exact = (float*)(ws + (48u << 20) + (276u << 10));    // 12 KB
    int*      idx     = (int*)(ws + (48u << 20) + (292u << 10));      // ~5 KB
    float*    sel_out = (float*)(ws + (48u << 20) + (300u << 10));    // 304 KB
    unsigned* selmask = (unsigned*)(ws + (48u << 20) + (640u << 10)); // 16 KB
    int*      selu    = (int*)(ws + (48u << 20) + (656u << 10));      // 256 KB
    float*    mstat   = (float*)(ws + (48u << 20) + (912u << 10));    // 38 KB
    float*    lstat   = (float*)(ws + (48u << 20) + (960u << 10));    // 38 KB
    float*    q_exact = (float*)(ws + (49u << 20));                   // 786 KB
    int*      rank2c  = (int*)(ws + (49u << 20) + (800u << 10));      // ~5 KB

    prep<<<2048 + 768, 256, 0, stream>>>(x, Wq, Wk, Wv, xh, wqhT, wkhT, wvhT);
    {
        dim3 g((NB * T_SEQ) / GBM, D_MODEL / GBN, 3);
        qkv_mfma<<<g, 256, 0, stream>>>(xh, wqhT, wkhT, wvhT, bq, bk, bv,
                                        k, vT, norms);
    }
    topk_select<<<NB * NH, 256, 0, stream>>>(norms, cand_t, cand_cnt, selmask);
    {
        dim3 g(NB * NH, CAND_CAP);
        fixup_norms<<<g, 256, 0, stream>>>(x, Wq, bq, cand_t, cand_cnt, n_exact, q_exact);
    }
    fixup_select<<<NB * NH, 128, 0, stream>>>(n_exact, cand_t, cand_cnt, idx,
                                              selmask, selu, rank2c);
    {
        dim3 g(NB * NH, T_SEQ / 256, 2);
        attn_scores<<<g, 256, 0, stream>>>(q_exact, rank2c, k, idx, S, mstat, lstat);
    }
    {
        dim3 g(NB * NH, U_SEL);
        attn_pv<<<g, 256, 0, stream>>>(S, vT, idx, mstat, lstat, sel_out);
    }
    out_proj<<<NB * T_SEQ, 256, 0, stream>>>(sel_out, Wo, bo, selmask, selu, out);
}